// Round 1
// baseline (672.224 us; speedup 1.0000x reference)
//
#include <hip/hip_runtime.h>

// Problem constants (fixed by reference: B=32, 32x32 tokens, DM=768, C=64, ch=32,
// theta_res=3 -> 60 thetas, rho_res=1 on 32x32 -> q=44 -> 89 rhos)
#define NB    32          // batch
#define NTOK  1024        // tokens per batch (32*32)
#define DMODEL 768
#define CF    64          // C (to_feats channels)
#define CHH   32          // ch = C/2
#define NRHO  89
#define NTH   60
#define HRB   (NRHO*NTH)  // 5340

// ---------------------------------------------------------------------------
// K0a: extract flat[n][t] = hough bin index h (h = rho*60 + t) from vote
__global__ __launch_bounds__(256) void k0_flat(const float* __restrict__ vote,
                                               int* __restrict__ flat) {
    int i = blockIdx.x * 256 + threadIdx.x;
    if (i >= NTOK * HRB) return;
    float v = vote[i];
    if (v != 0.0f) {
        int n = i / HRB, h = i % HRB;
        flat[n * NTH + (h % NTH)] = h;
    }
}

// K0b: inv[h] = 1 / max(count(h), 1)  (count = column-sum of vote)
__global__ __launch_bounds__(256) void k0_inv(const float* __restrict__ vote,
                                              float* __restrict__ inv) {
    int h = blockIdx.x * 256 + threadIdx.x;
    if (h >= HRB) return;
    float cnt = 0.0f;
    for (int n = 0; n < NTOK; ++n)
        cnt += (vote[(size_t)n * HRB + h] != 0.0f) ? 1.0f : 0.0f;
    inv[h] = 1.0f / fmaxf(cnt, 1.0f);
}

// ---------------------------------------------------------------------------
// K1: feat = tokens @ Wt_in^T + bt_in;  y = relu(feat @ W1^T)
// M = NB*NTOK = 32768 rows. Block: 64 rows x 64 cols, 256 threads (16x16 of 4x4).
__global__ __launch_bounds__(256) void k1_feat_y(
    const float* __restrict__ tokens, const float* __restrict__ Wt_in,
    const float* __restrict__ bt_in, const float* __restrict__ W1,
    float* __restrict__ feat, float* __restrict__ y) {
    __shared__ float As[32][68];    // A^T chunk: As[kk][m]
    __shared__ float Ws[32][68];    // W^T chunk: Ws[kk][c]
    __shared__ float fs[64][68];    // feat tile [m][c]
    __shared__ float w1t[64 * 32];  // w1t[c][cc] = W1[cc][c]

    const int tid = threadIdx.x;
    const int row0 = blockIdx.x * 64;

    for (int idx = tid; idx < 64 * 32; idx += 256) {
        int cc = idx & 31, c = idx >> 5;
        w1t[c * 32 + cc] = W1[cc * 64 + c];
    }

    const int tx = tid & 15, ty = tid >> 4;
    float acc[4][4] = {};

    for (int k0 = 0; k0 < DMODEL; k0 += 32) {
        __syncthreads();
        for (int idx = tid; idx < 64 * 32; idx += 256) {
            int m = idx >> 5, kk = idx & 31;
            As[kk][m] = tokens[(size_t)(row0 + m) * DMODEL + k0 + kk];
        }
        for (int idx = tid; idx < 64 * 32; idx += 256) {
            int c = idx >> 5, kk = idx & 31;
            Ws[kk][c] = Wt_in[(size_t)c * DMODEL + k0 + kk];
        }
        __syncthreads();
        #pragma unroll
        for (int kk = 0; kk < 32; ++kk) {
            float4 av = *(const float4*)&As[kk][ty * 4];
            float4 bv = *(const float4*)&Ws[kk][tx * 4];
            float aa[4] = {av.x, av.y, av.z, av.w};
            float bb[4] = {bv.x, bv.y, bv.z, bv.w};
            #pragma unroll
            for (int i = 0; i < 4; ++i)
                #pragma unroll
                for (int j = 0; j < 4; ++j) acc[i][j] += aa[i] * bb[j];
        }
    }

    float4 bi = *(const float4*)&bt_in[tx * 4];
    #pragma unroll
    for (int i = 0; i < 4; ++i) {
        int m = ty * 4 + i;
        float4 v;
        v.x = acc[i][0] + bi.x; v.y = acc[i][1] + bi.y;
        v.z = acc[i][2] + bi.z; v.w = acc[i][3] + bi.w;
        *(float4*)&fs[m][tx * 4] = v;
        *(float4*)&feat[(size_t)(row0 + m) * CF + tx * 4] = v;
    }
    __syncthreads();

    // y = relu(fs @ W1^T): 64 m x 32 cc outputs
    const int cc = tid & 31, mb = tid >> 5;
    for (int mm = mb; mm < 64; mm += 8) {
        float s = 0.0f;
        #pragma unroll 8
        for (int c = 0; c < 64; ++c) s += fs[mm][c] * w1t[c * 32 + cc];
        y[(size_t)(row0 + mm) * CHH + cc] = fmaxf(s, 0.0f);
    }
}

// ---------------------------------------------------------------------------
// K2: ht[b, h, c] = (sum over pixels voting into h of y[b,n,c]) * inv[h]
// One block per (b, t). LDS accumulator [NRHO][CHH] with shared-mem atomics.
__global__ __launch_bounds__(256) void k2_ht(
    const float* __restrict__ y, const int* __restrict__ flat,
    const float* __restrict__ inv, float* __restrict__ ht) {
    __shared__ float acc[NRHO * CHH];  // 11.4 KB
    const int tid = threadIdx.x;
    const int b = blockIdx.x / NTH, t = blockIdx.x % NTH;

    for (int i = tid; i < NRHO * CHH; i += 256) acc[i] = 0.0f;
    __syncthreads();

    const int c = tid & 31, g = tid >> 5;  // 8 n-groups
    for (int n = g; n < NTOK; n += 8) {
        int h = flat[n * NTH + t];
        float v = y[((size_t)b * NTOK + n) * CHH + c];
        atomicAdd(&acc[(h / NTH) * CHH + c], v);
    }
    __syncthreads();

    for (int i = tid; i < NRHO * CHH; i += 256) {
        int rho = i / CHH, cc2 = i % CHH;
        int h = rho * NTH + t;
        ht[((size_t)b * HRB + h) * CHH + cc2] = acc[i] * inv[h];
    }
}

// ---------------------------------------------------------------------------
// K3: in-place (9,1) conv along rho + relu.  One block per (b, t).
// out[o,r] = relu( sum_{i,k} W2[o,i,k] * in[i, r+k-4] )
__global__ __launch_bounds__(256) void k3_conv(float* __restrict__ ht,
                                               const float* __restrict__ W2) {
    __shared__ float ins[32 * 97];   // ins[i*97 + r], padded stride
    __shared__ float w2s[32 * 32 * 9];
    const int tid = threadIdx.x;
    const int b = blockIdx.x / NTH, t = blockIdx.x % NTH;

    for (int idx = tid; idx < 32 * 32 * 9; idx += 256) w2s[idx] = W2[idx];
    for (int idx = tid; idx < 32 * NRHO; idx += 256) {
        int i = idx & 31, r = idx >> 5;
        ins[i * 97 + r] = ht[((size_t)b * HRB + r * NTH + t) * CHH + i];
    }
    __syncthreads();

    const int o0 = (tid >> 4) * 2;      // 0,2,...,30
    const int r0 = (tid & 15) * 6;      // 0,6,...,90
    float a0[6] = {}, a1[6] = {};
    for (int i = 0; i < 32; ++i) {
        float xv[14];
        #pragma unroll
        for (int j = 0; j < 14; ++j) {
            int x = r0 - 4 + j;
            xv[j] = (x >= 0 && x < NRHO) ? ins[i * 97 + x] : 0.0f;
        }
        const float* w0 = &w2s[(o0 * 32 + i) * 9];
        const float* w1 = &w2s[((o0 + 1) * 32 + i) * 9];
        #pragma unroll
        for (int k = 0; k < 9; ++k) {
            float wa = w0[k], wb = w1[k];
            #pragma unroll
            for (int j = 0; j < 6; ++j) {
                a0[j] += wa * xv[k + j];
                a1[j] += wb * xv[k + j];
            }
        }
    }
    #pragma unroll
    for (int j = 0; j < 6; ++j) {
        int r = r0 + j;
        if (r < NRHO) {
            size_t base = ((size_t)b * HRB + r * NTH + t) * CHH;
            ht[base + o0]     = fmaxf(a0[j], 0.0f);
            ht[base + o0 + 1] = fmaxf(a1[j], 0.0f);
        }
    }
}

// ---------------------------------------------------------------------------
// K4: iht gather (÷60) -> z = iht @ W3^T -> feat += z   (in-place, feat becomes g)
// One block per (b, 64-token tile).
__global__ __launch_bounds__(256) void k4_iht_z(
    const float* __restrict__ ht, const int* __restrict__ flat,
    const float* __restrict__ W3, float* __restrict__ feat) {
    __shared__ float ihts[64 * 32];
    __shared__ float w3t[32 * 64];  // w3t[c][j] = W3[j][c]
    const int tid = threadIdx.x;
    const int b = blockIdx.x >> 4;
    const int n0 = (blockIdx.x & 15) * 64;

    for (int idx = tid; idx < 2048; idx += 256) {
        int c = idx >> 6, j = idx & 63;
        w3t[idx] = W3[j * 32 + c];
    }

    const int c = tid & 31, np = tid >> 5;  // 8 tokens per pass
    for (int p = 0; p < 8; ++p) {
        int nl = p * 8 + np;
        const int* fp = &flat[(n0 + nl) * NTH];
        float s = 0.0f;
        for (int t = 0; t < NTH; ++t) {
            int h = fp[t];
            s += ht[((size_t)b * HRB + h) * CHH + c];
        }
        ihts[nl * 32 + c] = s * (1.0f / 60.0f);
    }
    __syncthreads();

    const int j = tid & 63, nb = tid >> 6;  // 4 token-groups
    for (int nn = nb; nn < 64; nn += 4) {
        float z = 0.0f;
        #pragma unroll 8
        for (int cc = 0; cc < 32; ++cc) z += ihts[nn * 32 + cc] * w3t[cc * 64 + j];
        size_t fi = ((size_t)b * NTOK + n0 + nn) * CF + j;
        feat[fi] = feat[fi] + z;
    }
}

// ---------------------------------------------------------------------------
// K5: out = g @ Wt_out^T + bt_out.  M=32768, K=64, N=768.
// Block: 64 m x 64 d, 256 threads (16x16 of 4x4), single K pass.
__global__ __launch_bounds__(256) void k5_out(
    const float* __restrict__ g, const float* __restrict__ Wt_out,
    const float* __restrict__ bt_out, float* __restrict__ out) {
    __shared__ float gs[64][68];  // gs[j][m]
    __shared__ float ws[64][68];  // ws[j][d]
    const int tid = threadIdx.x;
    const int mblk = blockIdx.x & 511, dblk = blockIdx.x >> 9;
    const int m0 = mblk * 64, d0 = dblk * 64;

    for (int idx = tid; idx < 4096; idx += 256) {
        int ml = idx >> 6, j = idx & 63;
        gs[j][ml] = g[(size_t)(m0 + ml) * CF + j];
    }
    for (int idx = tid; idx < 4096; idx += 256) {
        int dl = idx >> 6, j = idx & 63;
        ws[j][dl] = Wt_out[(size_t)(d0 + dl) * CF + j];
    }
    __syncthreads();

    const int tx = tid & 15, ty = tid >> 4;
    float acc[4][4] = {};
    #pragma unroll
    for (int j = 0; j < 64; ++j) {
        float4 av = *(const float4*)&gs[j][ty * 4];
        float4 bv = *(const float4*)&ws[j][tx * 4];
        float aa[4] = {av.x, av.y, av.z, av.w};
        float bb[4] = {bv.x, bv.y, bv.z, bv.w};
        #pragma unroll
        for (int i = 0; i < 4; ++i)
            #pragma unroll
            for (int jj = 0; jj < 4; ++jj) acc[i][jj] += aa[i] * bb[jj];
    }

    float4 bi = *(const float4*)&bt_out[d0 + tx * 4];
    #pragma unroll
    for (int i = 0; i < 4; ++i) {
        float4 v;
        v.x = acc[i][0] + bi.x; v.y = acc[i][1] + bi.y;
        v.z = acc[i][2] + bi.z; v.w = acc[i][3] + bi.w;
        *(float4*)&out[(size_t)(m0 + ty * 4 + i) * DMODEL + d0 + tx * 4] = v;
    }
}

// ---------------------------------------------------------------------------
extern "C" void kernel_launch(void* const* d_in, const int* in_sizes, int n_in,
                              void* d_out, int out_size, void* d_ws, size_t ws_size,
                              hipStream_t stream) {
    const float* tokens = (const float*)d_in[0];
    const float* vote   = (const float*)d_in[1];
    const float* Wt_in  = (const float*)d_in[2];
    const float* bt_in  = (const float*)d_in[3];
    const float* W1     = (const float*)d_in[4];
    const float* W2     = (const float*)d_in[5];
    const float* W3     = (const float*)d_in[6];
    const float* Wt_out = (const float*)d_in[7];
    const float* bt_out = (const float*)d_in[8];
    float* out = (float*)d_out;

    // workspace layout
    char* w = (char*)d_ws;
    int*   flat = (int*)w;                         // 1024*60*4      = 245760
    float* inv  = (float*)(w + 245760);            // 5340*4         = 21360
    float* feat = (float*)(w + 267264);            // 32768*64*4     = 8388608
    float* yb   = (float*)(w + 267264 + 8388608);  // 32768*32*4     = 4194304
    float* ht   = (float*)(w + 267264 + 8388608 + 4194304);  // 32*5340*32*4 = 21872640

    k0_flat<<<(NTOK * HRB + 255) / 256, 256, 0, stream>>>(vote, flat);
    k0_inv<<<(HRB + 255) / 256, 256, 0, stream>>>(vote, inv);
    k1_feat_y<<<(NB * NTOK) / 64, 256, 0, stream>>>(tokens, Wt_in, bt_in, W1, feat, yb);
    k2_ht<<<NB * NTH, 256, 0, stream>>>(yb, flat, inv, ht);
    k3_conv<<<NB * NTH, 256, 0, stream>>>(ht, W2);
    k4_iht_z<<<NB * (NTOK / 64), 256, 0, stream>>>(ht, flat, W3, feat);
    k5_out<<<(NB * NTOK / 64) * (DMODEL / 64), 256, 0, stream>>>(feat, Wt_out, bt_out, out);
}

// Round 2
// 467.625 us; speedup vs baseline: 1.4375x; 1.4375x over previous
//
#include <hip/hip_runtime.h>

// Problem constants (fixed by reference: B=32, 32x32 tokens, DM=768, C=64, ch=32,
// theta_res=3 -> 60 thetas, rho_res=1 on 32x32 -> q=44 -> 89 rhos)
#define NB    32          // batch
#define NTOK  1024        // tokens per batch (32*32)
#define DMODEL 768
#define CF    64          // C (to_feats channels)
#define CHH   32          // ch = C/2
#define NRHO  89
#define NTH   60
#define HRB   (NRHO*NTH)  // 5340

// ---------------------------------------------------------------------------
// K0a: extract flat[n][t] = hough bin index h (h = rho*60 + t) from vote
__global__ __launch_bounds__(256) void k0_flat(const float* __restrict__ vote,
                                               int* __restrict__ flat) {
    int i = blockIdx.x * 256 + threadIdx.x;
    if (i >= NTOK * HRB) return;
    float v = vote[i];
    if (v != 0.0f) {
        int n = i / HRB, h = i % HRB;
        flat[n * NTH + (h % NTH)] = h;
    }
}

// K0b: inv[h] = 1 / max(count(h), 1)  (count = column-sum of vote)
__global__ __launch_bounds__(256) void k0_inv(const float* __restrict__ vote,
                                              float* __restrict__ inv) {
    int h = blockIdx.x * 256 + threadIdx.x;
    if (h >= HRB) return;
    float cnt = 0.0f;
    for (int n = 0; n < NTOK; ++n)
        cnt += (vote[(size_t)n * HRB + h] != 0.0f) ? 1.0f : 0.0f;
    inv[h] = 1.0f / fmaxf(cnt, 1.0f);
}

// K0c: build per-theta CSR over rho bins: perm[t][1024] tokens grouped by rho
// (stable, increasing n), rowptr[t][90] bin starts. Deterministic.
__global__ __launch_bounds__(256) void k0_csr(const int* __restrict__ flat,
                                              int* __restrict__ perm,
                                              int* __restrict__ rowptr) {
    __shared__ int rho_n[NTOK];
    __shared__ int cnt[96];
    __shared__ int base[96];
    const int tid = threadIdx.x;
    const int t = blockIdx.x;

    for (int n = tid; n < NTOK; n += 256) rho_n[n] = flat[n * NTH + t] / NTH;
    for (int i = tid; i < 96; i += 256) cnt[i] = 0;
    __syncthreads();
    for (int n = tid; n < NTOK; n += 256) atomicAdd(&cnt[rho_n[n]], 1);
    __syncthreads();
    if (tid == 0) {
        int s = 0;
        for (int r = 0; r < NRHO; ++r) { base[r] = s; s += cnt[r]; }
        base[NRHO] = s;  // == 1024
    }
    __syncthreads();
    if (tid < NRHO) {
        int p = base[tid];
        for (int n = 0; n < NTOK; ++n)
            if (rho_n[n] == tid) perm[t * NTOK + (p++)] = n;
    }
    if (tid < NRHO + 1) rowptr[t * 90 + tid] = base[tid];
}

// ---------------------------------------------------------------------------
// K1: feat = tokens @ Wt_in^T + bt_in;  y = relu(feat @ W1^T)
// M = NB*NTOK = 32768 rows. Block: 64 rows x 64 cols, 256 threads (16x16 of 4x4).
__global__ __launch_bounds__(256) void k1_feat_y(
    const float* __restrict__ tokens, const float* __restrict__ Wt_in,
    const float* __restrict__ bt_in, const float* __restrict__ W1,
    float* __restrict__ feat, float* __restrict__ y) {
    __shared__ float As[32][68];    // A^T chunk: As[kk][m]
    __shared__ float Ws[32][68];    // W^T chunk: Ws[kk][c]
    __shared__ float fs[64][68];    // feat tile [m][c]
    __shared__ float w1t[64 * 32];  // w1t[c][cc] = W1[cc][c]

    const int tid = threadIdx.x;
    const int row0 = blockIdx.x * 64;

    for (int idx = tid; idx < 64 * 32; idx += 256) {
        int cc = idx & 31, c = idx >> 5;
        w1t[c * 32 + cc] = W1[cc * 64 + c];
    }

    const int tx = tid & 15, ty = tid >> 4;
    float acc[4][4] = {};

    for (int k0 = 0; k0 < DMODEL; k0 += 32) {
        __syncthreads();
        for (int idx = tid; idx < 64 * 32; idx += 256) {
            int m = idx >> 5, kk = idx & 31;
            As[kk][m] = tokens[(size_t)(row0 + m) * DMODEL + k0 + kk];
        }
        for (int idx = tid; idx < 64 * 32; idx += 256) {
            int c = idx >> 5, kk = idx & 31;
            Ws[kk][c] = Wt_in[(size_t)c * DMODEL + k0 + kk];
        }
        __syncthreads();
        #pragma unroll
        for (int kk = 0; kk < 32; ++kk) {
            float4 av = *(const float4*)&As[kk][ty * 4];
            float4 bv = *(const float4*)&Ws[kk][tx * 4];
            float aa[4] = {av.x, av.y, av.z, av.w};
            float bb[4] = {bv.x, bv.y, bv.z, bv.w};
            #pragma unroll
            for (int i = 0; i < 4; ++i)
                #pragma unroll
                for (int j = 0; j < 4; ++j) acc[i][j] += aa[i] * bb[j];
        }
    }

    float4 bi = *(const float4*)&bt_in[tx * 4];
    #pragma unroll
    for (int i = 0; i < 4; ++i) {
        int m = ty * 4 + i;
        float4 v;
        v.x = acc[i][0] + bi.x; v.y = acc[i][1] + bi.y;
        v.z = acc[i][2] + bi.z; v.w = acc[i][3] + bi.w;
        *(float4*)&fs[m][tx * 4] = v;
        *(float4*)&feat[(size_t)(row0 + m) * CF + tx * 4] = v;
    }
    __syncthreads();

    // y = relu(fs @ W1^T): 64 m x 32 cc outputs
    const int cc = tid & 31, mb = tid >> 5;
    for (int mm = mb; mm < 64; mm += 8) {
        float s = 0.0f;
        #pragma unroll 8
        for (int c = 0; c < 64; ++c) s += fs[mm][c] * w1t[c * 32 + cc];
        y[(size_t)(row0 + mm) * CHH + cc] = fmaxf(s, 0.0f);
    }
}

// ---------------------------------------------------------------------------
// K23: fused HT scatter (as CSR gather) + (9,1) rho-conv + relu.
// One block per (b, t). Phase A: acc[c][rho] in LDS via per-bin token gather
// (no atomics). Phase B: 9-tap conv along rho from LDS, relu, write htc.
__global__ __launch_bounds__(256) void k23_ht_conv(
    const float* __restrict__ y, const int* __restrict__ perm,
    const int* __restrict__ rowptr, const float* __restrict__ inv,
    const float* __restrict__ W2, float* __restrict__ htc) {
    __shared__ float w2s[32 * 32 * 9];   // 36.8 KB
    __shared__ float ins[32 * 97];       // [c_in][rho], padded stride 97
    __shared__ int   pperm[NTOK];        // 4 KB
    __shared__ int   prow[90];

    const int tid = threadIdx.x;
    const int b = blockIdx.x / NTH, t = blockIdx.x % NTH;

    for (int i = tid; i < 32 * 32 * 9; i += 256) w2s[i] = W2[i];
    for (int i = tid; i < NTOK; i += 256) pperm[i] = perm[t * NTOK + i];
    for (int i = tid; i < 90; i += 256) prow[i] = rowptr[t * 90 + i];
    __syncthreads();

    // Phase A: per-rho gather of y, normalized by inv.
    {
        const int c = tid & 31, g = tid >> 5;  // 8 rho-groups
        const float* yb = y + (size_t)b * NTOK * CHH + c;
        for (int rho = g; rho < NRHO; rho += 8) {
            int k0 = prow[rho], k1 = prow[rho + 1];
            float s = 0.0f;
            for (int k = k0; k < k1; ++k) {
                int n = pperm[k];
                s += yb[n * CHH];
            }
            ins[c * 97 + rho] = s * inv[rho * NTH + t];
        }
    }
    __syncthreads();

    // Phase B: out[o,r] = relu( sum_{i,k} W2[o,i,k] * ins[i, r+k-4] )
    const int o0 = (tid >> 4) * 2;      // 0,2,...,30
    const int r0 = (tid & 15) * 6;      // 0,6,...,90
    float a0[6] = {}, a1[6] = {};
    for (int i = 0; i < 32; ++i) {
        float xv[14];
        #pragma unroll
        for (int j = 0; j < 14; ++j) {
            int x = r0 - 4 + j;
            xv[j] = (x >= 0 && x < NRHO) ? ins[i * 97 + x] : 0.0f;
        }
        const float* w0 = &w2s[(o0 * 32 + i) * 9];
        const float* w1 = &w2s[((o0 + 1) * 32 + i) * 9];
        #pragma unroll
        for (int k = 0; k < 9; ++k) {
            float wa = w0[k], wb = w1[k];
            #pragma unroll
            for (int j = 0; j < 6; ++j) {
                a0[j] += wa * xv[k + j];
                a1[j] += wb * xv[k + j];
            }
        }
    }
    #pragma unroll
    for (int j = 0; j < 6; ++j) {
        int r = r0 + j;
        if (r < NRHO) {
            size_t base = ((size_t)b * HRB + r * NTH + t) * CHH;
            htc[base + o0]     = fmaxf(a0[j], 0.0f);
            htc[base + o0 + 1] = fmaxf(a1[j], 0.0f);
        }
    }
}

// ---------------------------------------------------------------------------
// K4: iht gather (÷60) -> z = iht @ W3^T -> feat += z   (in-place, feat becomes g)
// One block per (b, 64-token tile).
__global__ __launch_bounds__(256) void k4_iht_z(
    const float* __restrict__ ht, const int* __restrict__ flat,
    const float* __restrict__ W3, float* __restrict__ feat) {
    __shared__ float ihts[64 * 32];
    __shared__ float w3t[32 * 64];  // w3t[c][j] = W3[j][c]
    const int tid = threadIdx.x;
    const int b = blockIdx.x >> 4;
    const int n0 = (blockIdx.x & 15) * 64;

    for (int idx = tid; idx < 2048; idx += 256) {
        int c = idx >> 6, j = idx & 63;
        w3t[idx] = W3[j * 32 + c];
    }

    const int c = tid & 31, np = tid >> 5;  // 8 tokens per pass
    for (int p = 0; p < 8; ++p) {
        int nl = p * 8 + np;
        const int* fp = &flat[(n0 + nl) * NTH];
        float s = 0.0f;
        for (int t = 0; t < NTH; ++t) {
            int h = fp[t];
            s += ht[((size_t)b * HRB + h) * CHH + c];
        }
        ihts[nl * 32 + c] = s * (1.0f / 60.0f);
    }
    __syncthreads();

    const int j = tid & 63, nb = tid >> 6;  // 4 token-groups
    for (int nn = nb; nn < 64; nn += 4) {
        float z = 0.0f;
        #pragma unroll 8
        for (int cc = 0; cc < 32; ++cc) z += ihts[nn * 32 + cc] * w3t[cc * 64 + j];
        size_t fi = ((size_t)b * NTOK + n0 + nn) * CF + j;
        feat[fi] = feat[fi] + z;
    }
}

// ---------------------------------------------------------------------------
// K5: out = g @ Wt_out^T + bt_out.  M=32768, K=64, N=768.
// Block: 64 m x 64 d, 256 threads (16x16 of 4x4), single K pass.
__global__ __launch_bounds__(256) void k5_out(
    const float* __restrict__ g, const float* __restrict__ Wt_out,
    const float* __restrict__ bt_out, float* __restrict__ out) {
    __shared__ float gs[64][68];  // gs[j][m]
    __shared__ float ws[64][68];  // ws[j][d]
    const int tid = threadIdx.x;
    const int mblk = blockIdx.x & 511, dblk = blockIdx.x >> 9;
    const int m0 = mblk * 64, d0 = dblk * 64;

    for (int idx = tid; idx < 4096; idx += 256) {
        int ml = idx >> 6, j = idx & 63;
        gs[j][ml] = g[(size_t)(m0 + ml) * CF + j];
    }
    for (int idx = tid; idx < 4096; idx += 256) {
        int dl = idx >> 6, j = idx & 63;
        ws[j][dl] = Wt_out[(size_t)(d0 + dl) * CF + j];
    }
    __syncthreads();

    const int tx = tid & 15, ty = tid >> 4;
    float acc[4][4] = {};
    #pragma unroll
    for (int j = 0; j < 64; ++j) {
        float4 av = *(const float4*)&gs[j][ty * 4];
        float4 bv = *(const float4*)&ws[j][tx * 4];
        float aa[4] = {av.x, av.y, av.z, av.w};
        float bb[4] = {bv.x, bv.y, bv.z, bv.w};
        #pragma unroll
        for (int i = 0; i < 4; ++i)
            #pragma unroll
            for (int jj = 0; jj < 4; ++jj) acc[i][jj] += aa[i] * bb[jj];
    }

    float4 bi = *(const float4*)&bt_out[d0 + tx * 4];
    #pragma unroll
    for (int i = 0; i < 4; ++i) {
        float4 v;
        v.x = acc[i][0] + bi.x; v.y = acc[i][1] + bi.y;
        v.z = acc[i][2] + bi.z; v.w = acc[i][3] + bi.w;
        *(float4*)&out[(size_t)(m0 + ty * 4 + i) * DMODEL + d0 + tx * 4] = v;
    }
}

// ---------------------------------------------------------------------------
extern "C" void kernel_launch(void* const* d_in, const int* in_sizes, int n_in,
                              void* d_out, int out_size, void* d_ws, size_t ws_size,
                              hipStream_t stream) {
    const float* tokens = (const float*)d_in[0];
    const float* vote   = (const float*)d_in[1];
    const float* Wt_in  = (const float*)d_in[2];
    const float* bt_in  = (const float*)d_in[3];
    const float* W1     = (const float*)d_in[4];
    const float* W2     = (const float*)d_in[5];
    const float* W3     = (const float*)d_in[6];
    const float* Wt_out = (const float*)d_in[7];
    const float* bt_out = (const float*)d_in[8];
    float* out = (float*)d_out;

    // workspace layout (bytes)
    char* w = (char*)d_ws;
    int*   flat   = (int*)(w);                  // 1024*60*4 = 245760
    float* inv    = (float*)(w + 245760);       // 5340*4    = 21360 -> next 267264
    int*   perm   = (int*)(w + 267264);         // 60*1024*4 = 245760 -> 513024
    int*   rowptr = (int*)(w + 513024);         // 60*90*4   = 21600  -> 534784
    float* feat   = (float*)(w + 534784);       // 32768*64*4 = 8388608 -> 8923392
    float* yb     = (float*)(w + 8923392);      // 32768*32*4 = 4194304 -> 13117696
    float* htc    = (float*)(w + 13117696);     // 32*5340*32*4 = 21872640 -> 34990336

    k0_flat<<<(NTOK * HRB + 255) / 256, 256, 0, stream>>>(vote, flat);
    k0_inv<<<(HRB + 255) / 256, 256, 0, stream>>>(vote, inv);
    k0_csr<<<NTH, 256, 0, stream>>>(flat, perm, rowptr);
    k1_feat_y<<<(NB * NTOK) / 64, 256, 0, stream>>>(tokens, Wt_in, bt_in, W1, feat, yb);
    k23_ht_conv<<<NB * NTH, 256, 0, stream>>>(yb, perm, rowptr, inv, W2, htc);
    k4_iht_z<<<NB * (NTOK / 64), 256, 0, stream>>>(htc, flat, W3, feat);
    k5_out<<<(NB * NTOK / 64) * (DMODEL / 64), 256, 0, stream>>>(feat, Wt_out, bt_out, out);
}

// Round 3
// 348.761 us; speedup vs baseline: 1.9275x; 1.3408x over previous
//
#include <hip/hip_runtime.h>

// Problem constants (fixed by reference: B=32, 32x32 tokens, DM=768, C=64, ch=32,
// theta_res=3 -> 60 thetas, rho_res=1 on 32x32 -> q=44 -> 89 rhos)
#define NB    32
#define NTOK  1024
#define DMODEL 768
#define CF    64
#define CHH   32
#define NRHO  89
#define NTH   60
#define HRB   (NRHO*NTH)  // 5340

typedef short bf16x8 __attribute__((ext_vector_type(8)));
typedef float f32x4  __attribute__((ext_vector_type(4)));
typedef unsigned int uint;
typedef unsigned short ushort;

__device__ __forceinline__ ushort f2bf(float f) {
    uint u = __float_as_uint(f);
    return (ushort)((u + 0x7FFF + ((u >> 16) & 1)) >> 16);
}

#define GLDS16(gp, lp) __builtin_amdgcn_global_load_lds( \
    (const __attribute__((address_space(1))) unsigned int*)(gp), \
    (__attribute__((address_space(3))) unsigned int*)(lp), 16, 0, 0)

// ---------------------------------------------------------------------------
// K0a: flat[n][t] = hough bin index h (h = rho*60 + t)
__global__ __launch_bounds__(256) void k0_flat(const float* __restrict__ vote,
                                               int* __restrict__ flat) {
    int i = blockIdx.x * 256 + threadIdx.x;
    if (i >= NTOK * HRB) return;
    if (vote[i] != 0.0f) {
        int n = i / HRB, h = i % HRB;
        flat[n * NTH + (h % NTH)] = h;
    }
}

// K0b: inv[h] = 1 / max(count(h), 1)
__global__ __launch_bounds__(256) void k0_inv(const float* __restrict__ vote,
                                              float* __restrict__ inv) {
    int h = blockIdx.x * 256 + threadIdx.x;
    if (h >= HRB) return;
    float cnt = 0.0f;
    for (int n = 0; n < NTOK; ++n)
        cnt += (vote[(size_t)n * HRB + h] != 0.0f) ? 1.0f : 0.0f;
    inv[h] = 1.0f / fmaxf(cnt, 1.0f);
}

// K0c: per-theta CSR over rho bins (stable order, deterministic)
__global__ __launch_bounds__(256) void k0_csr(const int* __restrict__ flat,
                                              int* __restrict__ perm,
                                              int* __restrict__ rowptr) {
    __shared__ int rho_n[NTOK];
    __shared__ int cnt[96];
    __shared__ int base[96];
    const int tid = threadIdx.x;
    const int t = blockIdx.x;

    for (int n = tid; n < NTOK; n += 256) rho_n[n] = flat[n * NTH + t] / NTH;
    for (int i = tid; i < 96; i += 256) cnt[i] = 0;
    __syncthreads();
    for (int n = tid; n < NTOK; n += 256) atomicAdd(&cnt[rho_n[n]], 1);
    __syncthreads();
    if (tid == 0) {
        int s = 0;
        for (int r = 0; r < NRHO; ++r) { base[r] = s; s += cnt[r]; }
        base[NRHO] = s;
    }
    __syncthreads();
    if (tid < NRHO) {
        int p = base[tid];
        for (int n = 0; n < NTOK; ++n)
            if (rho_n[n] == tid) perm[t * NTOK + (p++)] = n;
    }
    if (tid < NRHO + 1) rowptr[t * 90 + tid] = base[tid];
}

// ---------------------------------------------------------------------------
// K0d: Wcat = [Wt_in; W1@Wt_in] (96 x 768) -> bf16 tiled [kt12][kg8][c96][k8]
//      bcat = [bt_in; W1@bt_in]
__global__ __launch_bounds__(256) void k0_wcat(
    const float* __restrict__ Wt_in, const float* __restrict__ bt_in,
    const float* __restrict__ W1, short* __restrict__ wcat,
    float* __restrict__ bcat) {
    __shared__ float w1row[64];
    const int c = blockIdx.x;   // 0..95
    const int tid = threadIdx.x;
    if (c >= 64)
        for (int j = tid; j < 64; j += 256) w1row[j] = W1[(c - 64) * 64 + j];
    __syncthreads();
    for (int k = tid; k < DMODEL; k += 256) {
        float v;
        if (c < 64) v = Wt_in[c * DMODEL + k];
        else {
            v = 0.0f;
            for (int j = 0; j < 64; ++j) v += w1row[j] * Wt_in[j * DMODEL + k];
        }
        int kt = k >> 6, kk = k & 63;
        wcat[(((kt << 3) + (kk >> 3)) * 96 + c) * 8 + (k & 7)] = (short)f2bf(v);
    }
    if (tid == 0) {
        float bv;
        if (c < 64) bv = bt_in[c];
        else {
            bv = 0.0f;
            for (int j = 0; j < 64; ++j) bv += W1[(c - 64) * 64 + j] * bt_in[j];
        }
        bcat[c] = bv;
    }
}

// K0e: Wt_out [768][64] -> bf16 tiled [dt6][kg8][dloc128][k8]
__global__ __launch_bounds__(256) void k0_wout(const float* __restrict__ Wt_out,
                                               short* __restrict__ wout) {
    int idx = blockIdx.x * 256 + threadIdx.x;   // 6144 chunks
    if (idx >= 6144) return;
    int d = idx >> 3, kg = idx & 7;
    float4 a = *(const float4*)&Wt_out[d * 64 + kg * 8];
    float4 b = *(const float4*)&Wt_out[d * 64 + kg * 8 + 4];
    uint p0 = (uint)f2bf(a.x) | ((uint)f2bf(a.y) << 16);
    uint p1 = (uint)f2bf(a.z) | ((uint)f2bf(a.w) << 16);
    uint p2 = (uint)f2bf(b.x) | ((uint)f2bf(b.y) << 16);
    uint p3 = (uint)f2bf(b.z) | ((uint)f2bf(b.w) << 16);
    uint4 v = make_uint4(p0, p1, p2, p3);
    *(uint4*)&wout[(((d >> 7) * 8 + kg) * 128 + (d & 127)) * 8] = v;
}

// ---------------------------------------------------------------------------
// K1: MFMA bf16 GEMM: [feat | y] = tokens @ Wcat^T + bcat, y gets relu.
// M-tile 64, N=96, BK=64 (12 K-steps), 4 waves (2x2), double-buffered LDS.
__global__ __launch_bounds__(256) void k1_mfma(
    const float* __restrict__ tokens, const short* __restrict__ wcat,
    const float* __restrict__ bcat, float* __restrict__ feat,
    float* __restrict__ y) {
    __shared__ __align__(16) short Asm[2][4096];   // [kg8][m64][k8]
    __shared__ __align__(16) short Bsm[2][6144];   // [kg8][c96][k8]

    const int tid = threadIdx.x;
    const int lane = tid & 63, wave = tid >> 6;
    const int wm = wave >> 1, wn = wave & 1;
    const int row0 = blockIdx.x * 64;
    const int sm = tid >> 2, sq = tid & 3;   // staging: row, quad-group

    const float* arow = tokens + (size_t)(row0 + sm) * DMODEL;

    f32x4 acc[2][3] = {};
    float4 ta[4];

    // prologue: stage kt=0 into buffer 0
    #pragma unroll
    for (int p = 0; p < 4; ++p)
        ta[p] = *(const float4*)&arow[(sq + 4 * p) * 4];
    for (int ch = tid; ch < 768; ch += 256)
        GLDS16((const char*)wcat + ch * 16, (char*)Bsm[0] + ch * 16);
    #pragma unroll
    for (int p = 0; p < 4; ++p) {
        int q = sq + 4 * p, kg = q >> 1, half = q & 1;
        uint lo = (uint)f2bf(ta[p].x) | ((uint)f2bf(ta[p].y) << 16);
        uint hi = (uint)f2bf(ta[p].z) | ((uint)f2bf(ta[p].w) << 16);
        *(uint2*)((char*)Asm[0] + (kg * 64 + sm) * 16 + half * 8) = make_uint2(lo, hi);
    }
    __syncthreads();

    int cur = 0;
    for (int kt = 0; kt < 12; ++kt) {
        // prefetch kt+1 into the other buffer
        if (kt < 11) {
            const float* src = arow + (kt + 1) * 64;
            #pragma unroll
            for (int p = 0; p < 4; ++p)
                ta[p] = *(const float4*)&src[(sq + 4 * p) * 4];
            const char* bsrc = (const char*)wcat + (size_t)(kt + 1) * 12288;
            for (int ch = tid; ch < 768; ch += 256)
                GLDS16(bsrc + ch * 16, (char*)Bsm[cur ^ 1] + ch * 16);
        }
        // MFMA on current buffer
        const bf16x8* Ap = (const bf16x8*)Asm[cur];
        const bf16x8* Bp = (const bf16x8*)Bsm[cur];
        #pragma unroll
        for (int ks = 0; ks < 2; ++ks) {
            int kg = (lane >> 4) + ks * 4;
            bf16x8 av[2], bv[3];
            #pragma unroll
            for (int i = 0; i < 2; ++i)
                av[i] = Ap[kg * 64 + wm * 32 + i * 16 + (lane & 15)];
            #pragma unroll
            for (int j = 0; j < 3; ++j)
                bv[j] = Bp[kg * 96 + wn * 48 + j * 16 + (lane & 15)];
            #pragma unroll
            for (int i = 0; i < 2; ++i)
                #pragma unroll
                for (int j = 0; j < 3; ++j)
                    acc[i][j] = __builtin_amdgcn_mfma_f32_16x16x32_bf16(
                        av[i], bv[j], acc[i][j], 0, 0, 0);
        }
        // write prefetched A into other buffer
        if (kt < 11) {
            #pragma unroll
            for (int p = 0; p < 4; ++p) {
                int q = sq + 4 * p, kg = q >> 1, half = q & 1;
                uint lo = (uint)f2bf(ta[p].x) | ((uint)f2bf(ta[p].y) << 16);
                uint hi = (uint)f2bf(ta[p].z) | ((uint)f2bf(ta[p].w) << 16);
                *(uint2*)((char*)Asm[cur ^ 1] + (kg * 64 + sm) * 16 + half * 8) =
                    make_uint2(lo, hi);
            }
        }
        __syncthreads();
        cur ^= 1;
    }

    // epilogue: feat (cols 0-63) fp32, y = relu(cols 64-95)
    float bb[3];
    #pragma unroll
    for (int j = 0; j < 3; ++j) bb[j] = bcat[wn * 48 + j * 16 + (lane & 15)];
    #pragma unroll
    for (int i = 0; i < 2; ++i) {
        #pragma unroll
        for (int j = 0; j < 3; ++j) {
            int c = wn * 48 + j * 16 + (lane & 15);
            #pragma unroll
            for (int r = 0; r < 4; ++r) {
                int m = row0 + wm * 32 + i * 16 + ((lane >> 4) << 2) + r;
                float v = acc[i][j][r] + bb[j];
                if (c < 64) feat[(size_t)m * CF + c] = v;
                else        y[(size_t)m * CHH + (c - 64)] = fmaxf(v, 0.0f);
            }
        }
    }
}

// ---------------------------------------------------------------------------
// K23: fused HT scatter (CSR gather) + (9,1) rho-conv + relu.
__global__ __launch_bounds__(256) void k23_ht_conv(
    const float* __restrict__ y, const int* __restrict__ perm,
    const int* __restrict__ rowptr, const float* __restrict__ inv,
    const float* __restrict__ W2, float* __restrict__ htc) {
    __shared__ float w2s[32 * 32 * 9];
    __shared__ float ins[32 * 97];
    __shared__ int   pperm[NTOK];
    __shared__ int   prow[90];

    const int tid = threadIdx.x;
    const int b = blockIdx.x / NTH, t = blockIdx.x % NTH;

    for (int i = tid; i < 32 * 32 * 9; i += 256) w2s[i] = W2[i];
    for (int i = tid; i < NTOK; i += 256) pperm[i] = perm[t * NTOK + i];
    for (int i = tid; i < 90; i += 256) prow[i] = rowptr[t * 90 + i];
    __syncthreads();

    {
        const int c = tid & 31, g = tid >> 5;
        const float* yb = y + (size_t)b * NTOK * CHH + c;
        for (int rho = g; rho < NRHO; rho += 8) {
            int k0 = prow[rho], k1 = prow[rho + 1];
            float s = 0.0f;
            for (int k = k0; k < k1; ++k) s += yb[pperm[k] * CHH];
            ins[c * 97 + rho] = s * inv[rho * NTH + t];
        }
    }
    __syncthreads();

    const int o0 = (tid >> 4) * 2;
    const int r0 = (tid & 15) * 6;
    float a0[6] = {}, a1[6] = {};
    for (int i = 0; i < 32; ++i) {
        float xv[14];
        #pragma unroll
        for (int j = 0; j < 14; ++j) {
            int x = r0 - 4 + j;
            xv[j] = (x >= 0 && x < NRHO) ? ins[i * 97 + x] : 0.0f;
        }
        const float* w0 = &w2s[(o0 * 32 + i) * 9];
        const float* w1 = &w2s[((o0 + 1) * 32 + i) * 9];
        #pragma unroll
        for (int k = 0; k < 9; ++k) {
            float wa = w0[k], wb = w1[k];
            #pragma unroll
            for (int j = 0; j < 6; ++j) {
                a0[j] += wa * xv[k + j];
                a1[j] += wb * xv[k + j];
            }
        }
    }
    #pragma unroll
    for (int j = 0; j < 6; ++j) {
        int r = r0 + j;
        if (r < NRHO) {
            size_t base = ((size_t)b * HRB + r * NTH + t) * CHH;
            htc[base + o0]     = fmaxf(a0[j], 0.0f);
            htc[base + o0 + 1] = fmaxf(a1[j], 0.0f);
        }
    }
}

// ---------------------------------------------------------------------------
// K4: iht gather (/60) -> z = iht @ W3^T -> g = bf16(feat + z) in k5 tiled layout
__global__ __launch_bounds__(256) void k4_iht_z(
    const float* __restrict__ ht, const int* __restrict__ flat,
    const float* __restrict__ W3, const float* __restrict__ feat,
    short* __restrict__ g) {
    __shared__ float ihts[64 * 32];
    __shared__ float w3t[32 * 64];
    __shared__ __align__(16) ushort gs16[64 * 88];
    const int tid = threadIdx.x;
    const int b = blockIdx.x >> 4;
    const int n0 = (blockIdx.x & 15) * 64;

    for (int idx = tid; idx < 2048; idx += 256) {
        int c = idx >> 6, j = idx & 63;
        w3t[idx] = W3[j * 32 + c];
    }

    const int c = tid & 31, np = tid >> 5;
    for (int p = 0; p < 8; ++p) {
        int nl = p * 8 + np;
        const int* fp = &flat[(n0 + nl) * NTH];
        float s = 0.0f;
        for (int t = 0; t < NTH; ++t)
            s += ht[((size_t)b * HRB + fp[t]) * CHH + c];
        ihts[nl * 32 + c] = s * (1.0f / 60.0f);
    }
    __syncthreads();

    const int j = tid & 63, nb = tid >> 6;
    for (int nn = nb; nn < 64; nn += 4) {
        float z = 0.0f;
        #pragma unroll 8
        for (int cc = 0; cc < 32; ++cc) z += ihts[nn * 32 + cc] * w3t[cc * 64 + j];
        float v = feat[((size_t)b * NTOK + n0 + nn) * CF + j] + z;
        gs16[nn * 88 + j] = f2bf(v);
    }
    __syncthreads();

    // write 16B chunks into g tiled [mt][kg8][mloc128][k8]
    for (int idx = tid; idx < 512; idx += 256) {
        int kg = idx >> 6, nnl = idx & 63;
        bf16x8 frag = *(const bf16x8*)&gs16[nnl * 88 + kg * 8];
        int m = b * NTOK + n0 + nnl;
        int mt = m >> 7, mloc = m & 127;
        *(bf16x8*)&g[((mt * 8 + kg) * 128 + mloc) * 8] = frag;
    }
}

// ---------------------------------------------------------------------------
// K5: MFMA bf16 GEMM: out = g @ Wt_out^T + bt_out. M-tile 128 x N-tile 128, K=64.
__global__ __launch_bounds__(256) void k5_mfma(
    const short* __restrict__ g, const short* __restrict__ wout,
    const float* __restrict__ bt_out, float* __restrict__ out) {
    __shared__ __align__(16) short Asm[8192];   // [kg8][m128][k8]
    __shared__ __align__(16) short Bsm[8192];   // [kg8][d128][k8]
    const int tid = threadIdx.x;
    const int lane = tid & 63, wave = tid >> 6;
    const int wm = wave >> 1, wn = wave & 1;
    const int mb = blockIdx.x / 6, db = blockIdx.x % 6;

    for (int ch = tid; ch < 1024; ch += 256) {
        GLDS16((const char*)g + (size_t)mb * 16384 + ch * 16, (char*)Asm + ch * 16);
        GLDS16((const char*)wout + (size_t)db * 16384 + ch * 16, (char*)Bsm + ch * 16);
    }
    __syncthreads();

    f32x4 acc[4][4] = {};
    const bf16x8* Ap = (const bf16x8*)Asm;
    const bf16x8* Bp = (const bf16x8*)Bsm;
    #pragma unroll
    for (int ks = 0; ks < 2; ++ks) {
        int kg = (lane >> 4) + ks * 4;
        bf16x8 av[4], bv[4];
        #pragma unroll
        for (int i = 0; i < 4; ++i)
            av[i] = Ap[kg * 128 + wm * 64 + i * 16 + (lane & 15)];
        #pragma unroll
        for (int j = 0; j < 4; ++j)
            bv[j] = Bp[kg * 128 + wn * 64 + j * 16 + (lane & 15)];
        #pragma unroll
        for (int i = 0; i < 4; ++i)
            #pragma unroll
            for (int j = 0; j < 4; ++j)
                acc[i][j] = __builtin_amdgcn_mfma_f32_16x16x32_bf16(
                    av[i], bv[j], acc[i][j], 0, 0, 0);
    }

    const int d0 = db * 128 + wn * 64 + (lane & 15);
    float bb[4];
    #pragma unroll
    for (int j = 0; j < 4; ++j) bb[j] = bt_out[d0 + j * 16];
    const int mrow = mb * 128 + wm * 64 + ((lane >> 4) << 2);
    #pragma unroll
    for (int i = 0; i < 4; ++i)
        #pragma unroll
        for (int r = 0; r < 4; ++r)
            #pragma unroll
            for (int j = 0; j < 4; ++j)
                out[(size_t)(mrow + i * 16 + r) * DMODEL + d0 + j * 16] =
                    acc[i][j][r] + bb[j];
}

// ---------------------------------------------------------------------------
extern "C" void kernel_launch(void* const* d_in, const int* in_sizes, int n_in,
                              void* d_out, int out_size, void* d_ws, size_t ws_size,
                              hipStream_t stream) {
    const float* tokens = (const float*)d_in[0];
    const float* vote   = (const float*)d_in[1];
    const float* Wt_in  = (const float*)d_in[2];
    const float* bt_in  = (const float*)d_in[3];
    const float* W1     = (const float*)d_in[4];
    const float* W2     = (const float*)d_in[5];
    const float* W3     = (const float*)d_in[6];
    const float* Wt_out = (const float*)d_in[7];
    const float* bt_out = (const float*)d_in[8];
    float* out = (float*)d_out;

    // workspace layout (bytes, 16-aligned)
    char* w = (char*)d_ws;
    int*   flat   = (int*)(w);                     // 245760
    float* inv    = (float*)(w + 245760);          // 21360 -> 267136
    int*   perm   = (int*)(w + 267136);            // 245760 -> 512896
    int*   rowptr = (int*)(w + 512896);            // 21600 -> 534496
    short* wcat   = (short*)(w + 534496);          // 147456 -> 681952
    float* bcat   = (float*)(w + 681952);          // 384 -> 682336
    short* wout   = (short*)(w + 682336);          // 98304 -> 780640
    float* feat   = (float*)(w + 780640);          // 8388608 -> 9169248
    float* yb     = (float*)(w + 9169248);         // 4194304 -> 13363552
    short* g      = (short*)(w + 9169248);         // aliases yb (y dead after k23)
    float* htc    = (float*)(w + 13363552);        // 21872640 -> 35236192

    k0_flat<<<(NTOK * HRB + 255) / 256, 256, 0, stream>>>(vote, flat);
    k0_inv<<<(HRB + 255) / 256, 256, 0, stream>>>(vote, inv);
    k0_csr<<<NTH, 256, 0, stream>>>(flat, perm, rowptr);
    k0_wcat<<<96, 256, 0, stream>>>(Wt_in, bt_in, W1, wcat, bcat);
    k0_wout<<<24, 256, 0, stream>>>(Wt_out, wout);
    k1_mfma<<<NB * NTOK / 64, 256, 0, stream>>>(tokens, wcat, bcat, feat, yb);
    k23_ht_conv<<<NB * NTH, 256, 0, stream>>>(yb, perm, rowptr, inv, W2, htc);
    k4_iht_z<<<NB * (NTOK / 64), 256, 0, stream>>>(htc, flat, W3, feat, g);
    k5_mfma<<<(NB * NTOK / 128) * (DMODEL / 128), 256, 0, stream>>>(g, wout, bt_out, out);
}

// Round 4
// 209.361 us; speedup vs baseline: 3.2108x; 1.6658x over previous
//
#include <hip/hip_runtime.h>

// Problem constants (fixed by reference: B=32, 32x32 tokens, DM=768, C=64, ch=32,
// theta_res=3 -> 60 thetas, rho_res=1 on 32x32 -> q=44 -> 89 rhos)
#define NB    32
#define NTOK  1024
#define DMODEL 768
#define CF    64
#define CHH   32
#define NRHO  89
#define NTH   60
#define HRB   (NRHO*NTH)  // 5340

typedef short bf16x8 __attribute__((ext_vector_type(8)));
typedef float f32x4  __attribute__((ext_vector_type(4)));
typedef unsigned int uint;
typedef unsigned short ushort;

__device__ __forceinline__ ushort f2bf(float f) {
    uint u = __float_as_uint(f);
    return (ushort)((u + 0x7FFF + ((u >> 16) & 1)) >> 16);
}

#define GLDS16(gp, lp) __builtin_amdgcn_global_load_lds( \
    (const __attribute__((address_space(1))) unsigned int*)(gp), \
    (__attribute__((address_space(3))) unsigned int*)(lp), 16, 0, 0)

// ---------------------------------------------------------------------------
// K0a: flat[n][t] = hough bin index h (h = rho*60 + t); cnti[h] += 1 (int atomics,
// deterministic). Coalesced single scan of vote.
__global__ __launch_bounds__(256) void k0_flat(const float* __restrict__ vote,
                                               int* __restrict__ flat,
                                               int* __restrict__ cnti) {
    int i = blockIdx.x * 256 + threadIdx.x;
    if (i >= NTOK * HRB) return;
    if (vote[i] != 0.0f) {
        int n = i / HRB, h = i % HRB;
        flat[n * NTH + (h % NTH)] = h;
        atomicAdd(&cnti[h], 1);
    }
}

// K0b: inv[h] = 1 / max(count,1)
__global__ __launch_bounds__(256) void k0_inv(const int* __restrict__ cnti,
                                              float* __restrict__ inv) {
    int h = blockIdx.x * 256 + threadIdx.x;
    if (h >= HRB) return;
    inv[h] = 1.0f / fmaxf((float)cnti[h], 1.0f);
}

// K0c: per-theta CSR over rho bins (stable order, deterministic)
__global__ __launch_bounds__(256) void k0_csr(const int* __restrict__ flat,
                                              int* __restrict__ perm,
                                              int* __restrict__ rowptr) {
    __shared__ int rho_n[NTOK];
    __shared__ int cnt[96];
    __shared__ int base[96];
    const int tid = threadIdx.x;
    const int t = blockIdx.x;

    for (int n = tid; n < NTOK; n += 256) rho_n[n] = flat[n * NTH + t] / NTH;
    for (int i = tid; i < 96; i += 256) cnt[i] = 0;
    __syncthreads();
    for (int n = tid; n < NTOK; n += 256) atomicAdd(&cnt[rho_n[n]], 1);
    __syncthreads();
    if (tid == 0) {
        int s = 0;
        for (int r = 0; r < NRHO; ++r) { base[r] = s; s += cnt[r]; }
        base[NRHO] = s;
    }
    __syncthreads();
    if (tid < NRHO) {
        int p = base[tid];
        for (int n = 0; n < NTOK; ++n)
            if (rho_n[n] == tid) perm[t * NTOK + (p++)] = n;
    }
    if (tid < NRHO + 1) rowptr[t * 90 + tid] = base[tid];
}

// ---------------------------------------------------------------------------
// K0d: Wcat = [Wt_in; W1@Wt_in] (96 x 768) -> bf16 tiled [kt12][kg8][c96][k8]
__global__ __launch_bounds__(256) void k0_wcat(
    const float* __restrict__ Wt_in, const float* __restrict__ bt_in,
    const float* __restrict__ W1, short* __restrict__ wcat,
    float* __restrict__ bcat) {
    __shared__ float w1row[64];
    const int c = blockIdx.x;   // 0..95
    const int tid = threadIdx.x;
    if (c >= 64)
        for (int j = tid; j < 64; j += 256) w1row[j] = W1[(c - 64) * 64 + j];
    __syncthreads();
    for (int k = tid; k < DMODEL; k += 256) {
        float v;
        if (c < 64) v = Wt_in[c * DMODEL + k];
        else {
            v = 0.0f;
            for (int j = 0; j < 64; ++j) v += w1row[j] * Wt_in[j * DMODEL + k];
        }
        int kt = k >> 6, kk = k & 63;
        wcat[(((kt << 3) + (kk >> 3)) * 96 + c) * 8 + (k & 7)] = (short)f2bf(v);
    }
    if (tid == 0) {
        float bv;
        if (c < 64) bv = bt_in[c];
        else {
            bv = 0.0f;
            for (int j = 0; j < 64; ++j) bv += W1[(c - 64) * 64 + j] * bt_in[j];
        }
        bcat[c] = bv;
    }
}

// K0e: Wt_out [768][64] -> bf16 tiled [dt6][kg8][dloc128][k8]
__global__ __launch_bounds__(256) void k0_wout(const float* __restrict__ Wt_out,
                                               short* __restrict__ wout) {
    int idx = blockIdx.x * 256 + threadIdx.x;   // 6144 chunks
    if (idx >= 6144) return;
    int d = idx >> 3, kg = idx & 7;
    float4 a = *(const float4*)&Wt_out[d * 64 + kg * 8];
    float4 b = *(const float4*)&Wt_out[d * 64 + kg * 8 + 4];
    uint p0 = (uint)f2bf(a.x) | ((uint)f2bf(a.y) << 16);
    uint p1 = (uint)f2bf(a.z) | ((uint)f2bf(a.w) << 16);
    uint p2 = (uint)f2bf(b.x) | ((uint)f2bf(b.y) << 16);
    uint p3 = (uint)f2bf(b.z) | ((uint)f2bf(b.w) << 16);
    uint4 v = make_uint4(p0, p1, p2, p3);
    *(uint4*)&wout[(((d >> 7) * 8 + kg) * 128 + (d & 127)) * 8] = v;
}

// K0f: W2 [32 o][32 i][9 k] -> bf16 MFMA A-frags: w2t[((k*2+wm)*64+lane)*8+e]
//      where o = wm*16 + (lane&15), i = (lane>>4)*8 + e
__global__ __launch_bounds__(256) void k0_w2t(const float* __restrict__ W2,
                                              short* __restrict__ w2t) {
    int idx = blockIdx.x * 256 + threadIdx.x;   // 9216 total
    if (idx >= 9216) return;
    int e = idx & 7, ln = (idx >> 3) & 63, wm = (idx >> 9) & 1, k = idx >> 10;
    int o = wm * 16 + (ln & 15), i = ((ln >> 4) << 3) + e;
    w2t[idx] = (short)f2bf(W2[(o * 32 + i) * 9 + k]);
}

// ---------------------------------------------------------------------------
// K1: MFMA bf16 GEMM: [feat | y] = tokens @ Wcat^T + bcat, y gets relu.
__global__ __launch_bounds__(256) void k1_mfma(
    const float* __restrict__ tokens, const short* __restrict__ wcat,
    const float* __restrict__ bcat, float* __restrict__ feat,
    float* __restrict__ y) {
    __shared__ __align__(16) short Asm[2][4096];   // [kg8][m64][k8]
    __shared__ __align__(16) short Bsm[2][6144];   // [kg8][c96][k8]

    const int tid = threadIdx.x;
    const int lane = tid & 63, wave = tid >> 6;
    const int wm = wave >> 1, wn = wave & 1;
    const int row0 = blockIdx.x * 64;
    const int sm = tid >> 2, sq = tid & 3;

    const float* arow = tokens + (size_t)(row0 + sm) * DMODEL;

    f32x4 acc[2][3] = {};
    float4 ta[4];

    #pragma unroll
    for (int p = 0; p < 4; ++p)
        ta[p] = *(const float4*)&arow[(sq + 4 * p) * 4];
    for (int ch = tid; ch < 768; ch += 256)
        GLDS16((const char*)wcat + ch * 16, (char*)Bsm[0] + ch * 16);
    #pragma unroll
    for (int p = 0; p < 4; ++p) {
        int q = sq + 4 * p, kg = q >> 1, half = q & 1;
        uint lo = (uint)f2bf(ta[p].x) | ((uint)f2bf(ta[p].y) << 16);
        uint hi = (uint)f2bf(ta[p].z) | ((uint)f2bf(ta[p].w) << 16);
        *(uint2*)((char*)Asm[0] + (kg * 64 + sm) * 16 + half * 8) = make_uint2(lo, hi);
    }
    __syncthreads();

    int cur = 0;
    for (int kt = 0; kt < 12; ++kt) {
        if (kt < 11) {
            const float* src = arow + (kt + 1) * 64;
            #pragma unroll
            for (int p = 0; p < 4; ++p)
                ta[p] = *(const float4*)&src[(sq + 4 * p) * 4];
            const char* bsrc = (const char*)wcat + (size_t)(kt + 1) * 12288;
            for (int ch = tid; ch < 768; ch += 256)
                GLDS16(bsrc + ch * 16, (char*)Bsm[cur ^ 1] + ch * 16);
        }
        const bf16x8* Ap = (const bf16x8*)Asm[cur];
        const bf16x8* Bp = (const bf16x8*)Bsm[cur];
        #pragma unroll
        for (int ks = 0; ks < 2; ++ks) {
            int kg = (lane >> 4) + ks * 4;
            bf16x8 av[2], bv[3];
            #pragma unroll
            for (int i = 0; i < 2; ++i)
                av[i] = Ap[kg * 64 + wm * 32 + i * 16 + (lane & 15)];
            #pragma unroll
            for (int j = 0; j < 3; ++j)
                bv[j] = Bp[kg * 96 + wn * 48 + j * 16 + (lane & 15)];
            #pragma unroll
            for (int i = 0; i < 2; ++i)
                #pragma unroll
                for (int j = 0; j < 3; ++j)
                    acc[i][j] = __builtin_amdgcn_mfma_f32_16x16x32_bf16(
                        av[i], bv[j], acc[i][j], 0, 0, 0);
        }
        if (kt < 11) {
            #pragma unroll
            for (int p = 0; p < 4; ++p) {
                int q = sq + 4 * p, kg = q >> 1, half = q & 1;
                uint lo = (uint)f2bf(ta[p].x) | ((uint)f2bf(ta[p].y) << 16);
                uint hi = (uint)f2bf(ta[p].z) | ((uint)f2bf(ta[p].w) << 16);
                *(uint2*)((char*)Asm[cur ^ 1] + (kg * 64 + sm) * 16 + half * 8) =
                    make_uint2(lo, hi);
            }
        }
        __syncthreads();
        cur ^= 1;
    }

    float bb[3];
    #pragma unroll
    for (int j = 0; j < 3; ++j) bb[j] = bcat[wn * 48 + j * 16 + (lane & 15)];
    #pragma unroll
    for (int i = 0; i < 2; ++i) {
        #pragma unroll
        for (int j = 0; j < 3; ++j) {
            int c = wn * 48 + j * 16 + (lane & 15);
            #pragma unroll
            for (int r = 0; r < 4; ++r) {
                int m = row0 + wm * 32 + i * 16 + ((lane >> 4) << 2) + r;
                float v = acc[i][j][r] + bb[j];
                if (c < 64) feat[(size_t)m * CF + c] = v;
                else        y[(size_t)m * CHH + (c - 64)] = fmaxf(v, 0.0f);
            }
        }
    }
}

// ---------------------------------------------------------------------------
// K23: fused HT (CSR gather, float4-vectorized) + (9,1) rho-conv via MFMA.
// insp[104][40] bf16: insp[r+4][i] = ins[i][r] (zero-padded rho). Per wave:
// 9 taps in registers (A-frags), 3 n-frags x 9 MFMAs. Output staged in outt
// then streamed 128B-coalesced to htc.
__global__ __launch_bounds__(256) void k23_ht_conv(
    const float* __restrict__ y, const int* __restrict__ perm,
    const int* __restrict__ rowptr, const float* __restrict__ inv,
    const short* __restrict__ w2t, float* __restrict__ htc) {
    __shared__ int pperm[NTOK];                      // 4 KB
    __shared__ int prow[90];
    __shared__ __align__(16) short insp[104 * 40];   // 8.3 KB bf16, stride 40
    __shared__ float outt[NRHO * 33];                // 11.7 KB

    const int tid = threadIdx.x;
    const int lane = tid & 63, wave = tid >> 6;
    const int wm = wave >> 1, wn = wave & 1;
    const int b = blockIdx.x / NTH, t = blockIdx.x % NTH;

    // W2 tap A-frags -> registers (coalesced, L2-hot)
    bf16x8 av[9];
    #pragma unroll
    for (int k = 0; k < 9; ++k)
        av[k] = *(const bf16x8*)&w2t[(((k * 2 + wm) * 64) + lane) * 8];

    for (int i = tid; i < NTOK; i += 256) pperm[i] = perm[t * NTOK + i];
    for (int i = tid; i < 90; i += 256) prow[i] = rowptr[t * 90 + i];
    for (int i = tid; i < 104 * 40 / 2; i += 256) ((uint*)insp)[i] = 0;
    __syncthreads();

    // Phase A: per-rho gather of y (8 lanes x float4 per token)
    {
        const int c0 = (tid & 7) * 4, g = tid >> 3;   // 32 rho groups
        const float* yb = y + (size_t)b * NTOK * CHH;
        for (int rho = g; rho < NRHO; rho += 32) {
            int k0 = prow[rho], k1 = prow[rho + 1];
            float4 s = {0.0f, 0.0f, 0.0f, 0.0f};
            for (int k = k0; k < k1; ++k) {
                int n = pperm[k];
                float4 v = *(const float4*)&yb[n * CHH + c0];
                s.x += v.x; s.y += v.y; s.z += v.z; s.w += v.w;
            }
            float iv = inv[rho * NTH + t];
            uint p0 = (uint)f2bf(s.x * iv) | ((uint)f2bf(s.y * iv) << 16);
            uint p1 = (uint)f2bf(s.z * iv) | ((uint)f2bf(s.w * iv) << 16);
            *(uint2*)&insp[(rho + 4) * 40 + c0] = make_uint2(p0, p1);
        }
    }
    __syncthreads();

    // Phase B: conv as 27 MFMAs/wave: out[o][r] = sum_k W2k[o][i] @ insp[r+k][i]
    f32x4 acc[3] = {};
    #pragma unroll
    for (int f = 0; f < 3; ++f) {
        int Rn = wn * 48 + f * 16 + (lane & 15);
        #pragma unroll
        for (int k = 0; k < 9; ++k) {
            bf16x8 bv = *(const bf16x8*)&insp[(Rn + k) * 40 + ((lane >> 4) << 3)];
            acc[f] = __builtin_amdgcn_mfma_f32_16x16x32_bf16(av[k], bv, acc[f], 0, 0, 0);
        }
    }
    #pragma unroll
    for (int f = 0; f < 3; ++f) {
        int r = wn * 48 + f * 16 + (lane & 15);
        if (r < NRHO) {
            #pragma unroll
            for (int reg = 0; reg < 4; ++reg) {
                int o = wm * 16 + ((lane >> 4) << 2) + reg;
                outt[r * 33 + o] = fmaxf(acc[f][reg], 0.0f);
            }
        }
    }
    __syncthreads();

    // stream to htc: 128B rows (32 c) coalesced
    {
        const int c = tid & 31, rw = tid >> 5;
        for (int r = rw; r < NRHO; r += 8)
            htc[((size_t)b * HRB + r * NTH + t) * CHH + c] = outt[r * 33 + c];
    }
}

// ---------------------------------------------------------------------------
// K4: iht gather (/60, float4-vectorized) -> z = iht @ W3^T -> g = bf16(feat+z)
__global__ __launch_bounds__(256) void k4_iht_z(
    const float* __restrict__ ht, const int* __restrict__ flat,
    const float* __restrict__ W3, const float* __restrict__ feat,
    short* __restrict__ g) {
    __shared__ float ihts[64 * 32];
    __shared__ float w3t[32 * 64];
    __shared__ __align__(16) ushort gs16[64 * 88];
    const int tid = threadIdx.x;
    const int b = blockIdx.x >> 4;
    const int n0 = (blockIdx.x & 15) * 64;

    for (int idx = tid; idx < 2048; idx += 256) {
        int c = idx >> 6, j = idx & 63;
        w3t[idx] = W3[j * 32 + c];
    }

    {
        const int c0 = (tid & 7) * 4, np = tid >> 3;   // 32 token groups x 2
        for (int p = 0; p < 2; ++p) {
            int nl = np * 2 + p;
            const int* fp = &flat[(n0 + nl) * NTH];
            float4 s = {0.0f, 0.0f, 0.0f, 0.0f};
            for (int t = 0; t < NTH; ++t) {
                int h = fp[t];
                float4 v = *(const float4*)&ht[((size_t)b * HRB + h) * CHH + c0];
                s.x += v.x; s.y += v.y; s.z += v.z; s.w += v.w;
            }
            float4 r;
            r.x = s.x * (1.0f / 60.0f); r.y = s.y * (1.0f / 60.0f);
            r.z = s.z * (1.0f / 60.0f); r.w = s.w * (1.0f / 60.0f);
            *(float4*)&ihts[nl * 32 + c0] = r;
        }
    }
    __syncthreads();

    const int j = tid & 63, nb = tid >> 6;
    for (int nn = nb; nn < 64; nn += 4) {
        float z = 0.0f;
        #pragma unroll 8
        for (int cc = 0; cc < 32; ++cc) z += ihts[nn * 32 + cc] * w3t[cc * 64 + j];
        float v = feat[((size_t)b * NTOK + n0 + nn) * CF + j] + z;
        gs16[nn * 88 + j] = f2bf(v);
    }
    __syncthreads();

    for (int idx = tid; idx < 512; idx += 256) {
        int kg = idx >> 6, nnl = idx & 63;
        bf16x8 frag = *(const bf16x8*)&gs16[nnl * 88 + kg * 8];
        int m = b * NTOK + n0 + nnl;
        int mt = m >> 7, mloc = m & 127;
        *(bf16x8*)&g[((mt * 8 + kg) * 128 + mloc) * 8] = frag;
    }
}

// ---------------------------------------------------------------------------
// K5: MFMA bf16 GEMM: out = g @ Wt_out^T + bt_out. 128x128 tile, K=64.
__global__ __launch_bounds__(256) void k5_mfma(
    const short* __restrict__ g, const short* __restrict__ wout,
    const float* __restrict__ bt_out, float* __restrict__ out) {
    __shared__ __align__(16) short Asm[8192];
    __shared__ __align__(16) short Bsm[8192];
    const int tid = threadIdx.x;
    const int lane = tid & 63, wave = tid >> 6;
    const int wm = wave >> 1, wn = wave & 1;
    const int mb = blockIdx.x / 6, db = blockIdx.x % 6;

    for (int ch = tid; ch < 1024; ch += 256) {
        GLDS16((const char*)g + (size_t)mb * 16384 + ch * 16, (char*)Asm + ch * 16);
        GLDS16((const char*)wout + (size_t)db * 16384 + ch * 16, (char*)Bsm + ch * 16);
    }
    __syncthreads();

    f32x4 acc[4][4] = {};
    const bf16x8* Ap = (const bf16x8*)Asm;
    const bf16x8* Bp = (const bf16x8*)Bsm;
    #pragma unroll
    for (int ks = 0; ks < 2; ++ks) {
        int kg = (lane >> 4) + ks * 4;
        bf16x8 av[4], bv[4];
        #pragma unroll
        for (int i = 0; i < 4; ++i)
            av[i] = Ap[kg * 128 + wm * 64 + i * 16 + (lane & 15)];
        #pragma unroll
        for (int j = 0; j < 4; ++j)
            bv[j] = Bp[kg * 128 + wn * 64 + j * 16 + (lane & 15)];
        #pragma unroll
        for (int i = 0; i < 4; ++i)
            #pragma unroll
            for (int j = 0; j < 4; ++j)
                acc[i][j] = __builtin_amdgcn_mfma_f32_16x16x32_bf16(
                    av[i], bv[j], acc[i][j], 0, 0, 0);
    }

    const int d0 = db * 128 + wn * 64 + (lane & 15);
    float bb[4];
    #pragma unroll
    for (int j = 0; j < 4; ++j) bb[j] = bt_out[d0 + j * 16];
    const int mrow = mb * 128 + wm * 64 + ((lane >> 4) << 2);
    #pragma unroll
    for (int i = 0; i < 4; ++i)
        #pragma unroll
        for (int r = 0; r < 4; ++r)
            #pragma unroll
            for (int j = 0; j < 4; ++j)
                out[(size_t)(mrow + i * 16 + r) * DMODEL + d0 + j * 16] =
                    acc[i][j][r] + bb[j];
}

// ---------------------------------------------------------------------------
extern "C" void kernel_launch(void* const* d_in, const int* in_sizes, int n_in,
                              void* d_out, int out_size, void* d_ws, size_t ws_size,
                              hipStream_t stream) {
    const float* tokens = (const float*)d_in[0];
    const float* vote   = (const float*)d_in[1];
    const float* Wt_in  = (const float*)d_in[2];
    const float* bt_in  = (const float*)d_in[3];
    const float* W1     = (const float*)d_in[4];
    const float* W2     = (const float*)d_in[5];
    const float* W3     = (const float*)d_in[6];
    const float* Wt_out = (const float*)d_in[7];
    const float* bt_out = (const float*)d_in[8];
    float* out = (float*)d_out;

    // workspace layout (bytes, all offsets 16-aligned)
    char* w = (char*)d_ws;
    int*   flat   = (int*)(w);                 // 245760 -> 245760
    int*   cnti   = (int*)(w + 245760);        // 21360  -> 267120
    float* inv    = (float*)(w + 267120);      // 21360  -> 288480
    int*   perm   = (int*)(w + 288480);        // 245760 -> 534240
    int*   rowptr = (int*)(w + 534240);        // 21600  -> 555840
    short* wcat   = (short*)(w + 555840);      // 147456 -> 703296
    float* bcat   = (float*)(w + 703296);      // 384    -> 703680
    short* wout   = (short*)(w + 703680);      // 98304  -> 801984
    short* w2t    = (short*)(w + 801984);      // 18432  -> 820416
    float* feat   = (float*)(w + 820416);      // 8388608 -> 9209024
    float* yb     = (float*)(w + 9209024);     // 4194304 -> 13403328
    short* g      = (short*)(w + 9209024);     // aliases yb (y dead after k23)
    float* htc    = (float*)(w + 13403328);    // 21872640 -> 35275968

    hipMemsetAsync(cnti, 0, HRB * sizeof(int), stream);
    k0_flat<<<(NTOK * HRB + 255) / 256, 256, 0, stream>>>(vote, flat, cnti);
    k0_inv<<<(HRB + 255) / 256, 256, 0, stream>>>(cnti, inv);
    k0_csr<<<NTH, 256, 0, stream>>>(flat, perm, rowptr);
    k0_wcat<<<96, 256, 0, stream>>>(Wt_in, bt_in, W1, wcat, bcat);
    k0_wout<<<24, 256, 0, stream>>>(Wt_out, wout);
    k0_w2t<<<36, 256, 0, stream>>>(W2, w2t);
    k1_mfma<<<NB * NTOK / 64, 256, 0, stream>>>(tokens, wcat, bcat, feat, yb);
    k23_ht_conv<<<NB * NTH, 256, 0, stream>>>(yb, perm, rowptr, inv, w2t, htc);
    k4_iht_z<<<NB * (NTOK / 64), 256, 0, stream>>>(htc, flat, W3, feat, g);
    k5_mfma<<<(NB * NTOK / 128) * (DMODEL / 128), 256, 0, stream>>>(g, wout, bt_out, out);
}

// Round 5
// 148.275 us; speedup vs baseline: 4.5336x; 1.4120x over previous
//
#include <hip/hip_runtime.h>

// Problem constants (fixed by reference: B=32, 32x32 tokens, DM=768, C=64, ch=32,
// theta_res=3 -> 60 thetas, rho_res=1 on 32x32 -> q=44 -> 89 rhos)
#define NB    32
#define NTOK  1024
#define DMODEL 768
#define CF    64
#define CHH   32
#define NRHO  89
#define NTH   60
#define HRB   (NRHO*NTH)  // 5340

typedef short bf16x8 __attribute__((ext_vector_type(8)));
typedef float f32x4  __attribute__((ext_vector_type(4)));
typedef unsigned int uint;
typedef unsigned short ushort;

__device__ __forceinline__ ushort f2bf(float f) {
    uint u = __float_as_uint(f);
    return (ushort)((u + 0x7FFF + ((u >> 16) & 1)) >> 16);
}

#define GLDS16(gp, lp) __builtin_amdgcn_global_load_lds( \
    (const __attribute__((address_space(1))) unsigned int*)(gp), \
    (__attribute__((address_space(3))) unsigned int*)(lp), 16, 0, 0)

// ---------------------------------------------------------------------------
// K0a: flat[n][t] = hough bin h; flatT[t][n] = rho (coalesced layout for CSR);
// cnti[h] += 1 (int atomics, deterministic counts).
__global__ __launch_bounds__(256) void k0_flat(const float* __restrict__ vote,
                                               int* __restrict__ flat,
                                               int* __restrict__ flatT,
                                               int* __restrict__ cnti) {
    int i = blockIdx.x * 256 + threadIdx.x;
    if (i >= NTOK * HRB) return;
    if (vote[i] != 0.0f) {
        int n = i / HRB, h = i % HRB;
        int t = h % NTH;
        flat[n * NTH + t] = h;
        flatT[t * NTOK + n] = h / NTH;
        atomicAdd(&cnti[h], 1);
    }
}

// K0b: inv[h] = 1 / max(count,1)
__global__ __launch_bounds__(256) void k0_inv(const int* __restrict__ cnti,
                                              float* __restrict__ inv) {
    int h = blockIdx.x * 256 + threadIdx.x;
    if (h >= HRB) return;
    inv[h] = 1.0f / fmaxf((float)cnti[h], 1.0f);
}

// K0c: per-theta CSR via parallel counting sort (deterministic, stable (rho,n)).
// 64 chunks x 16 tokens: LDS histogram -> per-rho chunk scan -> base scan -> fill.
__global__ __launch_bounds__(256) void k0_csr(const int* __restrict__ flatT,
                                              int* __restrict__ perm,
                                              int* __restrict__ rowptr) {
    __shared__ int rho_n[NTOK];        // 4 KB
    __shared__ int cnt2[64 * 90];      // 23 KB chunk histograms / cursors
    __shared__ int tot[96];
    __shared__ int base[96];
    const int tid = threadIdx.x;
    const int t = blockIdx.x;

    for (int n = tid; n < NTOK; n += 256) rho_n[n] = flatT[t * NTOK + n];
    for (int i = tid; i < 64 * 90; i += 256) cnt2[i] = 0;
    __syncthreads();
    for (int n = tid; n < NTOK; n += 256)
        atomicAdd(&cnt2[(n >> 4) * 90 + rho_n[n]], 1);
    __syncthreads();
    if (tid < NRHO) {   // exclusive scan over chunks for this rho
        int s = 0;
        for (int c = 0; c < 64; ++c) {
            int v = cnt2[c * 90 + tid];
            cnt2[c * 90 + tid] = s;
            s += v;
        }
        tot[tid] = s;
    }
    __syncthreads();
    if (tid == 0) {
        int s = 0;
        for (int r = 0; r < NRHO; ++r) { base[r] = s; s += tot[r]; }
        base[NRHO] = s;   // 1024
    }
    __syncthreads();
    if (tid < NRHO + 1) rowptr[t * 90 + tid] = base[tid];
    if (tid < 64) {   // fill: one thread per chunk, private cursors
        const int c = tid;
        #pragma unroll
        for (int j = 0; j < 16; ++j) {
            int n = c * 16 + j;
            int r = rho_n[n];
            int cur = cnt2[c * 90 + r];
            cnt2[c * 90 + r] = cur + 1;
            perm[t * NTOK + base[r] + cur] = n;
        }
    }
}

// ---------------------------------------------------------------------------
// K0d: Wcat = [Wt_in; W1@Wt_in] (96 x 768) -> bf16 tiled [kt12][kg8][c96][k8]
__global__ __launch_bounds__(256) void k0_wcat(
    const float* __restrict__ Wt_in, const float* __restrict__ bt_in,
    const float* __restrict__ W1, short* __restrict__ wcat,
    float* __restrict__ bcat) {
    __shared__ float w1row[64];
    const int c = blockIdx.x;   // 0..95
    const int tid = threadIdx.x;
    if (c >= 64)
        for (int j = tid; j < 64; j += 256) w1row[j] = W1[(c - 64) * 64 + j];
    __syncthreads();
    for (int k = tid; k < DMODEL; k += 256) {
        float v;
        if (c < 64) v = Wt_in[c * DMODEL + k];
        else {
            v = 0.0f;
            for (int j = 0; j < 64; ++j) v += w1row[j] * Wt_in[j * DMODEL + k];
        }
        int kt = k >> 6, kk = k & 63;
        wcat[(((kt << 3) + (kk >> 3)) * 96 + c) * 8 + (k & 7)] = (short)f2bf(v);
    }
    if (tid == 0) {
        float bv;
        if (c < 64) bv = bt_in[c];
        else {
            bv = 0.0f;
            for (int j = 0; j < 64; ++j) bv += W1[(c - 64) * 64 + j] * bt_in[j];
        }
        bcat[c] = bv;
    }
}

// K0e: Wt_out [768][64] -> bf16 tiled [dt6][kg8][dloc128][k8]
__global__ __launch_bounds__(256) void k0_wout(const float* __restrict__ Wt_out,
                                               short* __restrict__ wout) {
    int idx = blockIdx.x * 256 + threadIdx.x;   // 6144 chunks
    if (idx >= 6144) return;
    int d = idx >> 3, kg = idx & 7;
    float4 a = *(const float4*)&Wt_out[d * 64 + kg * 8];
    float4 b = *(const float4*)&Wt_out[d * 64 + kg * 8 + 4];
    uint p0 = (uint)f2bf(a.x) | ((uint)f2bf(a.y) << 16);
    uint p1 = (uint)f2bf(a.z) | ((uint)f2bf(a.w) << 16);
    uint p2 = (uint)f2bf(b.x) | ((uint)f2bf(b.y) << 16);
    uint p3 = (uint)f2bf(b.z) | ((uint)f2bf(b.w) << 16);
    uint4 v = make_uint4(p0, p1, p2, p3);
    *(uint4*)&wout[(((d >> 7) * 8 + kg) * 128 + (d & 127)) * 8] = v;
}

// K0f: W2 [32 o][32 i][9 k] -> bf16 MFMA A-frags: w2t[((k*2+wm)*64+lane)*8+e]
__global__ __launch_bounds__(256) void k0_w2t(const float* __restrict__ W2,
                                              short* __restrict__ w2t) {
    int idx = blockIdx.x * 256 + threadIdx.x;   // 9216 total
    if (idx >= 9216) return;
    int e = idx & 7, ln = (idx >> 3) & 63, wm = (idx >> 9) & 1, k = idx >> 10;
    int o = wm * 16 + (ln & 15), i = ((ln >> 4) << 3) + e;
    w2t[idx] = (short)f2bf(W2[(o * 32 + i) * 9 + k]);
}

// ---------------------------------------------------------------------------
// K1: MFMA bf16 GEMM: [feat | y] = tokens @ Wcat^T + bcat, y gets relu.
__global__ __launch_bounds__(256) void k1_mfma(
    const float* __restrict__ tokens, const short* __restrict__ wcat,
    const float* __restrict__ bcat, float* __restrict__ feat,
    float* __restrict__ y) {
    __shared__ __align__(16) short Asm[2][4096];   // [kg8][m64][k8]
    __shared__ __align__(16) short Bsm[2][6144];   // [kg8][c96][k8]

    const int tid = threadIdx.x;
    const int lane = tid & 63, wave = tid >> 6;
    const int wm = wave >> 1, wn = wave & 1;
    const int row0 = blockIdx.x * 64;
    const int sm = tid >> 2, sq = tid & 3;

    const float* arow = tokens + (size_t)(row0 + sm) * DMODEL;

    f32x4 acc[2][3] = {};
    float4 ta[4];

    #pragma unroll
    for (int p = 0; p < 4; ++p)
        ta[p] = *(const float4*)&arow[(sq + 4 * p) * 4];
    for (int ch = tid; ch < 768; ch += 256)
        GLDS16((const char*)wcat + ch * 16, (char*)Bsm[0] + ch * 16);
    #pragma unroll
    for (int p = 0; p < 4; ++p) {
        int q = sq + 4 * p, kg = q >> 1, half = q & 1;
        uint lo = (uint)f2bf(ta[p].x) | ((uint)f2bf(ta[p].y) << 16);
        uint hi = (uint)f2bf(ta[p].z) | ((uint)f2bf(ta[p].w) << 16);
        *(uint2*)((char*)Asm[0] + (kg * 64 + sm) * 16 + half * 8) = make_uint2(lo, hi);
    }
    __syncthreads();

    int cur = 0;
    for (int kt = 0; kt < 12; ++kt) {
        if (kt < 11) {
            const float* src = arow + (kt + 1) * 64;
            #pragma unroll
            for (int p = 0; p < 4; ++p)
                ta[p] = *(const float4*)&src[(sq + 4 * p) * 4];
            const char* bsrc = (const char*)wcat + (size_t)(kt + 1) * 12288;
            for (int ch = tid; ch < 768; ch += 256)
                GLDS16(bsrc + ch * 16, (char*)Bsm[cur ^ 1] + ch * 16);
        }
        const bf16x8* Ap = (const bf16x8*)Asm[cur];
        const bf16x8* Bp = (const bf16x8*)Bsm[cur];
        #pragma unroll
        for (int ks = 0; ks < 2; ++ks) {
            int kg = (lane >> 4) + ks * 4;
            bf16x8 av[2], bv[3];
            #pragma unroll
            for (int i = 0; i < 2; ++i)
                av[i] = Ap[kg * 64 + wm * 32 + i * 16 + (lane & 15)];
            #pragma unroll
            for (int j = 0; j < 3; ++j)
                bv[j] = Bp[kg * 96 + wn * 48 + j * 16 + (lane & 15)];
            #pragma unroll
            for (int i = 0; i < 2; ++i)
                #pragma unroll
                for (int j = 0; j < 3; ++j)
                    acc[i][j] = __builtin_amdgcn_mfma_f32_16x16x32_bf16(
                        av[i], bv[j], acc[i][j], 0, 0, 0);
        }
        if (kt < 11) {
            #pragma unroll
            for (int p = 0; p < 4; ++p) {
                int q = sq + 4 * p, kg = q >> 1, half = q & 1;
                uint lo = (uint)f2bf(ta[p].x) | ((uint)f2bf(ta[p].y) << 16);
                uint hi = (uint)f2bf(ta[p].z) | ((uint)f2bf(ta[p].w) << 16);
                *(uint2*)((char*)Asm[cur ^ 1] + (kg * 64 + sm) * 16 + half * 8) =
                    make_uint2(lo, hi);
            }
        }
        __syncthreads();
        cur ^= 1;
    }

    float bb[3];
    #pragma unroll
    for (int j = 0; j < 3; ++j) bb[j] = bcat[wn * 48 + j * 16 + (lane & 15)];
    #pragma unroll
    for (int i = 0; i < 2; ++i) {
        #pragma unroll
        for (int j = 0; j < 3; ++j) {
            int c = wn * 48 + j * 16 + (lane & 15);
            #pragma unroll
            for (int r = 0; r < 4; ++r) {
                int m = row0 + wm * 32 + i * 16 + ((lane >> 4) << 2) + r;
                float v = acc[i][j][r] + bb[j];
                if (c < 64) feat[(size_t)m * CF + c] = v;
                else        y[(size_t)m * CHH + (c - 64)] = fmaxf(v, 0.0f);
            }
        }
    }
}

// ---------------------------------------------------------------------------
// K23: fused HT (CSR gather, float4-vectorized) + (9,1) rho-conv via MFMA.
__global__ __launch_bounds__(256) void k23_ht_conv(
    const float* __restrict__ y, const int* __restrict__ perm,
    const int* __restrict__ rowptr, const float* __restrict__ inv,
    const short* __restrict__ w2t, float* __restrict__ htc) {
    __shared__ int pperm[NTOK];                      // 4 KB
    __shared__ int prow[90];
    __shared__ __align__(16) short insp[104 * 40];   // 8.3 KB bf16, stride 40
    __shared__ float outt[NRHO * 33];                // 11.7 KB

    const int tid = threadIdx.x;
    const int lane = tid & 63, wave = tid >> 6;
    const int wm = wave >> 1, wn = wave & 1;
    const int b = blockIdx.x / NTH, t = blockIdx.x % NTH;

    bf16x8 av[9];
    #pragma unroll
    for (int k = 0; k < 9; ++k)
        av[k] = *(const bf16x8*)&w2t[(((k * 2 + wm) * 64) + lane) * 8];

    for (int i = tid; i < NTOK; i += 256) pperm[i] = perm[t * NTOK + i];
    for (int i = tid; i < 90; i += 256) prow[i] = rowptr[t * 90 + i];
    for (int i = tid; i < 104 * 40 / 2; i += 256) ((uint*)insp)[i] = 0;
    __syncthreads();

    {
        const int c0 = (tid & 7) * 4, g = tid >> 3;   // 32 rho groups
        const float* yb = y + (size_t)b * NTOK * CHH;
        for (int rho = g; rho < NRHO; rho += 32) {
            int k0 = prow[rho], k1 = prow[rho + 1];
            float4 s = {0.0f, 0.0f, 0.0f, 0.0f};
            for (int k = k0; k < k1; ++k) {
                int n = pperm[k];
                float4 v = *(const float4*)&yb[n * CHH + c0];
                s.x += v.x; s.y += v.y; s.z += v.z; s.w += v.w;
            }
            float iv = inv[rho * NTH + t];
            uint p0 = (uint)f2bf(s.x * iv) | ((uint)f2bf(s.y * iv) << 16);
            uint p1 = (uint)f2bf(s.z * iv) | ((uint)f2bf(s.w * iv) << 16);
            *(uint2*)&insp[(rho + 4) * 40 + c0] = make_uint2(p0, p1);
        }
    }
    __syncthreads();

    f32x4 acc[3] = {};
    #pragma unroll
    for (int f = 0; f < 3; ++f) {
        int Rn = wn * 48 + f * 16 + (lane & 15);
        #pragma unroll
        for (int k = 0; k < 9; ++k) {
            bf16x8 bv = *(const bf16x8*)&insp[(Rn + k) * 40 + ((lane >> 4) << 3)];
            acc[f] = __builtin_amdgcn_mfma_f32_16x16x32_bf16(av[k], bv, acc[f], 0, 0, 0);
        }
    }
    #pragma unroll
    for (int f = 0; f < 3; ++f) {
        int r = wn * 48 + f * 16 + (lane & 15);
        if (r < NRHO) {
            #pragma unroll
            for (int reg = 0; reg < 4; ++reg) {
                int o = wm * 16 + ((lane >> 4) << 2) + reg;
                outt[r * 33 + o] = fmaxf(acc[f][reg], 0.0f);
            }
        }
    }
    __syncthreads();

    {
        const int c = tid & 31, rw = tid >> 5;
        for (int r = rw; r < NRHO; r += 8)
            htc[((size_t)b * HRB + r * NTH + t) * CHH + c] = outt[r * 33 + c];
    }
}

// ---------------------------------------------------------------------------
// K4: iht gather (/60, float4-vectorized) -> z = iht @ W3^T -> g = bf16(feat+z)
__global__ __launch_bounds__(256) void k4_iht_z(
    const float* __restrict__ ht, const int* __restrict__ flat,
    const float* __restrict__ W3, const float* __restrict__ feat,
    short* __restrict__ g) {
    __shared__ float ihts[64 * 32];
    __shared__ float w3t[32 * 64];
    __shared__ __align__(16) ushort gs16[64 * 88];
    const int tid = threadIdx.x;
    const int b = blockIdx.x >> 4;
    const int n0 = (blockIdx.x & 15) * 64;

    for (int idx = tid; idx < 2048; idx += 256) {
        int c = idx >> 6, j = idx & 63;
        w3t[idx] = W3[j * 32 + c];
    }

    {
        const int c0 = (tid & 7) * 4, np = tid >> 3;
        for (int p = 0; p < 2; ++p) {
            int nl = np * 2 + p;
            const int* fp = &flat[(n0 + nl) * NTH];
            float4 s = {0.0f, 0.0f, 0.0f, 0.0f};
            for (int t = 0; t < NTH; ++t) {
                int h = fp[t];
                float4 v = *(const float4*)&ht[((size_t)b * HRB + h) * CHH + c0];
                s.x += v.x; s.y += v.y; s.z += v.z; s.w += v.w;
            }
            float4 r;
            r.x = s.x * (1.0f / 60.0f); r.y = s.y * (1.0f / 60.0f);
            r.z = s.z * (1.0f / 60.0f); r.w = s.w * (1.0f / 60.0f);
            *(float4*)&ihts[nl * 32 + c0] = r;
        }
    }
    __syncthreads();

    const int j = tid & 63, nb = tid >> 6;
    for (int nn = nb; nn < 64; nn += 4) {
        float z = 0.0f;
        #pragma unroll 8
        for (int cc = 0; cc < 32; ++cc) z += ihts[nn * 32 + cc] * w3t[cc * 64 + j];
        float v = feat[((size_t)b * NTOK + n0 + nn) * CF + j] + z;
        gs16[nn * 88 + j] = f2bf(v);
    }
    __syncthreads();

    for (int idx = tid; idx < 512; idx += 256) {
        int kg = idx >> 6, nnl = idx & 63;
        bf16x8 frag = *(const bf16x8*)&gs16[nnl * 88 + kg * 8];
        int m = b * NTOK + n0 + nnl;
        int mt = m >> 7, mloc = m & 127;
        *(bf16x8*)&g[((mt * 8 + kg) * 128 + mloc) * 8] = frag;
    }
}

// ---------------------------------------------------------------------------
// K5: MFMA bf16 GEMM: out = g @ Wt_out^T + bt_out. 128x128 tile, K=64.
__global__ __launch_bounds__(256) void k5_mfma(
    const short* __restrict__ g, const short* __restrict__ wout,
    const float* __restrict__ bt_out, float* __restrict__ out) {
    __shared__ __align__(16) short Asm[8192];
    __shared__ __align__(16) short Bsm[8192];
    const int tid = threadIdx.x;
    const int lane = tid & 63, wave = tid >> 6;
    const int wm = wave >> 1, wn = wave & 1;
    const int mb = blockIdx.x / 6, db = blockIdx.x % 6;

    for (int ch = tid; ch < 1024; ch += 256) {
        GLDS16((const char*)g + (size_t)mb * 16384 + ch * 16, (char*)Asm + ch * 16);
        GLDS16((const char*)wout + (size_t)db * 16384 + ch * 16, (char*)Bsm + ch * 16);
    }
    __syncthreads();

    f32x4 acc[4][4] = {};
    const bf16x8* Ap = (const bf16x8*)Asm;
    const bf16x8* Bp = (const bf16x8*)Bsm;
    #pragma unroll
    for (int ks = 0; ks < 2; ++ks) {
        int kg = (lane >> 4) + ks * 4;
        bf16x8 av[4], bv[4];
        #pragma unroll
        for (int i = 0; i < 4; ++i)
            av[i] = Ap[kg * 128 + wm * 64 + i * 16 + (lane & 15)];
        #pragma unroll
        for (int j = 0; j < 4; ++j)
            bv[j] = Bp[kg * 128 + wn * 64 + j * 16 + (lane & 15)];
        #pragma unroll
        for (int i = 0; i < 4; ++i)
            #pragma unroll
            for (int j = 0; j < 4; ++j)
                acc[i][j] = __builtin_amdgcn_mfma_f32_16x16x32_bf16(
                    av[i], bv[j], acc[i][j], 0, 0, 0);
    }

    const int d0 = db * 128 + wn * 64 + (lane & 15);
    float bb[4];
    #pragma unroll
    for (int j = 0; j < 4; ++j) bb[j] = bt_out[d0 + j * 16];
    const int mrow = mb * 128 + wm * 64 + ((lane >> 4) << 2);
    #pragma unroll
    for (int i = 0; i < 4; ++i)
        #pragma unroll
        for (int r = 0; r < 4; ++r)
            #pragma unroll
            for (int j = 0; j < 4; ++j)
                out[(size_t)(mrow + i * 16 + r) * DMODEL + d0 + j * 16] =
                    acc[i][j][r] + bb[j];
}

// ---------------------------------------------------------------------------
extern "C" void kernel_launch(void* const* d_in, const int* in_sizes, int n_in,
                              void* d_out, int out_size, void* d_ws, size_t ws_size,
                              hipStream_t stream) {
    const float* tokens = (const float*)d_in[0];
    const float* vote   = (const float*)d_in[1];
    const float* Wt_in  = (const float*)d_in[2];
    const float* bt_in  = (const float*)d_in[3];
    const float* W1     = (const float*)d_in[4];
    const float* W2     = (const float*)d_in[5];
    const float* W3     = (const float*)d_in[6];
    const float* Wt_out = (const float*)d_in[7];
    const float* bt_out = (const float*)d_in[8];
    float* out = (float*)d_out;

    // workspace layout (bytes, all offsets 16-aligned)
    char* w = (char*)d_ws;
    int*   flat   = (int*)(w);                 // 245760  -> 245760
    int*   cnti   = (int*)(w + 245760);        // 21360   -> 267120
    float* inv    = (float*)(w + 267120);      // 21360   -> 288480
    int*   perm   = (int*)(w + 288480);        // 245760  -> 534240
    int*   rowptr = (int*)(w + 534240);        // 21600   -> 555840
    int*   flatT  = (int*)(w + 555840);        // 245760  -> 801600
    short* wcat   = (short*)(w + 801600);      // 147456  -> 949056
    float* bcat   = (float*)(w + 949056);      // 384     -> 949440
    short* wout   = (short*)(w + 949440);      // 98304   -> 1047744
    short* w2t    = (short*)(w + 1047744);     // 18432   -> 1066176
    float* feat   = (float*)(w + 1066176);     // 8388608 -> 9454784
    float* yb     = (float*)(w + 9454784);     // 4194304 -> 13649088
    short* g      = (short*)(w + 9454784);     // aliases yb (y dead after k23)
    float* htc    = (float*)(w + 13649088);    // 21872640 -> 35521728

    hipMemsetAsync(cnti, 0, HRB * sizeof(int), stream);
    k0_flat<<<(NTOK * HRB + 255) / 256, 256, 0, stream>>>(vote, flat, flatT, cnti);
    k0_inv<<<(HRB + 255) / 256, 256, 0, stream>>>(cnti, inv);
    k0_csr<<<NTH, 256, 0, stream>>>(flatT, perm, rowptr);
    k0_wcat<<<96, 256, 0, stream>>>(Wt_in, bt_in, W1, wcat, bcat);
    k0_wout<<<24, 256, 0, stream>>>(Wt_out, wout);
    k0_w2t<<<36, 256, 0, stream>>>(W2, w2t);
    k1_mfma<<<NB * NTOK / 64, 256, 0, stream>>>(tokens, wcat, bcat, feat, yb);
    k23_ht_conv<<<NB * NTH, 256, 0, stream>>>(yb, perm, rowptr, inv, w2t, htc);
    k4_iht_z<<<NB * (NTOK / 64), 256, 0, stream>>>(htc, flat, W3, feat, g);
    k5_mfma<<<(NB * NTOK / 128) * (DMODEL / 128), 256, 0, stream>>>(g, wout, bt_out, out);
}

// Round 6
// 133.474 us; speedup vs baseline: 5.0364x; 1.1109x over previous
//
#include <hip/hip_runtime.h>
#include <math.h>

// Problem constants (fixed by reference: B=32, 32x32 tokens, DM=768, C=64, ch=32,
// theta_res=3 -> 60 thetas, rho_res=1 on 32x32 -> q=44 -> 89 rhos)
#define NB    32
#define NTOK  1024
#define DMODEL 768
#define CF    64
#define CHH   32
#define NRHO  89
#define NTH   60
#define HRB   (NRHO*NTH)  // 5340

typedef short bf16x8 __attribute__((ext_vector_type(8)));
typedef float f32x4  __attribute__((ext_vector_type(4)));
typedef unsigned int uint;
typedef unsigned short ushort;

__device__ __forceinline__ ushort f2bf(float f) {
    uint u = __float_as_uint(f);
    return (ushort)((u + 0x7FFF + ((u >> 16) & 1)) >> 16);
}

#define GLDS16(gp, lp) __builtin_amdgcn_global_load_lds( \
    (const __attribute__((address_space(1))) unsigned int*)(gp), \
    (__attribute__((address_space(3))) unsigned int*)(lp), 16, 0, 0)

// ---------------------------------------------------------------------------
// K0a: compute hough geometry directly (replicates numpy fp64 path):
//   theta_k = 3k deg exact; rad = theta * (pi/180); rho = xc*cos + yc*sin (fp64)
//   ridx = rint(rho) + 44 (half-to-even == np.round); h = ridx*60 + t
// flat[n][t] = h (coalesced); flatT[t][n] = ridx (CSR input layout).
__global__ __launch_bounds__(256) void k0_geom(int* __restrict__ flat,
                                               int* __restrict__ flatT) {
    int idx = blockIdx.x * 256 + threadIdx.x;
    if (idx >= NTOK * NTH) return;
    int n = idx / NTH, t = idx % NTH;
    int i = n >> 5, j = n & 31;
    double xc = (double)(j - 16);
    double yc = (double)(16 - i);
    double rad = ((double)(t * 3)) * (M_PI / 180.0);
    double rho = xc * cos(rad) + yc * sin(rad);
    int ridx = (int)rint(rho) + 44;
    flat[n * NTH + t] = ridx * NTH + t;
    flatT[t * NTOK + n] = ridx;
}

// K0c: per-theta CSR via parallel counting sort (deterministic, stable (rho,n)).
// 64 chunks x 16 tokens: LDS histogram -> per-rho chunk scan -> base scan -> fill.
__global__ __launch_bounds__(256) void k0_csr(const int* __restrict__ flatT,
                                              int* __restrict__ perm,
                                              int* __restrict__ rowptr) {
    __shared__ int rho_n[NTOK];        // 4 KB
    __shared__ int cnt2[64 * 90];      // 23 KB chunk histograms / cursors
    __shared__ int tot[96];
    __shared__ int base[96];
    const int tid = threadIdx.x;
    const int t = blockIdx.x;

    for (int n = tid; n < NTOK; n += 256) rho_n[n] = flatT[t * NTOK + n];
    for (int i = tid; i < 64 * 90; i += 256) cnt2[i] = 0;
    __syncthreads();
    for (int n = tid; n < NTOK; n += 256)
        atomicAdd(&cnt2[(n >> 4) * 90 + rho_n[n]], 1);
    __syncthreads();
    if (tid < NRHO) {   // exclusive scan over chunks for this rho
        int s = 0;
        for (int c = 0; c < 64; ++c) {
            int v = cnt2[c * 90 + tid];
            cnt2[c * 90 + tid] = s;
            s += v;
        }
        tot[tid] = s;
    }
    __syncthreads();
    if (tid == 0) {
        int s = 0;
        for (int r = 0; r < NRHO; ++r) { base[r] = s; s += tot[r]; }
        base[NRHO] = s;   // 1024
    }
    __syncthreads();
    if (tid < NRHO + 1) rowptr[t * 90 + tid] = base[tid];
    if (tid < 64) {   // fill: one thread per chunk, private cursors
        const int c = tid;
        #pragma unroll
        for (int j = 0; j < 16; ++j) {
            int n = c * 16 + j;
            int r = rho_n[n];
            int cur = cnt2[c * 90 + r];
            cnt2[c * 90 + r] = cur + 1;
            perm[t * NTOK + base[r] + cur] = n;
        }
    }
}

// ---------------------------------------------------------------------------
// K0d: Wcat = [Wt_in; W1@Wt_in] (96 x 768) -> bf16 tiled [kt12][kg8][c96][k8]
__global__ __launch_bounds__(256) void k0_wcat(
    const float* __restrict__ Wt_in, const float* __restrict__ bt_in,
    const float* __restrict__ W1, short* __restrict__ wcat,
    float* __restrict__ bcat) {
    __shared__ float w1row[64];
    const int c = blockIdx.x;   // 0..95
    const int tid = threadIdx.x;
    if (c >= 64)
        for (int j = tid; j < 64; j += 256) w1row[j] = W1[(c - 64) * 64 + j];
    __syncthreads();
    for (int k = tid; k < DMODEL; k += 256) {
        float v;
        if (c < 64) v = Wt_in[c * DMODEL + k];
        else {
            v = 0.0f;
            for (int j = 0; j < 64; ++j) v += w1row[j] * Wt_in[j * DMODEL + k];
        }
        int kt = k >> 6, kk = k & 63;
        wcat[(((kt << 3) + (kk >> 3)) * 96 + c) * 8 + (k & 7)] = (short)f2bf(v);
    }
    if (tid == 0) {
        float bv;
        if (c < 64) bv = bt_in[c];
        else {
            bv = 0.0f;
            for (int j = 0; j < 64; ++j) bv += W1[(c - 64) * 64 + j] * bt_in[j];
        }
        bcat[c] = bv;
    }
}

// K0e (merged): Wt_out -> bf16 tiled [dt6][kg8][dloc128][k8]  (idx < 6144)
//              W2 -> bf16 MFMA A-frags w2t                    (idx >= 6144)
__global__ __launch_bounds__(256) void k0_wprep(const float* __restrict__ Wt_out,
                                                const float* __restrict__ W2,
                                                short* __restrict__ wout,
                                                short* __restrict__ w2t) {
    int idx = blockIdx.x * 256 + threadIdx.x;   // 15360 total
    if (idx < 6144) {
        int d = idx >> 3, kg = idx & 7;
        float4 a = *(const float4*)&Wt_out[d * 64 + kg * 8];
        float4 b = *(const float4*)&Wt_out[d * 64 + kg * 8 + 4];
        uint p0 = (uint)f2bf(a.x) | ((uint)f2bf(a.y) << 16);
        uint p1 = (uint)f2bf(a.z) | ((uint)f2bf(a.w) << 16);
        uint p2 = (uint)f2bf(b.x) | ((uint)f2bf(b.y) << 16);
        uint p3 = (uint)f2bf(b.z) | ((uint)f2bf(b.w) << 16);
        uint4 v = make_uint4(p0, p1, p2, p3);
        *(uint4*)&wout[(((d >> 7) * 8 + kg) * 128 + (d & 127)) * 8] = v;
    } else if (idx < 6144 + 9216) {
        int q = idx - 6144;
        int e = q & 7, ln = (q >> 3) & 63, wm = (q >> 9) & 1, k = q >> 10;
        int o = wm * 16 + (ln & 15), i = ((ln >> 4) << 3) + e;
        w2t[q] = (short)f2bf(W2[(o * 32 + i) * 9 + k]);
    }
}

// ---------------------------------------------------------------------------
// K1: MFMA bf16 GEMM: [feat | y] = tokens @ Wcat^T + bcat, y gets relu.
__global__ __launch_bounds__(256) void k1_mfma(
    const float* __restrict__ tokens, const short* __restrict__ wcat,
    const float* __restrict__ bcat, float* __restrict__ feat,
    float* __restrict__ y) {
    __shared__ __align__(16) short Asm[2][4096];   // [kg8][m64][k8]
    __shared__ __align__(16) short Bsm[2][6144];   // [kg8][c96][k8]

    const int tid = threadIdx.x;
    const int lane = tid & 63, wave = tid >> 6;
    const int wm = wave >> 1, wn = wave & 1;
    const int row0 = blockIdx.x * 64;
    const int sm = tid >> 2, sq = tid & 3;

    const float* arow = tokens + (size_t)(row0 + sm) * DMODEL;

    f32x4 acc[2][3] = {};
    float4 ta[4];

    #pragma unroll
    for (int p = 0; p < 4; ++p)
        ta[p] = *(const float4*)&arow[(sq + 4 * p) * 4];
    for (int ch = tid; ch < 768; ch += 256)
        GLDS16((const char*)wcat + ch * 16, (char*)Bsm[0] + ch * 16);
    #pragma unroll
    for (int p = 0; p < 4; ++p) {
        int q = sq + 4 * p, kg = q >> 1, half = q & 1;
        uint lo = (uint)f2bf(ta[p].x) | ((uint)f2bf(ta[p].y) << 16);
        uint hi = (uint)f2bf(ta[p].z) | ((uint)f2bf(ta[p].w) << 16);
        *(uint2*)((char*)Asm[0] + (kg * 64 + sm) * 16 + half * 8) = make_uint2(lo, hi);
    }
    __syncthreads();

    int cur = 0;
    for (int kt = 0; kt < 12; ++kt) {
        if (kt < 11) {
            const float* src = arow + (kt + 1) * 64;
            #pragma unroll
            for (int p = 0; p < 4; ++p)
                ta[p] = *(const float4*)&src[(sq + 4 * p) * 4];
            const char* bsrc = (const char*)wcat + (size_t)(kt + 1) * 12288;
            for (int ch = tid; ch < 768; ch += 256)
                GLDS16(bsrc + ch * 16, (char*)Bsm[cur ^ 1] + ch * 16);
        }
        const bf16x8* Ap = (const bf16x8*)Asm[cur];
        const bf16x8* Bp = (const bf16x8*)Bsm[cur];
        #pragma unroll
        for (int ks = 0; ks < 2; ++ks) {
            int kg = (lane >> 4) + ks * 4;
            bf16x8 av[2], bv[3];
            #pragma unroll
            for (int i = 0; i < 2; ++i)
                av[i] = Ap[kg * 64 + wm * 32 + i * 16 + (lane & 15)];
            #pragma unroll
            for (int j = 0; j < 3; ++j)
                bv[j] = Bp[kg * 96 + wn * 48 + j * 16 + (lane & 15)];
            #pragma unroll
            for (int i = 0; i < 2; ++i)
                #pragma unroll
                for (int j = 0; j < 3; ++j)
                    acc[i][j] = __builtin_amdgcn_mfma_f32_16x16x32_bf16(
                        av[i], bv[j], acc[i][j], 0, 0, 0);
        }
        if (kt < 11) {
            #pragma unroll
            for (int p = 0; p < 4; ++p) {
                int q = sq + 4 * p, kg = q >> 1, half = q & 1;
                uint lo = (uint)f2bf(ta[p].x) | ((uint)f2bf(ta[p].y) << 16);
                uint hi = (uint)f2bf(ta[p].z) | ((uint)f2bf(ta[p].w) << 16);
                *(uint2*)((char*)Asm[cur ^ 1] + (kg * 64 + sm) * 16 + half * 8) =
                    make_uint2(lo, hi);
            }
        }
        __syncthreads();
        cur ^= 1;
    }

    float bb[3];
    #pragma unroll
    for (int j = 0; j < 3; ++j) bb[j] = bcat[wn * 48 + j * 16 + (lane & 15)];
    #pragma unroll
    for (int i = 0; i < 2; ++i) {
        #pragma unroll
        for (int j = 0; j < 3; ++j) {
            int c = wn * 48 + j * 16 + (lane & 15);
            #pragma unroll
            for (int r = 0; r < 4; ++r) {
                int m = row0 + wm * 32 + i * 16 + ((lane >> 4) << 2) + r;
                float v = acc[i][j][r] + bb[j];
                if (c < 64) feat[(size_t)m * CF + c] = v;
                else        y[(size_t)m * CHH + (c - 64)] = fmaxf(v, 0.0f);
            }
        }
    }
}

// ---------------------------------------------------------------------------
// K23: fused HT (CSR gather, float4-vectorized) + (9,1) rho-conv via MFMA.
// Normalizer computed inline from rowptr diff (== vote column count).
__global__ __launch_bounds__(256) void k23_ht_conv(
    const float* __restrict__ y, const int* __restrict__ perm,
    const int* __restrict__ rowptr, const short* __restrict__ w2t,
    float* __restrict__ htc) {
    __shared__ int pperm[NTOK];                      // 4 KB
    __shared__ int prow[90];
    __shared__ __align__(16) short insp[104 * 40];   // 8.3 KB bf16, stride 40
    __shared__ float outt[NRHO * 33];                // 11.7 KB

    const int tid = threadIdx.x;
    const int lane = tid & 63, wave = tid >> 6;
    const int wm = wave >> 1, wn = wave & 1;
    const int b = blockIdx.x / NTH, t = blockIdx.x % NTH;

    bf16x8 av[9];
    #pragma unroll
    for (int k = 0; k < 9; ++k)
        av[k] = *(const bf16x8*)&w2t[(((k * 2 + wm) * 64) + lane) * 8];

    for (int i = tid; i < NTOK; i += 256) pperm[i] = perm[t * NTOK + i];
    for (int i = tid; i < 90; i += 256) prow[i] = rowptr[t * 90 + i];
    for (int i = tid; i < 104 * 40 / 2; i += 256) ((uint*)insp)[i] = 0;
    __syncthreads();

    {
        const int c0 = (tid & 7) * 4, g = tid >> 3;   // 32 rho groups
        const float* yb = y + (size_t)b * NTOK * CHH;
        for (int rho = g; rho < NRHO; rho += 32) {
            int p0 = prow[rho], p1 = prow[rho + 1];
            float4 s = {0.0f, 0.0f, 0.0f, 0.0f};
            for (int k = p0; k < p1; ++k) {
                int n = pperm[k];
                float4 v = *(const float4*)&yb[n * CHH + c0];
                s.x += v.x; s.y += v.y; s.z += v.z; s.w += v.w;
            }
            float iv = 1.0f / fmaxf((float)(p1 - p0), 1.0f);
            uint q0 = (uint)f2bf(s.x * iv) | ((uint)f2bf(s.y * iv) << 16);
            uint q1 = (uint)f2bf(s.z * iv) | ((uint)f2bf(s.w * iv) << 16);
            *(uint2*)&insp[(rho + 4) * 40 + c0] = make_uint2(q0, q1);
        }
    }
    __syncthreads();

    f32x4 acc[3] = {};
    #pragma unroll
    for (int f = 0; f < 3; ++f) {
        int Rn = wn * 48 + f * 16 + (lane & 15);
        #pragma unroll
        for (int k = 0; k < 9; ++k) {
            bf16x8 bv = *(const bf16x8*)&insp[(Rn + k) * 40 + ((lane >> 4) << 3)];
            acc[f] = __builtin_amdgcn_mfma_f32_16x16x32_bf16(av[k], bv, acc[f], 0, 0, 0);
        }
    }
    #pragma unroll
    for (int f = 0; f < 3; ++f) {
        int r = wn * 48 + f * 16 + (lane & 15);
        if (r < NRHO) {
            #pragma unroll
            for (int reg = 0; reg < 4; ++reg) {
                int o = wm * 16 + ((lane >> 4) << 2) + reg;
                outt[r * 33 + o] = fmaxf(acc[f][reg], 0.0f);
            }
        }
    }
    __syncthreads();

    {
        const int c = tid & 31, rw = tid >> 5;
        for (int r = rw; r < NRHO; r += 8)
            htc[((size_t)b * HRB + r * NTH + t) * CHH + c] = outt[r * 33 + c];
    }
}

// ---------------------------------------------------------------------------
// K4: iht gather (/60, float4-vectorized) -> z = iht @ W3^T -> g = bf16(feat+z)
__global__ __launch_bounds__(256) void k4_iht_z(
    const float* __restrict__ ht, const int* __restrict__ flat,
    const float* __restrict__ W3, const float* __restrict__ feat,
    short* __restrict__ g) {
    __shared__ float ihts[64 * 32];
    __shared__ float w3t[32 * 64];
    __shared__ __align__(16) ushort gs16[64 * 88];
    const int tid = threadIdx.x;
    const int b = blockIdx.x >> 4;
    const int n0 = (blockIdx.x & 15) * 64;

    for (int idx = tid; idx < 2048; idx += 256) {
        int c = idx >> 6, j = idx & 63;
        w3t[idx] = W3[j * 32 + c];
    }

    {
        const int c0 = (tid & 7) * 4, np = tid >> 3;
        for (int p = 0; p < 2; ++p) {
            int nl = np * 2 + p;
            const int* fp = &flat[(n0 + nl) * NTH];
            float4 s = {0.0f, 0.0f, 0.0f, 0.0f};
            for (int t = 0; t < NTH; ++t) {
                int h = fp[t];
                float4 v = *(const float4*)&ht[((size_t)b * HRB + h) * CHH + c0];
                s.x += v.x; s.y += v.y; s.z += v.z; s.w += v.w;
            }
            float4 r;
            r.x = s.x * (1.0f / 60.0f); r.y = s.y * (1.0f / 60.0f);
            r.z = s.z * (1.0f / 60.0f); r.w = s.w * (1.0f / 60.0f);
            *(float4*)&ihts[nl * 32 + c0] = r;
        }
    }
    __syncthreads();

    const int j = tid & 63, nb = tid >> 6;
    for (int nn = nb; nn < 64; nn += 4) {
        float z = 0.0f;
        #pragma unroll 8
        for (int cc = 0; cc < 32; ++cc) z += ihts[nn * 32 + cc] * w3t[cc * 64 + j];
        float v = feat[((size_t)b * NTOK + n0 + nn) * CF + j] + z;
        gs16[nn * 88 + j] = f2bf(v);
    }
    __syncthreads();

    for (int idx = tid; idx < 512; idx += 256) {
        int kg = idx >> 6, nnl = idx & 63;
        bf16x8 frag = *(const bf16x8*)&gs16[nnl * 88 + kg * 8];
        int m = b * NTOK + n0 + nnl;
        int mt = m >> 7, mloc = m & 127;
        *(bf16x8*)&g[((mt * 8 + kg) * 128 + mloc) * 8] = frag;
    }
}

// ---------------------------------------------------------------------------
// K5: MFMA bf16 GEMM: out = g @ Wt_out^T + bt_out. 128x128 tile, K=64.
__global__ __launch_bounds__(256) void k5_mfma(
    const short* __restrict__ g, const short* __restrict__ wout,
    const float* __restrict__ bt_out, float* __restrict__ out) {
    __shared__ __align__(16) short Asm[8192];
    __shared__ __align__(16) short Bsm[8192];
    const int tid = threadIdx.x;
    const int lane = tid & 63, wave = tid >> 6;
    const int wm = wave >> 1, wn = wave & 1;
    const int mb = blockIdx.x / 6, db = blockIdx.x % 6;

    for (int ch = tid; ch < 1024; ch += 256) {
        GLDS16((const char*)g + (size_t)mb * 16384 + ch * 16, (char*)Asm + ch * 16);
        GLDS16((const char*)wout + (size_t)db * 16384 + ch * 16, (char*)Bsm + ch * 16);
    }
    __syncthreads();

    f32x4 acc[4][4] = {};
    const bf16x8* Ap = (const bf16x8*)Asm;
    const bf16x8* Bp = (const bf16x8*)Bsm;
    #pragma unroll
    for (int ks = 0; ks < 2; ++ks) {
        int kg = (lane >> 4) + ks * 4;
        bf16x8 av[4], bv[4];
        #pragma unroll
        for (int i = 0; i < 4; ++i)
            av[i] = Ap[kg * 128 + wm * 64 + i * 16 + (lane & 15)];
        #pragma unroll
        for (int j = 0; j < 4; ++j)
            bv[j] = Bp[kg * 128 + wn * 64 + j * 16 + (lane & 15)];
        #pragma unroll
        for (int i = 0; i < 4; ++i)
            #pragma unroll
            for (int j = 0; j < 4; ++j)
                acc[i][j] = __builtin_amdgcn_mfma_f32_16x16x32_bf16(
                    av[i], bv[j], acc[i][j], 0, 0, 0);
    }

    const int d0 = db * 128 + wn * 64 + (lane & 15);
    float bb[4];
    #pragma unroll
    for (int j = 0; j < 4; ++j) bb[j] = bt_out[d0 + j * 16];
    const int mrow = mb * 128 + wm * 64 + ((lane >> 4) << 2);
    #pragma unroll
    for (int i = 0; i < 4; ++i)
        #pragma unroll
        for (int r = 0; r < 4; ++r)
            #pragma unroll
            for (int j = 0; j < 4; ++j)
                out[(size_t)(mrow + i * 16 + r) * DMODEL + d0 + j * 16] =
                    acc[i][j][r] + bb[j];
}

// ---------------------------------------------------------------------------
extern "C" void kernel_launch(void* const* d_in, const int* in_sizes, int n_in,
                              void* d_out, int out_size, void* d_ws, size_t ws_size,
                              hipStream_t stream) {
    const float* tokens = (const float*)d_in[0];
    const float* Wt_in  = (const float*)d_in[2];
    const float* bt_in  = (const float*)d_in[3];
    const float* W1     = (const float*)d_in[4];
    const float* W2     = (const float*)d_in[5];
    const float* W3     = (const float*)d_in[6];
    const float* Wt_out = (const float*)d_in[7];
    const float* bt_out = (const float*)d_in[8];
    float* out = (float*)d_out;

    // workspace layout (bytes, all offsets 16-aligned)
    char* w = (char*)d_ws;
    int*   flat   = (int*)(w);                 // 245760  -> 245760
    int*   perm   = (int*)(w + 245760);        // 245760  -> 491520
    int*   rowptr = (int*)(w + 491520);        // 21600   -> 513120
    int*   flatT  = (int*)(w + 513120);        // 245760  -> 758880
    short* wcat   = (short*)(w + 758880);      // 147456  -> 906336
    float* bcat   = (float*)(w + 906336);      // 384     -> 906720
    short* wout   = (short*)(w + 906720);      // 98304   -> 1005024
    short* w2t    = (short*)(w + 1005024);     // 18432   -> 1023456
    float* feat   = (float*)(w + 1023456);     // 8388608 -> 9412064
    float* yb     = (float*)(w + 9412064);     // 4194304 -> 13606368
    short* g      = (short*)(w + 9412064);     // aliases yb (y dead after k23)
    float* htc    = (float*)(w + 13606368);    // 21872640 -> 35479008

    k0_geom<<<(NTOK * NTH + 255) / 256, 256, 0, stream>>>(flat, flatT);
    k0_csr<<<NTH, 256, 0, stream>>>(flatT, perm, rowptr);
    k0_wcat<<<96, 256, 0, stream>>>(Wt_in, bt_in, W1, wcat, bcat);
    k0_wprep<<<60, 256, 0, stream>>>(Wt_out, W2, wout, w2t);
    k1_mfma<<<NB * NTOK / 64, 256, 0, stream>>>(tokens, wcat, bcat, feat, yb);
    k23_ht_conv<<<NB * NTH, 256, 0, stream>>>(yb, perm, rowptr, w2t, htc);
    k4_iht_z<<<NB * (NTOK / 64), 256, 0, stream>>>(htc, flat, W3, feat, g);
    k5_mfma<<<(NB * NTOK / 128) * (DMODEL / 128), 256, 0, stream>>>(g, wout, bt_out, out);
}

// Round 7
// 124.592 us; speedup vs baseline: 5.3954x; 1.0713x over previous
//
#include <hip/hip_runtime.h>
#include <math.h>

// Problem constants (fixed by reference: B=32, 32x32 tokens, DM=768, C=64, ch=32,
// theta_res=3 -> 60 thetas, rho_res=1 on 32x32 -> q=44 -> 89 rhos)
#define NB    32
#define NTOK  1024
#define DMODEL 768
#define CF    64
#define CHH   32
#define NRHO  89
#define NTH   60
#define HRB   (NRHO*NTH)  // 5340

typedef short bf16x8 __attribute__((ext_vector_type(8)));
typedef float f32x4  __attribute__((ext_vector_type(4)));
typedef unsigned int uint;
typedef unsigned short ushort;

__device__ __forceinline__ ushort f2bf(float f) {
    uint u = __float_as_uint(f);
    return (ushort)((u + 0x7FFF + ((u >> 16) & 1)) >> 16);
}
__device__ __forceinline__ float bf2f(ushort u) {
    return __uint_as_float(((uint)u) << 16);
}

#define GLDS16(gp, lp) __builtin_amdgcn_global_load_lds( \
    (const __attribute__((address_space(1))) unsigned int*)(gp), \
    (__attribute__((address_space(3))) unsigned int*)(lp), 16, 0, 0)

// ---------------------------------------------------------------------------
// K0c: per-theta CSR via parallel counting sort, with Hough geometry computed
// inline (fp64, replicates numpy: theta=3t deg, rho=xc*cos+yc*sin, rint
// half-to-even). Also writes flat[n][t] = bin index for k4's gather.
__global__ __launch_bounds__(256) void k0_csr(int* __restrict__ flat,
                                              int* __restrict__ perm,
                                              int* __restrict__ rowptr) {
    __shared__ int rho_n[NTOK];        // 4 KB
    __shared__ int cnt2[64 * 90];      // 23 KB chunk histograms / cursors
    __shared__ int tot[96];
    __shared__ int base[96];
    const int tid = threadIdx.x;
    const int t = blockIdx.x;

    const double rad = ((double)(t * 3)) * (M_PI / 180.0);
    const double ct = cos(rad), st = sin(rad);
    for (int n = tid; n < NTOK; n += 256) {
        int i = n >> 5, j = n & 31;
        double rho = (double)(j - 16) * ct + (double)(16 - i) * st;
        int ridx = (int)rint(rho) + 44;
        rho_n[n] = ridx;
        flat[n * NTH + t] = ridx * NTH + t;
    }
    for (int i = tid; i < 64 * 90; i += 256) cnt2[i] = 0;
    __syncthreads();
    for (int n = tid; n < NTOK; n += 256)
        atomicAdd(&cnt2[(n >> 4) * 90 + rho_n[n]], 1);
    __syncthreads();
    if (tid < NRHO) {   // exclusive scan over chunks for this rho
        int s = 0;
        for (int c = 0; c < 64; ++c) {
            int v = cnt2[c * 90 + tid];
            cnt2[c * 90 + tid] = s;
            s += v;
        }
        tot[tid] = s;
    }
    __syncthreads();
    if (tid == 0) {
        int s = 0;
        for (int r = 0; r < NRHO; ++r) { base[r] = s; s += tot[r]; }
        base[NRHO] = s;   // 1024
    }
    __syncthreads();
    if (tid < NRHO + 1) rowptr[t * 90 + tid] = base[tid];
    if (tid < 64) {   // fill: one thread per chunk, private cursors
        const int c = tid;
        #pragma unroll
        for (int j = 0; j < 16; ++j) {
            int n = c * 16 + j;
            int r = rho_n[n];
            int cur = cnt2[c * 90 + r];
            cnt2[c * 90 + r] = cur + 1;
            perm[t * NTOK + base[r] + cur] = n;
        }
    }
}

// ---------------------------------------------------------------------------
// K0d: Wcat = [Wt_in; W1@Wt_in] (96 x 768) -> bf16 tiled [kt12][kg8][c96][k8]
__global__ __launch_bounds__(256) void k0_wcat(
    const float* __restrict__ Wt_in, const float* __restrict__ bt_in,
    const float* __restrict__ W1, short* __restrict__ wcat,
    float* __restrict__ bcat) {
    __shared__ float w1row[64];
    const int c = blockIdx.x;   // 0..95
    const int tid = threadIdx.x;
    if (c >= 64)
        for (int j = tid; j < 64; j += 256) w1row[j] = W1[(c - 64) * 64 + j];
    __syncthreads();
    for (int k = tid; k < DMODEL; k += 256) {
        float v;
        if (c < 64) v = Wt_in[c * DMODEL + k];
        else {
            v = 0.0f;
            for (int j = 0; j < 64; ++j) v += w1row[j] * Wt_in[j * DMODEL + k];
        }
        int kt = k >> 6, kk = k & 63;
        wcat[(((kt << 3) + (kk >> 3)) * 96 + c) * 8 + (k & 7)] = (short)f2bf(v);
    }
    if (tid == 0) {
        float bv;
        if (c < 64) bv = bt_in[c];
        else {
            bv = 0.0f;
            for (int j = 0; j < 64; ++j) bv += W1[(c - 64) * 64 + j] * bt_in[j];
        }
        bcat[c] = bv;
    }
}

// K0e (merged): Wt_out -> bf16 tiled [dt6][kg8][dloc128][k8]  (idx < 6144)
//              W2 -> bf16 MFMA A-frags w2t                    (idx >= 6144)
__global__ __launch_bounds__(256) void k0_wprep(const float* __restrict__ Wt_out,
                                                const float* __restrict__ W2,
                                                short* __restrict__ wout,
                                                short* __restrict__ w2t) {
    int idx = blockIdx.x * 256 + threadIdx.x;   // 15360 total
    if (idx < 6144) {
        int d = idx >> 3, kg = idx & 7;
        float4 a = *(const float4*)&Wt_out[d * 64 + kg * 8];
        float4 b = *(const float4*)&Wt_out[d * 64 + kg * 8 + 4];
        uint p0 = (uint)f2bf(a.x) | ((uint)f2bf(a.y) << 16);
        uint p1 = (uint)f2bf(a.z) | ((uint)f2bf(a.w) << 16);
        uint p2 = (uint)f2bf(b.x) | ((uint)f2bf(b.y) << 16);
        uint p3 = (uint)f2bf(b.z) | ((uint)f2bf(b.w) << 16);
        uint4 v = make_uint4(p0, p1, p2, p3);
        *(uint4*)&wout[(((d >> 7) * 8 + kg) * 128 + (d & 127)) * 8] = v;
    } else if (idx < 6144 + 9216) {
        int q = idx - 6144;
        int e = q & 7, ln = (q >> 3) & 63, wm = (q >> 9) & 1, k = q >> 10;
        int o = wm * 16 + (ln & 15), i = ((ln >> 4) << 3) + e;
        w2t[q] = (short)f2bf(W2[(o * 32 + i) * 9 + k]);
    }
}

// ---------------------------------------------------------------------------
// K1: MFMA bf16 GEMM: [feat | y] = tokens @ Wcat^T + bcat, y gets relu.
// feat stored as bf16 (featb), y stays fp32 for the k23 gather.
__global__ __launch_bounds__(256) void k1_mfma(
    const float* __restrict__ tokens, const short* __restrict__ wcat,
    const float* __restrict__ bcat, ushort* __restrict__ featb,
    float* __restrict__ y) {
    __shared__ __align__(16) short Asm[2][4096];   // [kg8][m64][k8]
    __shared__ __align__(16) short Bsm[2][6144];   // [kg8][c96][k8]

    const int tid = threadIdx.x;
    const int lane = tid & 63, wave = tid >> 6;
    const int wm = wave >> 1, wn = wave & 1;
    const int row0 = blockIdx.x * 64;
    const int sm = tid >> 2, sq = tid & 3;

    const float* arow = tokens + (size_t)(row0 + sm) * DMODEL;

    f32x4 acc[2][3] = {};
    float4 ta[4];

    #pragma unroll
    for (int p = 0; p < 4; ++p)
        ta[p] = *(const float4*)&arow[(sq + 4 * p) * 4];
    for (int ch = tid; ch < 768; ch += 256)
        GLDS16((const char*)wcat + ch * 16, (char*)Bsm[0] + ch * 16);
    #pragma unroll
    for (int p = 0; p < 4; ++p) {
        int q = sq + 4 * p, kg = q >> 1, half = q & 1;
        uint lo = (uint)f2bf(ta[p].x) | ((uint)f2bf(ta[p].y) << 16);
        uint hi = (uint)f2bf(ta[p].z) | ((uint)f2bf(ta[p].w) << 16);
        *(uint2*)((char*)Asm[0] + (kg * 64 + sm) * 16 + half * 8) = make_uint2(lo, hi);
    }
    __syncthreads();

    int cur = 0;
    for (int kt = 0; kt < 12; ++kt) {
        if (kt < 11) {
            const float* src = arow + (kt + 1) * 64;
            #pragma unroll
            for (int p = 0; p < 4; ++p)
                ta[p] = *(const float4*)&src[(sq + 4 * p) * 4];
            const char* bsrc = (const char*)wcat + (size_t)(kt + 1) * 12288;
            for (int ch = tid; ch < 768; ch += 256)
                GLDS16(bsrc + ch * 16, (char*)Bsm[cur ^ 1] + ch * 16);
        }
        const bf16x8* Ap = (const bf16x8*)Asm[cur];
        const bf16x8* Bp = (const bf16x8*)Bsm[cur];
        #pragma unroll
        for (int ks = 0; ks < 2; ++ks) {
            int kg = (lane >> 4) + ks * 4;
            bf16x8 av[2], bv[3];
            #pragma unroll
            for (int i = 0; i < 2; ++i)
                av[i] = Ap[kg * 64 + wm * 32 + i * 16 + (lane & 15)];
            #pragma unroll
            for (int j = 0; j < 3; ++j)
                bv[j] = Bp[kg * 96 + wn * 48 + j * 16 + (lane & 15)];
            #pragma unroll
            for (int i = 0; i < 2; ++i)
                #pragma unroll
                for (int j = 0; j < 3; ++j)
                    acc[i][j] = __builtin_amdgcn_mfma_f32_16x16x32_bf16(
                        av[i], bv[j], acc[i][j], 0, 0, 0);
        }
        if (kt < 11) {
            #pragma unroll
            for (int p = 0; p < 4; ++p) {
                int q = sq + 4 * p, kg = q >> 1, half = q & 1;
                uint lo = (uint)f2bf(ta[p].x) | ((uint)f2bf(ta[p].y) << 16);
                uint hi = (uint)f2bf(ta[p].z) | ((uint)f2bf(ta[p].w) << 16);
                *(uint2*)((char*)Asm[cur ^ 1] + (kg * 64 + sm) * 16 + half * 8) =
                    make_uint2(lo, hi);
            }
        }
        __syncthreads();
        cur ^= 1;
    }

    float bb[3];
    #pragma unroll
    for (int j = 0; j < 3; ++j) bb[j] = bcat[wn * 48 + j * 16 + (lane & 15)];
    #pragma unroll
    for (int i = 0; i < 2; ++i) {
        #pragma unroll
        for (int j = 0; j < 3; ++j) {
            int c = wn * 48 + j * 16 + (lane & 15);
            #pragma unroll
            for (int r = 0; r < 4; ++r) {
                int m = row0 + wm * 32 + i * 16 + ((lane >> 4) << 2) + r;
                float v = acc[i][j][r] + bb[j];
                if (c < 64) featb[(size_t)m * CF + c] = f2bf(v);
                else        y[(size_t)m * CHH + (c - 64)] = fmaxf(v, 0.0f);
            }
        }
    }
}

// ---------------------------------------------------------------------------
// K23: fused HT (CSR gather, float4-vectorized) + (9,1) rho-conv via MFMA.
// Normalizer from rowptr diff. Output htcb stored as bf16.
__global__ __launch_bounds__(256) void k23_ht_conv(
    const float* __restrict__ y, const int* __restrict__ perm,
    const int* __restrict__ rowptr, const short* __restrict__ w2t,
    ushort* __restrict__ htcb) {
    __shared__ int pperm[NTOK];                      // 4 KB
    __shared__ int prow[90];
    __shared__ __align__(16) short insp[104 * 40];   // 8.3 KB bf16, stride 40
    __shared__ ushort outts[NRHO * 36];              // 6.4 KB bf16

    const int tid = threadIdx.x;
    const int lane = tid & 63, wave = tid >> 6;
    const int wm = wave >> 1, wn = wave & 1;
    const int b = blockIdx.x / NTH, t = blockIdx.x % NTH;

    bf16x8 av[9];
    #pragma unroll
    for (int k = 0; k < 9; ++k)
        av[k] = *(const bf16x8*)&w2t[(((k * 2 + wm) * 64) + lane) * 8];

    for (int i = tid; i < NTOK; i += 256) pperm[i] = perm[t * NTOK + i];
    for (int i = tid; i < 90; i += 256) prow[i] = rowptr[t * 90 + i];
    for (int i = tid; i < 104 * 40 / 2; i += 256) ((uint*)insp)[i] = 0;
    __syncthreads();

    {
        const int c0 = (tid & 7) * 4, g = tid >> 3;   // 32 rho groups
        const float* yb = y + (size_t)b * NTOK * CHH;
        for (int rho = g; rho < NRHO; rho += 32) {
            int p0 = prow[rho], p1 = prow[rho + 1];
            float4 s = {0.0f, 0.0f, 0.0f, 0.0f};
            for (int k = p0; k < p1; ++k) {
                int n = pperm[k];
                float4 v = *(const float4*)&yb[n * CHH + c0];
                s.x += v.x; s.y += v.y; s.z += v.z; s.w += v.w;
            }
            float iv = 1.0f / fmaxf((float)(p1 - p0), 1.0f);
            uint q0 = (uint)f2bf(s.x * iv) | ((uint)f2bf(s.y * iv) << 16);
            uint q1 = (uint)f2bf(s.z * iv) | ((uint)f2bf(s.w * iv) << 16);
            *(uint2*)&insp[(rho + 4) * 40 + c0] = make_uint2(q0, q1);
        }
    }
    __syncthreads();

    f32x4 acc[3] = {};
    #pragma unroll
    for (int f = 0; f < 3; ++f) {
        int Rn = wn * 48 + f * 16 + (lane & 15);
        #pragma unroll
        for (int k = 0; k < 9; ++k) {
            bf16x8 bv = *(const bf16x8*)&insp[(Rn + k) * 40 + ((lane >> 4) << 3)];
            acc[f] = __builtin_amdgcn_mfma_f32_16x16x32_bf16(av[k], bv, acc[f], 0, 0, 0);
        }
    }
    #pragma unroll
    for (int f = 0; f < 3; ++f) {
        int r = wn * 48 + f * 16 + (lane & 15);
        if (r < NRHO) {
            #pragma unroll
            for (int reg = 0; reg < 4; ++reg) {
                int o = wm * 16 + ((lane >> 4) << 2) + reg;
                outts[r * 36 + o] = f2bf(fmaxf(acc[f][reg], 0.0f));
            }
        }
    }
    __syncthreads();

    {
        const int c = tid & 31, rw = tid >> 5;
        for (int r = rw; r < NRHO; r += 8)
            htcb[((size_t)b * HRB + r * NTH + t) * CHH + c] = outts[r * 36 + c];
    }
}

// ---------------------------------------------------------------------------
// K4: iht gather from bf16 htcb (/60) -> z = iht @ W3^T -> g = bf16(feat+z)
__global__ __launch_bounds__(256) void k4_iht_z(
    const ushort* __restrict__ htcb, const int* __restrict__ flat,
    const float* __restrict__ W3, const ushort* __restrict__ featb,
    short* __restrict__ g) {
    __shared__ float ihts[64 * 32];
    __shared__ float w3t[32 * 64];
    __shared__ __align__(16) ushort gs16[64 * 88];
    const int tid = threadIdx.x;
    const int b = blockIdx.x >> 4;
    const int n0 = (blockIdx.x & 15) * 64;

    for (int idx = tid; idx < 2048; idx += 256) {
        int c = idx >> 6, j = idx & 63;
        w3t[idx] = W3[j * 32 + c];
    }

    {
        const int c0 = (tid & 7) * 4, np = tid >> 3;
        const ushort* hb = htcb + (size_t)b * HRB * CHH + c0;
        for (int p = 0; p < 2; ++p) {
            int nl = np * 2 + p;
            const int* fp = &flat[(n0 + nl) * NTH];
            float s0 = 0.0f, s1 = 0.0f, s2 = 0.0f, s3 = 0.0f;
            for (int t = 0; t < NTH; ++t) {
                int h = fp[t];
                ushort4 v = *(const ushort4*)&hb[(size_t)h * CHH];
                s0 += bf2f(v.x); s1 += bf2f(v.y); s2 += bf2f(v.z); s3 += bf2f(v.w);
            }
            float4 r;
            r.x = s0 * (1.0f / 60.0f); r.y = s1 * (1.0f / 60.0f);
            r.z = s2 * (1.0f / 60.0f); r.w = s3 * (1.0f / 60.0f);
            *(float4*)&ihts[nl * 32 + c0] = r;
        }
    }
    __syncthreads();

    const int j = tid & 63, nb = tid >> 6;
    for (int nn = nb; nn < 64; nn += 4) {
        float z = 0.0f;
        #pragma unroll 8
        for (int cc = 0; cc < 32; ++cc) z += ihts[nn * 32 + cc] * w3t[cc * 64 + j];
        float v = bf2f(featb[((size_t)b * NTOK + n0 + nn) * CF + j]) + z;
        gs16[nn * 88 + j] = f2bf(v);
    }
    __syncthreads();

    for (int idx = tid; idx < 512; idx += 256) {
        int kg = idx >> 6, nnl = idx & 63;
        bf16x8 frag = *(const bf16x8*)&gs16[nnl * 88 + kg * 8];
        int m = b * NTOK + n0 + nnl;
        int mt = m >> 7, mloc = m & 127;
        *(bf16x8*)&g[((mt * 8 + kg) * 128 + mloc) * 8] = frag;
    }
}

// ---------------------------------------------------------------------------
// K5: MFMA bf16 GEMM: out = g @ Wt_out^T + bt_out. 128x128 tile, K=64.
__global__ __launch_bounds__(256) void k5_mfma(
    const short* __restrict__ g, const short* __restrict__ wout,
    const float* __restrict__ bt_out, float* __restrict__ out) {
    __shared__ __align__(16) short Asm[8192];
    __shared__ __align__(16) short Bsm[8192];
    const int tid = threadIdx.x;
    const int lane = tid & 63, wave = tid >> 6;
    const int wm = wave >> 1, wn = wave & 1;
    const int mb = blockIdx.x / 6, db = blockIdx.x % 6;

    for (int ch = tid; ch < 1024; ch += 256) {
        GLDS16((const char*)g + (size_t)mb * 16384 + ch * 16, (char*)Asm + ch * 16);
        GLDS16((const char*)wout + (size_t)db * 16384 + ch * 16, (char*)Bsm + ch * 16);
    }
    __syncthreads();

    f32x4 acc[4][4] = {};
    const bf16x8* Ap = (const bf16x8*)Asm;
    const bf16x8* Bp = (const bf16x8*)Bsm;
    #pragma unroll
    for (int ks = 0; ks < 2; ++ks) {
        int kg = (lane >> 4) + ks * 4;
        bf16x8 av[4], bv[4];
        #pragma unroll
        for (int i = 0; i < 4; ++i)
            av[i] = Ap[kg * 128 + wm * 64 + i * 16 + (lane & 15)];
        #pragma unroll
        for (int j = 0; j < 4; ++j)
            bv[j] = Bp[kg * 128 + wn * 64 + j * 16 + (lane & 15)];
        #pragma unroll
        for (int i = 0; i < 4; ++i)
            #pragma unroll
            for (int j = 0; j < 4; ++j)
                acc[i][j] = __builtin_amdgcn_mfma_f32_16x16x32_bf16(
                    av[i], bv[j], acc[i][j], 0, 0, 0);
    }

    const int d0 = db * 128 + wn * 64 + (lane & 15);
    float bb[4];
    #pragma unroll
    for (int j = 0; j < 4; ++j) bb[j] = bt_out[d0 + j * 16];
    const int mrow = mb * 128 + wm * 64 + ((lane >> 4) << 2);
    #pragma unroll
    for (int i = 0; i < 4; ++i)
        #pragma unroll
        for (int r = 0; r < 4; ++r)
            #pragma unroll
            for (int j = 0; j < 4; ++j)
                out[(size_t)(mrow + i * 16 + r) * DMODEL + d0 + j * 16] =
                    acc[i][j][r] + bb[j];
}

// ---------------------------------------------------------------------------
extern "C" void kernel_launch(void* const* d_in, const int* in_sizes, int n_in,
                              void* d_out, int out_size, void* d_ws, size_t ws_size,
                              hipStream_t stream) {
    const float* tokens = (const float*)d_in[0];
    const float* Wt_in  = (const float*)d_in[2];
    const float* bt_in  = (const float*)d_in[3];
    const float* W1     = (const float*)d_in[4];
    const float* W2     = (const float*)d_in[5];
    const float* W3     = (const float*)d_in[6];
    const float* Wt_out = (const float*)d_in[7];
    const float* bt_out = (const float*)d_in[8];
    float* out = (float*)d_out;

    // workspace layout (bytes, all offsets 16-aligned)
    char* w = (char*)d_ws;
    int*    flat   = (int*)(w);                 // 245760   -> 245760
    int*    perm   = (int*)(w + 245760);        // 245760   -> 491520
    int*    rowptr = (int*)(w + 491520);        // 21600    -> 513120
    short*  wcat   = (short*)(w + 513120);      // 147456   -> 660576
    float*  bcat   = (float*)(w + 660576);      // 384      -> 660960
    short*  wout   = (short*)(w + 660960);      // 98304    -> 759264
    short*  w2t    = (short*)(w + 759264);      // 18432    -> 777696
    ushort* featb  = (ushort*)(w + 777696);     // 4194304  -> 4972000
    float*  yb     = (float*)(w + 4972000);     // 4194304  -> 9166304
    short*  g      = (short*)(w + 4972000);     // aliases yb (y dead after k23)
    ushort* htcb   = (ushort*)(w + 9166304);    // 10936320 -> 20102624

    k0_csr<<<NTH, 256, 0, stream>>>(flat, perm, rowptr);
    k0_wcat<<<96, 256, 0, stream>>>(Wt_in, bt_in, W1, wcat, bcat);
    k0_wprep<<<60, 256, 0, stream>>>(Wt_out, W2, wout, w2t);
    k1_mfma<<<NB * NTOK / 64, 256, 0, stream>>>(tokens, wcat, bcat, featb, yb);
    k23_ht_conv<<<NB * NTH, 256, 0, stream>>>(yb, perm, rowptr, w2t, htcb);
    k4_iht_z<<<NB * (NTOK / 64), 256, 0, stream>>>(htcb, flat, W3, featb, g);
    k5_mfma<<<(NB * NTOK / 128) * (DMODEL / 128), 256, 0, stream>>>(g, wout, bt_out, out);
}

// Round 8
// 106.461 us; speedup vs baseline: 6.3143x; 1.1703x over previous
//
#include <hip/hip_runtime.h>
#include <math.h>

// Problem constants (fixed by reference: B=32, 32x32 tokens, DM=768, C=64, ch=32,
// theta_res=3 -> 60 thetas, rho_res=1 on 32x32 -> q=44 -> 89 rhos)
#define NB    32
#define NTOK  1024
#define DMODEL 768
#define CF    64
#define CHH   32
#define NRHO  89
#define NTH   60
#define HRB   (NRHO*NTH)  // 5340

typedef short bf16x8 __attribute__((ext_vector_type(8)));
typedef float f32x4  __attribute__((ext_vector_type(4)));
typedef unsigned int uint;
typedef unsigned short ushort;
typedef unsigned char uchar;

__device__ __forceinline__ ushort f2bf(float f) {
    uint u = __float_as_uint(f);
    return (ushort)((u + 0x7FFF + ((u >> 16) & 1)) >> 16);
}
__device__ __forceinline__ float bf2f(ushort u) {
    return __uint_as_float(((uint)u) << 16);
}

#define GLDS16(gp, lp) __builtin_amdgcn_global_load_lds( \
    (const __attribute__((address_space(1))) unsigned int*)(gp), \
    (__attribute__((address_space(3))) unsigned int*)(lp), 16, 0, 0)

// ---------------------------------------------------------------------------
// K0 mega-kernel:
//  blocks 0..59    : per-theta CSR (counting sort) + rho8[t][n] byte table
//  blocks 60..155  : Wcat = [Wt_in; W1@Wt_in] -> bf16 tiled, bcat
//  blocks 156..215 : Wt_out -> wout tiled; W2 -> w2t MFMA A-frags
__global__ __launch_bounds__(256) void k0_prep(
    int* __restrict__ perm, int* __restrict__ rowptr, uchar* __restrict__ rho8,
    const float* __restrict__ Wt_in, const float* __restrict__ bt_in,
    const float* __restrict__ W1, short* __restrict__ wcat,
    float* __restrict__ bcat,
    const float* __restrict__ Wt_out, const float* __restrict__ W2,
    short* __restrict__ wout, short* __restrict__ w2t) {
    __shared__ int rho_n[NTOK];
    __shared__ int cnt2[64 * 90];
    __shared__ int tot[96];
    __shared__ int base[96];
    __shared__ float w1row[64];
    const int tid = threadIdx.x;
    const int blk = blockIdx.x;

    if (blk < 60) {
        const int t = blk;
        const double rad = ((double)(t * 3)) * (M_PI / 180.0);
        const double ct = cos(rad), st = sin(rad);
        for (int n = tid; n < NTOK; n += 256) {
            int i = n >> 5, j = n & 31;
            double rho = (double)(j - 16) * ct + (double)(16 - i) * st;
            int ridx = (int)rint(rho) + 44;
            rho_n[n] = ridx;
            rho8[t * NTOK + n] = (uchar)ridx;
        }
        for (int i = tid; i < 64 * 90; i += 256) cnt2[i] = 0;
        __syncthreads();
        for (int n = tid; n < NTOK; n += 256)
            atomicAdd(&cnt2[(n >> 4) * 90 + rho_n[n]], 1);
        __syncthreads();
        if (tid < NRHO) {   // exclusive scan over chunks for this rho
            int s = 0;
            for (int c = 0; c < 64; ++c) {
                int v = cnt2[c * 90 + tid];
                cnt2[c * 90 + tid] = s;
                s += v;
            }
            tot[tid] = s;
        }
        __syncthreads();
        if (tid == 0) {
            int s = 0;
            for (int r = 0; r < NRHO; ++r) { base[r] = s; s += tot[r]; }
            base[NRHO] = s;   // 1024
        }
        __syncthreads();
        if (tid < NRHO + 1) rowptr[t * 90 + tid] = base[tid];
        if (tid < 64) {   // fill: one thread per chunk, private cursors
            const int c = tid;
            #pragma unroll
            for (int j = 0; j < 16; ++j) {
                int n = c * 16 + j;
                int r = rho_n[n];
                int cur = cnt2[c * 90 + r];
                cnt2[c * 90 + r] = cur + 1;
                perm[t * NTOK + base[r] + cur] = n;
            }
        }
    } else if (blk < 156) {
        const int c = blk - 60;   // 0..95
        if (c >= 64)
            for (int j = tid; j < 64; j += 256) w1row[j] = W1[(c - 64) * 64 + j];
        __syncthreads();
        for (int k = tid; k < DMODEL; k += 256) {
            float v;
            if (c < 64) v = Wt_in[c * DMODEL + k];
            else {
                v = 0.0f;
                for (int j = 0; j < 64; ++j) v += w1row[j] * Wt_in[j * DMODEL + k];
            }
            int kt = k >> 6, kk = k & 63;
            wcat[(((kt << 3) + (kk >> 3)) * 96 + c) * 8 + (k & 7)] = (short)f2bf(v);
        }
        if (tid == 0) {
            float bv;
            if (c < 64) bv = bt_in[c];
            else {
                bv = 0.0f;
                for (int j = 0; j < 64; ++j) bv += W1[(c - 64) * 64 + j] * bt_in[j];
            }
            bcat[c] = bv;
        }
    } else {
        int idx = (blk - 156) * 256 + tid;   // 15360 total
        if (idx < 6144) {
            int d = idx >> 3, kg = idx & 7;
            float4 a = *(const float4*)&Wt_out[d * 64 + kg * 8];
            float4 b = *(const float4*)&Wt_out[d * 64 + kg * 8 + 4];
            uint p0 = (uint)f2bf(a.x) | ((uint)f2bf(a.y) << 16);
            uint p1 = (uint)f2bf(a.z) | ((uint)f2bf(a.w) << 16);
            uint p2 = (uint)f2bf(b.x) | ((uint)f2bf(b.y) << 16);
            uint p3 = (uint)f2bf(b.z) | ((uint)f2bf(b.w) << 16);
            uint4 v = make_uint4(p0, p1, p2, p3);
            *(uint4*)&wout[(((d >> 7) * 8 + kg) * 128 + (d & 127)) * 8] = v;
        } else if (idx < 6144 + 9216) {
            int q = idx - 6144;
            int e = q & 7, ln = (q >> 3) & 63, wm = (q >> 9) & 1, k = q >> 10;
            int o = wm * 16 + (ln & 15), i = ((ln >> 4) << 3) + e;
            w2t[q] = (short)f2bf(W2[(o * 32 + i) * 9 + k]);
        }
    }
}

// ---------------------------------------------------------------------------
// K1: MFMA bf16 GEMM: [feat | y] = tokens @ Wcat^T + bcat, y gets relu.
// feat stored bf16 (featb); y stored bf16 (ybb) for k23's gather.
__global__ __launch_bounds__(256) void k1_mfma(
    const float* __restrict__ tokens, const short* __restrict__ wcat,
    const float* __restrict__ bcat, ushort* __restrict__ featb,
    ushort* __restrict__ ybb) {
    __shared__ __align__(16) short Asm[2][4096];   // [kg8][m64][k8]
    __shared__ __align__(16) short Bsm[2][6144];   // [kg8][c96][k8]

    const int tid = threadIdx.x;
    const int lane = tid & 63, wave = tid >> 6;
    const int wm = wave >> 1, wn = wave & 1;
    const int row0 = blockIdx.x * 64;
    const int sm = tid >> 2, sq = tid & 3;

    const float* arow = tokens + (size_t)(row0 + sm) * DMODEL;

    f32x4 acc[2][3] = {};
    float4 ta[4];

    #pragma unroll
    for (int p = 0; p < 4; ++p)
        ta[p] = *(const float4*)&arow[(sq + 4 * p) * 4];
    for (int ch = tid; ch < 768; ch += 256)
        GLDS16((const char*)wcat + ch * 16, (char*)Bsm[0] + ch * 16);
    #pragma unroll
    for (int p = 0; p < 4; ++p) {
        int q = sq + 4 * p, kg = q >> 1, half = q & 1;
        uint lo = (uint)f2bf(ta[p].x) | ((uint)f2bf(ta[p].y) << 16);
        uint hi = (uint)f2bf(ta[p].z) | ((uint)f2bf(ta[p].w) << 16);
        *(uint2*)((char*)Asm[0] + (kg * 64 + sm) * 16 + half * 8) = make_uint2(lo, hi);
    }
    __syncthreads();

    int cur = 0;
    for (int kt = 0; kt < 12; ++kt) {
        if (kt < 11) {
            const float* src = arow + (kt + 1) * 64;
            #pragma unroll
            for (int p = 0; p < 4; ++p)
                ta[p] = *(const float4*)&src[(sq + 4 * p) * 4];
            const char* bsrc = (const char*)wcat + (size_t)(kt + 1) * 12288;
            for (int ch = tid; ch < 768; ch += 256)
                GLDS16(bsrc + ch * 16, (char*)Bsm[cur ^ 1] + ch * 16);
        }
        const bf16x8* Ap = (const bf16x8*)Asm[cur];
        const bf16x8* Bp = (const bf16x8*)Bsm[cur];
        #pragma unroll
        for (int ks = 0; ks < 2; ++ks) {
            int kg = (lane >> 4) + ks * 4;
            bf16x8 av[2], bv[3];
            #pragma unroll
            for (int i = 0; i < 2; ++i)
                av[i] = Ap[kg * 64 + wm * 32 + i * 16 + (lane & 15)];
            #pragma unroll
            for (int j = 0; j < 3; ++j)
                bv[j] = Bp[kg * 96 + wn * 48 + j * 16 + (lane & 15)];
            #pragma unroll
            for (int i = 0; i < 2; ++i)
                #pragma unroll
                for (int j = 0; j < 3; ++j)
                    acc[i][j] = __builtin_amdgcn_mfma_f32_16x16x32_bf16(
                        av[i], bv[j], acc[i][j], 0, 0, 0);
        }
        if (kt < 11) {
            #pragma unroll
            for (int p = 0; p < 4; ++p) {
                int q = sq + 4 * p, kg = q >> 1, half = q & 1;
                uint lo = (uint)f2bf(ta[p].x) | ((uint)f2bf(ta[p].y) << 16);
                uint hi = (uint)f2bf(ta[p].z) | ((uint)f2bf(ta[p].w) << 16);
                *(uint2*)((char*)Asm[cur ^ 1] + (kg * 64 + sm) * 16 + half * 8) =
                    make_uint2(lo, hi);
            }
        }
        __syncthreads();
        cur ^= 1;
    }

    float bb[3];
    #pragma unroll
    for (int j = 0; j < 3; ++j) bb[j] = bcat[wn * 48 + j * 16 + (lane & 15)];
    #pragma unroll
    for (int i = 0; i < 2; ++i) {
        #pragma unroll
        for (int j = 0; j < 3; ++j) {
            int c = wn * 48 + j * 16 + (lane & 15);
            #pragma unroll
            for (int r = 0; r < 4; ++r) {
                int m = row0 + wm * 32 + i * 16 + ((lane >> 4) << 2) + r;
                float v = acc[i][j][r] + bb[j];
                if (c < 64) featb[(size_t)m * CF + c] = f2bf(v);
                else        ybb[(size_t)m * CHH + (c - 64)] = f2bf(fmaxf(v, 0.0f));
            }
        }
    }
}

// ---------------------------------------------------------------------------
// K23: fused HT (CSR gather from bf16 y) + (9,1) rho-conv via MFMA.
// Output htcT[b][t][rho][c] bf16 -- fully contiguous 5.7 KB stream per block.
__global__ __launch_bounds__(256) void k23_ht_conv(
    const ushort* __restrict__ ybb, const int* __restrict__ perm,
    const int* __restrict__ rowptr, const short* __restrict__ w2t,
    ushort* __restrict__ htcT) {
    __shared__ int pperm[NTOK];                      // 4 KB
    __shared__ int prow[90];
    __shared__ __align__(16) short insp[104 * 40];   // 8.3 KB bf16, stride 40
    __shared__ ushort outts[NRHO * 36];              // 6.4 KB bf16

    const int tid = threadIdx.x;
    const int lane = tid & 63, wave = tid >> 6;
    const int wm = wave >> 1, wn = wave & 1;
    const int b = blockIdx.x / NTH, t = blockIdx.x % NTH;

    bf16x8 av[9];
    #pragma unroll
    for (int k = 0; k < 9; ++k)
        av[k] = *(const bf16x8*)&w2t[(((k * 2 + wm) * 64) + lane) * 8];

    for (int i = tid; i < NTOK; i += 256) pperm[i] = perm[t * NTOK + i];
    for (int i = tid; i < 90; i += 256) prow[i] = rowptr[t * 90 + i];
    for (int i = tid; i < 104 * 40 / 2; i += 256) ((uint*)insp)[i] = 0;
    __syncthreads();

    {
        const int c0 = (tid & 7) * 4, g = tid >> 3;   // 32 rho groups
        const ushort* yp = ybb + (size_t)b * NTOK * CHH + c0;
        for (int rho = g; rho < NRHO; rho += 32) {
            int p0 = prow[rho], p1 = prow[rho + 1];
            float s0 = 0.0f, s1 = 0.0f, s2 = 0.0f, s3 = 0.0f;
            for (int k = p0; k < p1; ++k) {
                int n = pperm[k];
                ushort4 v = *(const ushort4*)&yp[n * CHH];
                s0 += bf2f(v.x); s1 += bf2f(v.y); s2 += bf2f(v.z); s3 += bf2f(v.w);
            }
            float iv = 1.0f / fmaxf((float)(p1 - p0), 1.0f);
            uint q0 = (uint)f2bf(s0 * iv) | ((uint)f2bf(s1 * iv) << 16);
            uint q1 = (uint)f2bf(s2 * iv) | ((uint)f2bf(s3 * iv) << 16);
            *(uint2*)&insp[(rho + 4) * 40 + c0] = make_uint2(q0, q1);
        }
    }
    __syncthreads();

    f32x4 acc[3] = {};
    #pragma unroll
    for (int f = 0; f < 3; ++f) {
        int Rn = wn * 48 + f * 16 + (lane & 15);
        #pragma unroll
        for (int k = 0; k < 9; ++k) {
            bf16x8 bv = *(const bf16x8*)&insp[(Rn + k) * 40 + ((lane >> 4) << 3)];
            acc[f] = __builtin_amdgcn_mfma_f32_16x16x32_bf16(av[k], bv, acc[f], 0, 0, 0);
        }
    }
    #pragma unroll
    for (int f = 0; f < 3; ++f) {
        int r = wn * 48 + f * 16 + (lane & 15);
        if (r < NRHO) {
            #pragma unroll
            for (int reg = 0; reg < 4; ++reg) {
                int o = wm * 16 + ((lane >> 4) << 2) + reg;
                outts[r * 36 + o] = f2bf(fmaxf(acc[f][reg], 0.0f));
            }
        }
    }
    __syncthreads();

    {   // contiguous stream: htcT slab for (b,t) = 89*32 ushorts
        ushort* dst = htcT + (size_t)(b * NTH + t) * (NRHO * CHH);
        for (int idx = tid; idx < NRHO * 8; idx += 256) {   // 8B chunks
            int r = idx >> 3, cq = (idx & 7) * 4;
            ushort4 v;
            v.x = outts[r * 36 + cq];     v.y = outts[r * 36 + cq + 1];
            v.z = outts[r * 36 + cq + 2]; v.w = outts[r * 36 + cq + 3];
            *(ushort4*)&dst[r * CHH + cq] = v;
        }
    }
}

// ---------------------------------------------------------------------------
// K4: iht gather from htcT (per-t near-contiguous rho) -> z = iht @ W3^T
//     -> g = bf16(feat + z) in k5 tiled layout. 32-token tiles, 1024 blocks.
__global__ __launch_bounds__(256) void k4_iht_z(
    const ushort* __restrict__ htcT, const uchar* __restrict__ rho8,
    const float* __restrict__ W3, const ushort* __restrict__ featb,
    short* __restrict__ g) {
    __shared__ float w3t[32 * 64];                 // 8 KB
    __shared__ uchar lrho[NTH * 32];               // 1.9 KB [t][tok]
    __shared__ float ihts[32 * 32];                // 4 KB
    __shared__ __align__(16) ushort gs16[32 * 72]; // 4.6 KB
    const int tid = threadIdx.x;
    const int b = blockIdx.x >> 5;
    const int n0 = (blockIdx.x & 31) * 32;

    for (int idx = tid; idx < 2048; idx += 256) {
        int c = idx >> 6, j = idx & 63;
        w3t[idx] = W3[j * 32 + c];
    }
    for (int idx = tid; idx < NTH * 32; idx += 256) {
        int t = idx >> 5, tok = idx & 31;
        lrho[t * 32 + tok] = rho8[t * NTOK + n0 + tok];
    }
    __syncthreads();

    {
        const int c0 = (tid & 7) * 4, tok = tid >> 3;   // 1 token x 4 ch per thread
        const ushort* hb = htcT + (size_t)b * NTH * NRHO * CHH + c0;
        float s0 = 0.0f, s1 = 0.0f, s2 = 0.0f, s3 = 0.0f;
        #pragma unroll 10
        for (int t = 0; t < NTH; ++t) {
            int r = lrho[t * 32 + tok];
            ushort4 v = *(const ushort4*)&hb[(t * NRHO + r) * CHH];
            s0 += bf2f(v.x); s1 += bf2f(v.y); s2 += bf2f(v.z); s3 += bf2f(v.w);
        }
        float4 rr;
        rr.x = s0 * (1.0f / 60.0f); rr.y = s1 * (1.0f / 60.0f);
        rr.z = s2 * (1.0f / 60.0f); rr.w = s3 * (1.0f / 60.0f);
        *(float4*)&ihts[tok * 32 + c0] = rr;
    }
    __syncthreads();

    const int j = tid & 63, nb = tid >> 6;
    for (int nn = nb; nn < 32; nn += 4) {
        float z = 0.0f;
        #pragma unroll 8
        for (int cc = 0; cc < 32; ++cc) z += ihts[nn * 32 + cc] * w3t[cc * 64 + j];
        float v = bf2f(featb[((size_t)b * NTOK + n0 + nn) * CF + j]) + z;
        gs16[nn * 72 + j] = f2bf(v);
    }
    __syncthreads();

    {   // 1 chunk per thread into g tiled [mt][kg8][mloc128][k8]
        int nnl = tid >> 3, kg = tid & 7;
        bf16x8 frag = *(const bf16x8*)&gs16[nnl * 72 + kg * 8];
        int m = b * NTOK + n0 + nnl;
        int mt = m >> 7, mloc = m & 127;
        *(bf16x8*)&g[((mt * 8 + kg) * 128 + mloc) * 8] = frag;
    }
}

// ---------------------------------------------------------------------------
// K5: MFMA bf16 GEMM: out = g @ Wt_out^T + bt_out. 128x128 tile, K=64.
__global__ __launch_bounds__(256) void k5_mfma(
    const short* __restrict__ g, const short* __restrict__ wout,
    const float* __restrict__ bt_out, float* __restrict__ out) {
    __shared__ __align__(16) short Asm[8192];
    __shared__ __align__(16) short Bsm[8192];
    const int tid = threadIdx.x;
    const int lane = tid & 63, wave = tid >> 6;
    const int wm = wave >> 1, wn = wave & 1;
    const int mb = blockIdx.x / 6, db = blockIdx.x % 6;

    for (int ch = tid; ch < 1024; ch += 256) {
        GLDS16((const char*)g + (size_t)mb * 16384 + ch * 16, (char*)Asm + ch * 16);
        GLDS16((const char*)wout + (size_t)db * 16384 + ch * 16, (char*)Bsm + ch * 16);
    }
    __syncthreads();

    f32x4 acc[4][4] = {};
    const bf16x8* Ap = (const bf16x8*)Asm;
    const bf16x8* Bp = (const bf16x8*)Bsm;
    #pragma unroll
    for (int ks = 0; ks < 2; ++ks) {
        int kg = (lane >> 4) + ks * 4;
        bf16x8 av[4], bv[4];
        #pragma unroll
        for (int i = 0; i < 4; ++i)
            av[i] = Ap[kg * 128 + wm * 64 + i * 16 + (lane & 15)];
        #pragma unroll
        for (int j = 0; j < 4; ++j)
            bv[j] = Bp[kg * 128 + wn * 64 + j * 16 + (lane & 15)];
        #pragma unroll
        for (int i = 0; i < 4; ++i)
            #pragma unroll
            for (int j = 0; j < 4; ++j)
                acc[i][j] = __builtin_amdgcn_mfma_f32_16x16x32_bf16(
                    av[i], bv[j], acc[i][j], 0, 0, 0);
    }

    const int d0 = db * 128 + wn * 64 + (lane & 15);
    float bb[4];
    #pragma unroll
    for (int j = 0; j < 4; ++j) bb[j] = bt_out[d0 + j * 16];
    const int mrow = mb * 128 + wm * 64 + ((lane >> 4) << 2);
    #pragma unroll
    for (int i = 0; i < 4; ++i)
        #pragma unroll
        for (int r = 0; r < 4; ++r)
            #pragma unroll
            for (int j = 0; j < 4; ++j)
                out[(size_t)(mrow + i * 16 + r) * DMODEL + d0 + j * 16] =
                    acc[i][j][r] + bb[j];
}

// ---------------------------------------------------------------------------
extern "C" void kernel_launch(void* const* d_in, const int* in_sizes, int n_in,
                              void* d_out, int out_size, void* d_ws, size_t ws_size,
                              hipStream_t stream) {
    const float* tokens = (const float*)d_in[0];
    const float* Wt_in  = (const float*)d_in[2];
    const float* bt_in  = (const float*)d_in[3];
    const float* W1     = (const float*)d_in[4];
    const float* W2     = (const float*)d_in[5];
    const float* W3     = (const float*)d_in[6];
    const float* Wt_out = (const float*)d_in[7];
    const float* bt_out = (const float*)d_in[8];
    float* out = (float*)d_out;

    // workspace layout (bytes, 16-aligned)
    char* w = (char*)d_ws;
    int*    perm   = (int*)(w);                  // 245760   -> 245760
    int*    rowptr = (int*)(w + 245760);         // 21600    -> 267360
    uchar*  rho8   = (uchar*)(w + 267360);       // 61440    -> 328800
    short*  wcat   = (short*)(w + 328800);       // 147456   -> 476256
    float*  bcat   = (float*)(w + 476256);       // 384      -> 476640
    short*  wout   = (short*)(w + 476640);       // 98304    -> 574944
    short*  w2t    = (short*)(w + 574944);       // 18432    -> 593376
    ushort* featb  = (ushort*)(w + 593376);      // 4194304  -> 4787680
    ushort* ybb    = (ushort*)(w + 4787680);     // 2097152  -> 6884832
    short*  g      = (short*)(w + 6884832);      // 4194304  -> 11079136
    ushort* htcT   = (ushort*)(w + 11079136);    // 10936320 -> 22015456

    k0_prep<<<216, 256, 0, stream>>>(perm, rowptr, rho8, Wt_in, bt_in, W1,
                                     wcat, bcat, Wt_out, W2, wout, w2t);
    k1_mfma<<<NB * NTOK / 64, 256, 0, stream>>>(tokens, wcat, bcat, featb, ybb);
    k23_ht_conv<<<NB * NTH, 256, 0, stream>>>(ybb, perm, rowptr, w2t, htcT);
    k4_iht_z<<<NB * (NTOK / 32), 256, 0, stream>>>(htcT, rho8, W3, featb, g);
    k5_mfma<<<(NB * NTOK / 128) * (DMODEL / 128), 256, 0, stream>>>(g, wout, bt_out, out);
}

// Round 9
// 100.964 us; speedup vs baseline: 6.6581x; 1.0544x over previous
//
#include <hip/hip_runtime.h>
#include <math.h>

// Problem constants (fixed by reference: B=32, 32x32 tokens, DM=768, C=64, ch=32,
// theta_res=3 -> 60 thetas, rho_res=1 on 32x32 -> q=44 -> 89 rhos)
#define NB    32
#define NTOK  1024
#define DMODEL 768
#define CF    64
#define CHH   32
#define NRHO  89
#define NTH   60
#define HRB   (NRHO*NTH)  // 5340

typedef short bf16x8 __attribute__((ext_vector_type(8)));
typedef float f32x4  __attribute__((ext_vector_type(4)));
typedef unsigned int uint;
typedef unsigned short ushort;
typedef unsigned char uchar;

__device__ __forceinline__ ushort f2bf(float f) {
    uint u = __float_as_uint(f);
    return (ushort)((u + 0x7FFF + ((u >> 16) & 1)) >> 16);
}
__device__ __forceinline__ float bf2f(ushort u) {
    return __uint_as_float(((uint)u) << 16);
}
// HW packed convert: dst[15:0]=bf16(lo), dst[31:16]=bf16(hi). RTNE, same as f2bf.
__device__ __forceinline__ uint cvtpk(float lo, float hi) {
    uint r;
    asm("v_cvt_pk_bf16_f32 %0, %1, %2" : "=v"(r) : "v"(lo), "v"(hi));
    return r;
}

#define GLDS16(gp, lp) __builtin_amdgcn_global_load_lds( \
    (const __attribute__((address_space(1))) unsigned int*)(gp), \
    (__attribute__((address_space(3))) unsigned int*)(lp), 16, 0, 0)

// ---------------------------------------------------------------------------
// K0 mega-kernel:
//  blocks 0..59    : per-theta CSR (counting sort) + rho8[t][n] byte table
//  blocks 60..155  : Wcat = [Wt_in; W1@Wt_in] -> bf16 tiled, bcat
//  blocks 156..215 : Wt_out -> wout tiled; W2 -> w2t MFMA A-frags
__global__ __launch_bounds__(256) void k0_prep(
    int* __restrict__ perm, int* __restrict__ rowptr, uchar* __restrict__ rho8,
    const float* __restrict__ Wt_in, const float* __restrict__ bt_in,
    const float* __restrict__ W1, short* __restrict__ wcat,
    float* __restrict__ bcat,
    const float* __restrict__ Wt_out, const float* __restrict__ W2,
    short* __restrict__ wout, short* __restrict__ w2t) {
    __shared__ int rho_n[NTOK];
    __shared__ int cnt2[64 * 90];
    __shared__ int tot[96];
    __shared__ int base[96];
    __shared__ float w1row[64];
    const int tid = threadIdx.x;
    const int blk = blockIdx.x;

    if (blk < 60) {
        const int t = blk;
        const double rad = ((double)(t * 3)) * (M_PI / 180.0);
        const double ct = cos(rad), st = sin(rad);
        for (int n = tid; n < NTOK; n += 256) {
            int i = n >> 5, j = n & 31;
            double rho = (double)(j - 16) * ct + (double)(16 - i) * st;
            int ridx = (int)rint(rho) + 44;
            rho_n[n] = ridx;
            rho8[t * NTOK + n] = (uchar)ridx;
        }
        for (int i = tid; i < 64 * 90; i += 256) cnt2[i] = 0;
        __syncthreads();
        for (int n = tid; n < NTOK; n += 256)
            atomicAdd(&cnt2[(n >> 4) * 90 + rho_n[n]], 1);
        __syncthreads();
        if (tid < NRHO) {   // exclusive scan over chunks for this rho
            int s = 0;
            for (int c = 0; c < 64; ++c) {
                int v = cnt2[c * 90 + tid];
                cnt2[c * 90 + tid] = s;
                s += v;
            }
            tot[tid] = s;
        }
        __syncthreads();
        if (tid == 0) {
            int s = 0;
            for (int r = 0; r < NRHO; ++r) { base[r] = s; s += tot[r]; }
            base[NRHO] = s;   // 1024
        }
        __syncthreads();
        if (tid < NRHO + 1) rowptr[t * 90 + tid] = base[tid];
        if (tid < 64) {   // fill: one thread per chunk, private cursors
            const int c = tid;
            #pragma unroll
            for (int j = 0; j < 16; ++j) {
                int n = c * 16 + j;
                int r = rho_n[n];
                int cur = cnt2[c * 90 + r];
                cnt2[c * 90 + r] = cur + 1;
                perm[t * NTOK + base[r] + cur] = n;
            }
        }
    } else if (blk < 156) {
        const int c = blk - 60;   // 0..95
        if (c >= 64)
            for (int j = tid; j < 64; j += 256) w1row[j] = W1[(c - 64) * 64 + j];
        __syncthreads();
        for (int k = tid; k < DMODEL; k += 256) {
            float v;
            if (c < 64) v = Wt_in[c * DMODEL + k];
            else {
                v = 0.0f;
                for (int j = 0; j < 64; ++j) v += w1row[j] * Wt_in[j * DMODEL + k];
            }
            int kt = k >> 6, kk = k & 63;
            wcat[(((kt << 3) + (kk >> 3)) * 96 + c) * 8 + (k & 7)] = (short)f2bf(v);
        }
        if (tid == 0) {
            float bv;
            if (c < 64) bv = bt_in[c];
            else {
                bv = 0.0f;
                for (int j = 0; j < 64; ++j) bv += W1[(c - 64) * 64 + j] * bt_in[j];
            }
            bcat[c] = bv;
        }
    } else {
        int idx = (blk - 156) * 256 + tid;   // 15360 total
        if (idx < 6144) {
            int d = idx >> 3, kg = idx & 7;
            float4 a = *(const float4*)&Wt_out[d * 64 + kg * 8];
            float4 b = *(const float4*)&Wt_out[d * 64 + kg * 8 + 4];
            uint4 v = make_uint4(cvtpk(a.x, a.y), cvtpk(a.z, a.w),
                                 cvtpk(b.x, b.y), cvtpk(b.z, b.w));
            *(uint4*)&wout[(((d >> 7) * 8 + kg) * 128 + (d & 127)) * 8] = v;
        } else if (idx < 6144 + 9216) {
            int q = idx - 6144;
            int e = q & 7, ln = (q >> 3) & 63, wm = (q >> 9) & 1, k = q >> 10;
            int o = wm * 16 + (ln & 15), i = ((ln >> 4) << 3) + e;
            w2t[q] = (short)f2bf(W2[(o * 32 + i) * 9 + k]);
        }
    }
}

// ---------------------------------------------------------------------------
// K1: MFMA bf16 GEMM: [feat | y] = tokens @ Wcat^T + bcat, y gets relu.
// Staging pack via v_cvt_pk_bf16_f32; epilogue LDS-staged coalesced stores.
__global__ __launch_bounds__(256) void k1_mfma(
    const float* __restrict__ tokens, const short* __restrict__ wcat,
    const float* __restrict__ bcat, ushort* __restrict__ featb,
    ushort* __restrict__ ybb) {
    __shared__ __align__(16) short Asm[2][4096];   // [kg8][m64][k8]
    __shared__ __align__(16) short Bsm[2][6144];   // [kg8][c96][k8]

    const int tid = threadIdx.x;
    const int lane = tid & 63, wave = tid >> 6;
    const int wm = wave >> 1, wn = wave & 1;
    const int row0 = blockIdx.x * 64;
    const int sm = tid >> 2, sq = tid & 3;

    const float* arow = tokens + (size_t)(row0 + sm) * DMODEL;

    f32x4 acc[2][3] = {};
    float4 ta[4];

    #pragma unroll
    for (int p = 0; p < 4; ++p)
        ta[p] = *(const float4*)&arow[(sq + 4 * p) * 4];
    for (int ch = tid; ch < 768; ch += 256)
        GLDS16((const char*)wcat + ch * 16, (char*)Bsm[0] + ch * 16);
    #pragma unroll
    for (int p = 0; p < 4; ++p) {
        int q = sq + 4 * p, kg = q >> 1, half = q & 1;
        uint lo = cvtpk(ta[p].x, ta[p].y);
        uint hi = cvtpk(ta[p].z, ta[p].w);
        *(uint2*)((char*)Asm[0] + (kg * 64 + sm) * 16 + half * 8) = make_uint2(lo, hi);
    }
    __syncthreads();

    int cur = 0;
    for (int kt = 0; kt < 12; ++kt) {
        if (kt < 11) {
            const float* src = arow + (kt + 1) * 64;
            #pragma unroll
            for (int p = 0; p < 4; ++p)
                ta[p] = *(const float4*)&src[(sq + 4 * p) * 4];
            const char* bsrc = (const char*)wcat + (size_t)(kt + 1) * 12288;
            for (int ch = tid; ch < 768; ch += 256)
                GLDS16(bsrc + ch * 16, (char*)Bsm[cur ^ 1] + ch * 16);
        }
        const bf16x8* Ap = (const bf16x8*)Asm[cur];
        const bf16x8* Bp = (const bf16x8*)Bsm[cur];
        #pragma unroll
        for (int ks = 0; ks < 2; ++ks) {
            int kg = (lane >> 4) + ks * 4;
            bf16x8 av[2], bv[3];
            #pragma unroll
            for (int i = 0; i < 2; ++i)
                av[i] = Ap[kg * 64 + wm * 32 + i * 16 + (lane & 15)];
            #pragma unroll
            for (int j = 0; j < 3; ++j)
                bv[j] = Bp[kg * 96 + wn * 48 + j * 16 + (lane & 15)];
            #pragma unroll
            for (int i = 0; i < 2; ++i)
                #pragma unroll
                for (int j = 0; j < 3; ++j)
                    acc[i][j] = __builtin_amdgcn_mfma_f32_16x16x32_bf16(
                        av[i], bv[j], acc[i][j], 0, 0, 0);
        }
        if (kt < 11) {
            #pragma unroll
            for (int p = 0; p < 4; ++p) {
                int q = sq + 4 * p, kg = q >> 1, half = q & 1;
                uint lo = cvtpk(ta[p].x, ta[p].y);
                uint hi = cvtpk(ta[p].z, ta[p].w);
                *(uint2*)((char*)Asm[cur ^ 1] + (kg * 64 + sm) * 16 + half * 8) =
                    make_uint2(lo, hi);
            }
        }
        __syncthreads();
        cur ^= 1;
    }

    // epilogue: stage bf16 into LDS (reuse Asm), then 16B coalesced stores
    ushort* fs = (ushort*)Asm[0];   // 64 x 64
    ushort* ys = (ushort*)Asm[1];   // 64 x 32
    float bb[3];
    #pragma unroll
    for (int j = 0; j < 3; ++j) bb[j] = bcat[wn * 48 + j * 16 + (lane & 15)];
    #pragma unroll
    for (int i = 0; i < 2; ++i) {
        #pragma unroll
        for (int j = 0; j < 3; ++j) {
            int c = wn * 48 + j * 16 + (lane & 15);
            int mlb = wm * 32 + i * 16 + ((lane >> 4) << 2);
            #pragma unroll
            for (int r = 0; r < 4; ++r) {
                float v = acc[i][j][r] + bb[j];
                if (c < 64) fs[(mlb + r) * 64 + c] = f2bf(v);
                else        ys[(mlb + r) * 32 + (c - 64)] = f2bf(fmaxf(v, 0.0f));
            }
        }
    }
    __syncthreads();
    for (int idx = tid; idx < 512; idx += 256) {
        int ml = idx >> 3, cq = (idx & 7) * 8;
        *(uint4*)&featb[(size_t)(row0 + ml) * CF + cq] = *(const uint4*)&fs[ml * 64 + cq];
    }
    {
        int ml = tid >> 2, cq = (tid & 3) * 8;
        *(uint4*)&ybb[(size_t)(row0 + ml) * CHH + cq] = *(const uint4*)&ys[ml * 32 + cq];
    }
}

// ---------------------------------------------------------------------------
// K23: fused HT (CSR gather from bf16 y) + (9,1) rho-conv via MFMA.
// Output htcT[b][t][rho][c] bf16 (contiguous per-block stream).
__global__ __launch_bounds__(256) void k23_ht_conv(
    const ushort* __restrict__ ybb, const int* __restrict__ perm,
    const int* __restrict__ rowptr, const short* __restrict__ w2t,
    ushort* __restrict__ htcT) {
    __shared__ int pperm[NTOK];                      // 4 KB
    __shared__ int prow[90];
    __shared__ __align__(16) short insp[104 * 40];   // 8.3 KB bf16, stride 40
    __shared__ uint outtu[NRHO * 18];                // 6.4 KB packed bf16 pairs

    const int tid = threadIdx.x;
    const int lane = tid & 63, wave = tid >> 6;
    const int wm = wave >> 1, wn = wave & 1;
    const int b = blockIdx.x / NTH, t = blockIdx.x % NTH;

    bf16x8 av[9];
    #pragma unroll
    for (int k = 0; k < 9; ++k)
        av[k] = *(const bf16x8*)&w2t[(((k * 2 + wm) * 64) + lane) * 8];

    for (int i = tid; i < NTOK; i += 256) pperm[i] = perm[t * NTOK + i];
    for (int i = tid; i < 90; i += 256) prow[i] = rowptr[t * 90 + i];
    for (int i = tid; i < 104 * 40 / 2; i += 256) ((uint*)insp)[i] = 0;
    __syncthreads();

    {
        const int c0 = (tid & 7) * 4, g = tid >> 3;   // 32 rho groups
        const ushort* yp = ybb + (size_t)b * NTOK * CHH + c0;
        for (int rho = g; rho < NRHO; rho += 32) {
            int p0 = prow[rho], p1 = prow[rho + 1];
            float s0 = 0.0f, s1 = 0.0f, s2 = 0.0f, s3 = 0.0f;
            for (int k = p0; k < p1; ++k) {
                int n = pperm[k];
                ushort4 v = *(const ushort4*)&yp[n * CHH];
                s0 += bf2f(v.x); s1 += bf2f(v.y); s2 += bf2f(v.z); s3 += bf2f(v.w);
            }
            float iv = 1.0f / fmaxf((float)(p1 - p0), 1.0f);
            *(uint2*)&insp[(rho + 4) * 40 + c0] =
                make_uint2(cvtpk(s0 * iv, s1 * iv), cvtpk(s2 * iv, s3 * iv));
        }
    }
    __syncthreads();

    f32x4 acc[3] = {};
    #pragma unroll
    for (int f = 0; f < 3; ++f) {
        int Rn = wn * 48 + f * 16 + (lane & 15);
        #pragma unroll
        for (int k = 0; k < 9; ++k) {
            bf16x8 bv = *(const bf16x8*)&insp[(Rn + k) * 40 + ((lane >> 4) << 3)];
            acc[f] = __builtin_amdgcn_mfma_f32_16x16x32_bf16(av[k], bv, acc[f], 0, 0, 0);
        }
    }
    #pragma unroll
    for (int f = 0; f < 3; ++f) {
        int r = wn * 48 + f * 16 + (lane & 15);
        if (r < NRHO) {
            int ob = wm * 8 + ((lane >> 4) << 1);
            outtu[r * 18 + ob]     = cvtpk(fmaxf(acc[f][0], 0.0f), fmaxf(acc[f][1], 0.0f));
            outtu[r * 18 + ob + 1] = cvtpk(fmaxf(acc[f][2], 0.0f), fmaxf(acc[f][3], 0.0f));
        }
    }
    __syncthreads();

    {   // contiguous stream: htcT slab for (b,t) = 89*32 ushorts
        ushort* dst = htcT + (size_t)(b * NTH + t) * (NRHO * CHH);
        for (int idx = tid; idx < NRHO * 8; idx += 256) {   // 8B chunks
            int r = idx >> 3, q = idx & 7;
            uint2 v;
            v.x = outtu[r * 18 + q * 2];
            v.y = outtu[r * 18 + q * 2 + 1];
            *(uint2*)&dst[r * CHH + q * 4] = v;
        }
    }
}

// ---------------------------------------------------------------------------
// K45: fused iht gather -> z-GEMM -> A-tile (LDS, never global) -> out GEMM.
// 256 blocks x 512 threads; block owns 128 tokens, loops db=0..5 over out cols.
__global__ __launch_bounds__(512) void k45_iht_out(
    const ushort* __restrict__ htcT, const uchar* __restrict__ rho8,
    const float* __restrict__ W3, const ushort* __restrict__ featb,
    const short* __restrict__ wout, const float* __restrict__ bt_out,
    float* __restrict__ out) {
    __shared__ __align__(16) char smem[81408];
    short* Alds = (short*)smem;                   // 16 KB  [kg8][m128][k8]
    short* Blds = (short*)(smem + 16384);         // 32 KB dbuf [2][kg8][d128][k8]
    float* w3t  = (float*)(smem + 49152);         // 8 KB  [cc32][j64]
    uchar* lrho = (uchar*)(smem + 57344);         // 7.5 KB [t60][tok128]
    float* ihts = (float*)(smem + 65024);         // 16 KB [tok128][c32]

    const int tid = threadIdx.x;
    const int lane = tid & 63, wave = tid >> 6;
    const int wm = wave >> 1, wn = wave & 1;      // wm 0..3 (32 rows), wn 0..1 (64 cols)
    const int b = blockIdx.x >> 3;
    const int n0 = (blockIdx.x & 7) * 128;

    // issue B tile for db=0 early (hides under prologue)
    for (int ch = tid; ch < 1024; ch += 512)
        GLDS16((const char*)wout + ch * 16, (char*)Blds + ch * 16);

    for (int idx = tid; idx < 2048; idx += 512) {
        int c = idx >> 6, j = idx & 63;
        w3t[idx] = W3[j * 32 + c];
    }
    for (int idx = tid; idx < NTH * 128; idx += 512)
        lrho[idx] = rho8[(idx >> 7) * NTOK + n0 + (idx & 127)];
    __syncthreads();

    // iht gather: 1 token x 8 channels per thread (16B loads)
    {
        const int c0 = (tid & 3) * 8, tok = tid >> 2;
        const ushort* hb = htcT + (size_t)b * NTH * NRHO * CHH + c0;
        float s[8] = {};
        #pragma unroll 6
        for (int t = 0; t < NTH; ++t) {
            int r = lrho[t * 128 + tok];
            uint4 v = *(const uint4*)&hb[(size_t)(t * NRHO + r) * CHH];
            s[0] += bf2f((ushort)(v.x & 0xffff)); s[1] += bf2f((ushort)(v.x >> 16));
            s[2] += bf2f((ushort)(v.y & 0xffff)); s[3] += bf2f((ushort)(v.y >> 16));
            s[4] += bf2f((ushort)(v.z & 0xffff)); s[5] += bf2f((ushort)(v.z >> 16));
            s[6] += bf2f((ushort)(v.w & 0xffff)); s[7] += bf2f((ushort)(v.w >> 16));
        }
        float4 r0, r1;
        r0.x = s[0] * (1.0f / 60.0f); r0.y = s[1] * (1.0f / 60.0f);
        r0.z = s[2] * (1.0f / 60.0f); r0.w = s[3] * (1.0f / 60.0f);
        r1.x = s[4] * (1.0f / 60.0f); r1.y = s[5] * (1.0f / 60.0f);
        r1.z = s[6] * (1.0f / 60.0f); r1.w = s[7] * (1.0f / 60.0f);
        *(float4*)&ihts[tok * 32 + c0] = r0;
        *(float4*)&ihts[tok * 32 + c0 + 4] = r1;
    }
    __syncthreads();

    // z = iht @ W3^T; A = bf16(feat + z) packed [kg8][m128][k8]
    {
        const int j = tid & 63, nb = tid >> 6;
        ushort* Au = (ushort*)Alds;
        for (int nn = nb; nn < 128; nn += 8) {
            float z = 0.0f;
            #pragma unroll 8
            for (int cc = 0; cc < 32; ++cc) z += ihts[nn * 32 + cc] * w3t[cc * 64 + j];
            float v = bf2f(featb[((size_t)b * NTOK + n0 + nn) * CF + j]) + z;
            Au[((j >> 3) * 128 + nn) * 8 + (j & 7)] = f2bf(v);
        }
    }
    __syncthreads();   // A visible; B tile 0 GLDS drained (vmcnt)

    const bf16x8* Ap = (const bf16x8*)Alds;
    for (int db = 0; db < 6; ++db) {
        if (db < 5) {
            const char* src = (const char*)wout + (size_t)(db + 1) * 16384;
            char* dst = (char*)Blds + ((db + 1) & 1) * 16384;
            for (int ch = tid; ch < 1024; ch += 512)
                GLDS16(src + ch * 16, dst + ch * 16);
        }
        const bf16x8* Bp = (const bf16x8*)((const char*)Blds + (db & 1) * 16384);
        f32x4 acc[2][4] = {};
        #pragma unroll
        for (int ks = 0; ks < 2; ++ks) {
            int kg = (lane >> 4) + ks * 4;
            bf16x8 avv[2], bvv[4];
            #pragma unroll
            for (int i = 0; i < 2; ++i)
                avv[i] = Ap[kg * 128 + wm * 32 + i * 16 + (lane & 15)];
            #pragma unroll
            for (int jf = 0; jf < 4; ++jf)
                bvv[jf] = Bp[kg * 128 + wn * 64 + jf * 16 + (lane & 15)];
            #pragma unroll
            for (int i = 0; i < 2; ++i)
                #pragma unroll
                for (int jf = 0; jf < 4; ++jf)
                    acc[i][jf] = __builtin_amdgcn_mfma_f32_16x16x32_bf16(
                        avv[i], bvv[jf], acc[i][jf], 0, 0, 0);
        }
        const int d0 = db * 128 + wn * 64 + (lane & 15);
        float bb[4];
        #pragma unroll
        for (int jf = 0; jf < 4; ++jf) bb[jf] = bt_out[d0 + jf * 16];
        const int mrow = blockIdx.x * 128 + wm * 32 + ((lane >> 4) << 2);
        #pragma unroll
        for (int i = 0; i < 2; ++i)
            #pragma unroll
            for (int r = 0; r < 4; ++r)
                #pragma unroll
                for (int jf = 0; jf < 4; ++jf)
                    out[(size_t)(mrow + i * 16 + r) * DMODEL + d0 + jf * 16] =
                        acc[i][jf][r] + bb[jf];
        __syncthreads();
    }
}

// ---------------------------------------------------------------------------
extern "C" void kernel_launch(void* const* d_in, const int* in_sizes, int n_in,
                              void* d_out, int out_size, void* d_ws, size_t ws_size,
                              hipStream_t stream) {
    const float* tokens = (const float*)d_in[0];
    const float* Wt_in  = (const float*)d_in[2];
    const float* bt_in  = (const float*)d_in[3];
    const float* W1     = (const float*)d_in[4];
    const float* W2     = (const float*)d_in[5];
    const float* W3     = (const float*)d_in[6];
    const float* Wt_out = (const float*)d_in[7];
    const float* bt_out = (const float*)d_in[8];
    float* out = (float*)d_out;

    // workspace layout (bytes, 16-aligned)
    char* w = (char*)d_ws;
    int*    perm   = (int*)(w);                  // 245760   -> 245760
    int*    rowptr = (int*)(w + 245760);         // 21600    -> 267360
    uchar*  rho8   = (uchar*)(w + 267360);       // 61440    -> 328800
    short*  wcat   = (short*)(w + 328800);       // 147456   -> 476256
    float*  bcat   = (float*)(w + 476256);       // 384      -> 476640
    short*  wout   = (short*)(w + 476640);       // 98304    -> 574944
    short*  w2t    = (short*)(w + 574944);       // 18432    -> 593376
    ushort* featb  = (ushort*)(w + 593376);      // 4194304  -> 4787680
    ushort* ybb    = (ushort*)(w + 4787680);     // 2097152  -> 6884832
    ushort* htcT   = (ushort*)(w + 6884832);     // 10936320 -> 17821152

    k0_prep<<<216, 256, 0, stream>>>(perm, rowptr, rho8, Wt_in, bt_in, W1,
                                     wcat, bcat, Wt_out, W2, wout, w2t);
    k1_mfma<<<NB * NTOK / 64, 256, 0, stream>>>(tokens, wcat, bcat, featb, ybb);
    k23_ht_conv<<<NB * NTH, 256, 0, stream>>>(ybb, perm, rowptr, w2t, htcT);
    k45_iht_out<<<NB * (NTOK / 128), 512, 0, stream>>>(htcT, rho8, W3, featb,
                                                       wout, bt_out, out);
}

// Round 10
// 100.365 us; speedup vs baseline: 6.6978x; 1.0060x over previous
//
#include <hip/hip_runtime.h>
#include <math.h>

// Problem constants (fixed by reference: B=32, 32x32 tokens, DM=768, C=64, ch=32,
// theta_res=3 -> 60 thetas, rho_res=1 on 32x32 -> q=44 -> 89 rhos)
#define NB    32
#define NTOK  1024
#define DMODEL 768
#define CF    64
#define CHH   32
#define NRHO  89
#define NTH   60
#define HRB   (NRHO*NTH)  // 5340

typedef short bf16x8 __attribute__((ext_vector_type(8)));
typedef float f32x4  __attribute__((ext_vector_type(4)));
typedef unsigned int uint;
typedef unsigned short ushort;
typedef unsigned char uchar;

__device__ __forceinline__ ushort f2bf(float f) {
    uint u = __float_as_uint(f);
    return (ushort)((u + 0x7FFF + ((u >> 16) & 1)) >> 16);
}
__device__ __forceinline__ float bf2f(ushort u) {
    return __uint_as_float(((uint)u) << 16);
}
// HW packed convert: dst[15:0]=bf16(lo), dst[31:16]=bf16(hi). RTNE, same as f2bf.
__device__ __forceinline__ uint cvtpk(float lo, float hi) {
    uint r;
    asm("v_cvt_pk_bf16_f32 %0, %1, %2" : "=v"(r) : "v"(lo), "v"(hi));
    return r;
}

#define GLDS16(gp, lp) __builtin_amdgcn_global_load_lds( \
    (const __attribute__((address_space(1))) unsigned int*)(gp), \
    (__attribute__((address_space(3))) unsigned int*)(lp), 16, 0, 0)

// ---------------------------------------------------------------------------
// K0 mega-kernel:
//  blocks 0..59    : per-theta CSR (counting sort) + rho8[t][n] byte table
//  blocks 60..155  : Wcat = [Wt_in; W1@Wt_in] -> bf16 tiled, bcat
//  blocks 156..215 : Wt_out -> wout tiled; W2 -> w2t MFMA A-frags
__global__ __launch_bounds__(256) void k0_prep(
    int* __restrict__ perm, int* __restrict__ rowptr, uchar* __restrict__ rho8,
    const float* __restrict__ Wt_in, const float* __restrict__ bt_in,
    const float* __restrict__ W1, short* __restrict__ wcat,
    float* __restrict__ bcat,
    const float* __restrict__ Wt_out, const float* __restrict__ W2,
    short* __restrict__ wout, short* __restrict__ w2t) {
    __shared__ int rho_n[NTOK];
    __shared__ int cnt2[64 * 90];
    __shared__ int tot[96];
    __shared__ int base[96];
    __shared__ float w1row[64];
    const int tid = threadIdx.x;
    const int blk = blockIdx.x;

    if (blk < 60) {
        const int t = blk;
        const double rad = ((double)(t * 3)) * (M_PI / 180.0);
        const double ct = cos(rad), st = sin(rad);
        for (int n = tid; n < NTOK; n += 256) {
            int i = n >> 5, j = n & 31;
            double rho = (double)(j - 16) * ct + (double)(16 - i) * st;
            int ridx = (int)rint(rho) + 44;
            rho_n[n] = ridx;
            rho8[t * NTOK + n] = (uchar)ridx;
        }
        for (int i = tid; i < 64 * 90; i += 256) cnt2[i] = 0;
        __syncthreads();
        for (int n = tid; n < NTOK; n += 256)
            atomicAdd(&cnt2[(n >> 4) * 90 + rho_n[n]], 1);
        __syncthreads();
        if (tid < NRHO) {   // exclusive scan over chunks for this rho
            int s = 0;
            for (int c = 0; c < 64; ++c) {
                int v = cnt2[c * 90 + tid];
                cnt2[c * 90 + tid] = s;
                s += v;
            }
            tot[tid] = s;
        }
        __syncthreads();
        if (tid == 0) {
            int s = 0;
            for (int r = 0; r < NRHO; ++r) { base[r] = s; s += tot[r]; }
            base[NRHO] = s;   // 1024
        }
        __syncthreads();
        if (tid < NRHO + 1) rowptr[t * 90 + tid] = base[tid];
        if (tid < 64) {   // fill: one thread per chunk, private cursors
            const int c = tid;
            #pragma unroll
            for (int j = 0; j < 16; ++j) {
                int n = c * 16 + j;
                int r = rho_n[n];
                int cur = cnt2[c * 90 + r];
                cnt2[c * 90 + r] = cur + 1;
                perm[t * NTOK + base[r] + cur] = n;
            }
        }
    } else if (blk < 156) {
        const int c = blk - 60;   // 0..95
        if (c >= 64)
            for (int j = tid; j < 64; j += 256) w1row[j] = W1[(c - 64) * 64 + j];
        __syncthreads();
        for (int k = tid; k < DMODEL; k += 256) {
            float v;
            if (c < 64) v = Wt_in[c * DMODEL + k];
            else {
                v = 0.0f;
                for (int j = 0; j < 64; ++j) v += w1row[j] * Wt_in[j * DMODEL + k];
            }
            int kt = k >> 6, kk = k & 63;
            wcat[(((kt << 3) + (kk >> 3)) * 96 + c) * 8 + (k & 7)] = (short)f2bf(v);
        }
        if (tid == 0) {
            float bv;
            if (c < 64) bv = bt_in[c];
            else {
                bv = 0.0f;
                for (int j = 0; j < 64; ++j) bv += W1[(c - 64) * 64 + j] * bt_in[j];
            }
            bcat[c] = bv;
        }
    } else {
        int idx = (blk - 156) * 256 + tid;   // 15360 total
        if (idx < 6144) {
            int d = idx >> 3, kg = idx & 7;
            float4 a = *(const float4*)&Wt_out[d * 64 + kg * 8];
            float4 b = *(const float4*)&Wt_out[d * 64 + kg * 8 + 4];
            uint4 v = make_uint4(cvtpk(a.x, a.y), cvtpk(a.z, a.w),
                                 cvtpk(b.x, b.y), cvtpk(b.z, b.w));
            *(uint4*)&wout[(((d >> 7) * 8 + kg) * 128 + (d & 127)) * 8] = v;
        } else if (idx < 6144 + 9216) {
            int q = idx - 6144;
            int e = q & 7, ln = (q >> 3) & 63, wm = (q >> 9) & 1, k = q >> 10;
            int o = wm * 16 + (ln & 15), i = ((ln >> 4) << 3) + e;
            w2t[q] = (short)f2bf(W2[(o * 32 + i) * 9 + k]);
        }
    }
}

// ---------------------------------------------------------------------------
// K1: MFMA bf16 GEMM: [feat | y] = tokens @ Wcat^T + bcat, y gets relu.
__global__ __launch_bounds__(256) void k1_mfma(
    const float* __restrict__ tokens, const short* __restrict__ wcat,
    const float* __restrict__ bcat, ushort* __restrict__ featb,
    ushort* __restrict__ ybb) {
    __shared__ __align__(16) short Asm[2][4096];   // [kg8][m64][k8]
    __shared__ __align__(16) short Bsm[2][6144];   // [kg8][c96][k8]

    const int tid = threadIdx.x;
    const int lane = tid & 63, wave = tid >> 6;
    const int wm = wave >> 1, wn = wave & 1;
    const int row0 = blockIdx.x * 64;
    const int sm = tid >> 2, sq = tid & 3;

    const float* arow = tokens + (size_t)(row0 + sm) * DMODEL;

    f32x4 acc[2][3] = {};
    float4 ta[4];

    #pragma unroll
    for (int p = 0; p < 4; ++p)
        ta[p] = *(const float4*)&arow[(sq + 4 * p) * 4];
    for (int ch = tid; ch < 768; ch += 256)
        GLDS16((const char*)wcat + ch * 16, (char*)Bsm[0] + ch * 16);
    #pragma unroll
    for (int p = 0; p < 4; ++p) {
        int q = sq + 4 * p, kg = q >> 1, half = q & 1;
        uint lo = cvtpk(ta[p].x, ta[p].y);
        uint hi = cvtpk(ta[p].z, ta[p].w);
        *(uint2*)((char*)Asm[0] + (kg * 64 + sm) * 16 + half * 8) = make_uint2(lo, hi);
    }
    __syncthreads();

    int cur = 0;
    for (int kt = 0; kt < 12; ++kt) {
        if (kt < 11) {
            const float* src = arow + (kt + 1) * 64;
            #pragma unroll
            for (int p = 0; p < 4; ++p)
                ta[p] = *(const float4*)&src[(sq + 4 * p) * 4];
            const char* bsrc = (const char*)wcat + (size_t)(kt + 1) * 12288;
            for (int ch = tid; ch < 768; ch += 256)
                GLDS16(bsrc + ch * 16, (char*)Bsm[cur ^ 1] + ch * 16);
        }
        const bf16x8* Ap = (const bf16x8*)Asm[cur];
        const bf16x8* Bp = (const bf16x8*)Bsm[cur];
        #pragma unroll
        for (int ks = 0; ks < 2; ++ks) {
            int kg = (lane >> 4) + ks * 4;
            bf16x8 av[2], bv[3];
            #pragma unroll
            for (int i = 0; i < 2; ++i)
                av[i] = Ap[kg * 64 + wm * 32 + i * 16 + (lane & 15)];
            #pragma unroll
            for (int j = 0; j < 3; ++j)
                bv[j] = Bp[kg * 96 + wn * 48 + j * 16 + (lane & 15)];
            #pragma unroll
            for (int i = 0; i < 2; ++i)
                #pragma unroll
                for (int j = 0; j < 3; ++j)
                    acc[i][j] = __builtin_amdgcn_mfma_f32_16x16x32_bf16(
                        av[i], bv[j], acc[i][j], 0, 0, 0);
        }
        if (kt < 11) {
            #pragma unroll
            for (int p = 0; p < 4; ++p) {
                int q = sq + 4 * p, kg = q >> 1, half = q & 1;
                uint lo = cvtpk(ta[p].x, ta[p].y);
                uint hi = cvtpk(ta[p].z, ta[p].w);
                *(uint2*)((char*)Asm[cur ^ 1] + (kg * 64 + sm) * 16 + half * 8) =
                    make_uint2(lo, hi);
            }
        }
        __syncthreads();
        cur ^= 1;
    }

    // epilogue: stage bf16 into LDS (reuse Asm), then 16B coalesced stores
    ushort* fs = (ushort*)Asm[0];   // 64 x 64
    ushort* ys = (ushort*)Asm[1];   // 64 x 32
    float bb[3];
    #pragma unroll
    for (int j = 0; j < 3; ++j) bb[j] = bcat[wn * 48 + j * 16 + (lane & 15)];
    #pragma unroll
    for (int i = 0; i < 2; ++i) {
        #pragma unroll
        for (int j = 0; j < 3; ++j) {
            int c = wn * 48 + j * 16 + (lane & 15);
            int mlb = wm * 32 + i * 16 + ((lane >> 4) << 2);
            #pragma unroll
            for (int r = 0; r < 4; ++r) {
                float v = acc[i][j][r] + bb[j];
                if (c < 64) fs[(mlb + r) * 64 + c] = f2bf(v);
                else        ys[(mlb + r) * 32 + (c - 64)] = f2bf(fmaxf(v, 0.0f));
            }
        }
    }
    __syncthreads();
    for (int idx = tid; idx < 512; idx += 256) {
        int ml = idx >> 3, cq = (idx & 7) * 8;
        *(uint4*)&featb[(size_t)(row0 + ml) * CF + cq] = *(const uint4*)&fs[ml * 64 + cq];
    }
    {
        int ml = tid >> 2, cq = (tid & 3) * 8;
        *(uint4*)&ybb[(size_t)(row0 + ml) * CHH + cq] = *(const uint4*)&ys[ml * 32 + cq];
    }
}

// ---------------------------------------------------------------------------
// K23: fused HT (CSR gather from bf16 y, 16B loads) + (9,1) rho-conv via MFMA.
// Output htcT[b][t][rho][c] bf16 (contiguous per-block stream).
__global__ __launch_bounds__(256) void k23_ht_conv(
    const ushort* __restrict__ ybb, const int* __restrict__ perm,
    const int* __restrict__ rowptr, const short* __restrict__ w2t,
    ushort* __restrict__ htcT) {
    __shared__ int pperm[NTOK];                      // 4 KB
    __shared__ int prow[90];
    __shared__ __align__(16) short insp[104 * 40];   // 8.3 KB bf16, stride 40
    __shared__ uint outtu[NRHO * 18];                // 6.4 KB packed bf16 pairs

    const int tid = threadIdx.x;
    const int lane = tid & 63, wave = tid >> 6;
    const int wm = wave >> 1, wn = wave & 1;
    const int b = blockIdx.x / NTH, t = blockIdx.x % NTH;

    bf16x8 av[9];
    #pragma unroll
    for (int k = 0; k < 9; ++k)
        av[k] = *(const bf16x8*)&w2t[(((k * 2 + wm) * 64) + lane) * 8];

    for (int i = tid; i < NTOK; i += 256) pperm[i] = perm[t * NTOK + i];
    for (int i = tid; i < 90; i += 256) prow[i] = rowptr[t * 90 + i];
    for (int i = tid; i < 104 * 40 / 2; i += 256) ((uint*)insp)[i] = 0;
    __syncthreads();

    {   // 4 channel-groups x 64 rho-groups; 16B y loads (full 8-ch halves)
        const int c0 = (tid & 3) * 8, g = tid >> 2;
        const ushort* yp = ybb + (size_t)b * NTOK * CHH + c0;
        for (int rho = g; rho < NRHO; rho += 64) {
            int p0 = prow[rho], p1 = prow[rho + 1];
            float s0 = 0, s1 = 0, s2 = 0, s3 = 0, s4 = 0, s5 = 0, s6 = 0, s7 = 0;
            for (int k = p0; k < p1; ++k) {
                int n = pperm[k];
                uint4 v = *(const uint4*)&yp[n * CHH];
                s0 += bf2f((ushort)(v.x & 0xffff)); s1 += bf2f((ushort)(v.x >> 16));
                s2 += bf2f((ushort)(v.y & 0xffff)); s3 += bf2f((ushort)(v.y >> 16));
                s4 += bf2f((ushort)(v.z & 0xffff)); s5 += bf2f((ushort)(v.z >> 16));
                s6 += bf2f((ushort)(v.w & 0xffff)); s7 += bf2f((ushort)(v.w >> 16));
            }
            float iv = 1.0f / fmaxf((float)(p1 - p0), 1.0f);
            uint4 pk = make_uint4(cvtpk(s0 * iv, s1 * iv), cvtpk(s2 * iv, s3 * iv),
                                  cvtpk(s4 * iv, s5 * iv), cvtpk(s6 * iv, s7 * iv));
            *(uint4*)&insp[(rho + 4) * 40 + c0] = pk;
        }
    }
    __syncthreads();

    f32x4 acc[3] = {};
    #pragma unroll
    for (int f = 0; f < 3; ++f) {
        int Rn = wn * 48 + f * 16 + (lane & 15);
        #pragma unroll
        for (int k = 0; k < 9; ++k) {
            bf16x8 bv = *(const bf16x8*)&insp[(Rn + k) * 40 + ((lane >> 4) << 3)];
            acc[f] = __builtin_amdgcn_mfma_f32_16x16x32_bf16(av[k], bv, acc[f], 0, 0, 0);
        }
    }
    #pragma unroll
    for (int f = 0; f < 3; ++f) {
        int r = wn * 48 + f * 16 + (lane & 15);
        if (r < NRHO) {
            int ob = wm * 8 + ((lane >> 4) << 1);
            outtu[r * 18 + ob]     = cvtpk(fmaxf(acc[f][0], 0.0f), fmaxf(acc[f][1], 0.0f));
            outtu[r * 18 + ob + 1] = cvtpk(fmaxf(acc[f][2], 0.0f), fmaxf(acc[f][3], 0.0f));
        }
    }
    __syncthreads();

    {   // contiguous stream: htcT slab for (b,t) = 89*32 ushorts
        ushort* dst = htcT + (size_t)(b * NTH + t) * (NRHO * CHH);
        for (int idx = tid; idx < NRHO * 8; idx += 256) {   // 8B chunks
            int r = idx >> 3, q = idx & 7;
            uint2 v;
            v.x = outtu[r * 18 + q * 2];
            v.y = outtu[r * 18 + q * 2 + 1];
            *(uint2*)&dst[r * CHH + q * 4] = v;
        }
    }
}

// ---------------------------------------------------------------------------
// K45: fused iht gather -> z-GEMM -> A-tile (LDS) -> out GEMM.
// 512 blocks x 256 threads, 64-token tiles. LDS = exactly 40 KB (phased reuse
// of the B-dbuf region for gather scratch) -> 4 blocks/CU.
__global__ __launch_bounds__(256, 4) void k45_iht_out(
    const ushort* __restrict__ htcT, const uchar* __restrict__ rho8,
    const float* __restrict__ W3, const ushort* __restrict__ featb,
    const short* __restrict__ wout, const float* __restrict__ bt_out,
    float* __restrict__ out) {
    __shared__ __align__(16) char smem[40960];
    short* Blds = (short*)smem;                   // phase 2: [2][kg8][d128][k8] 32 KB
    short* Alds = (short*)(smem + 32768);         // 8 KB [kg8][m64][k8]
    float* w3t  = (float*)smem;                   // phase 1: 8 KB [cc32][j64]
    uchar* lrho = (uchar*)(smem + 8192);          // 3.75 KB [t60][tok64]
    float* ihts = (float*)(smem + 12032);         // 8 KB [tok64][c32]

    const int tid = threadIdx.x;
    const int lane = tid & 63, wave = tid >> 6;
    const int wm = wave >> 1, wn = wave & 1;
    const int bid = blockIdx.x;
    const int b = bid >> 4;
    const int n0 = (bid & 15) * 64;

    // phase 1a: gather scratch loads
    for (int idx = tid; idx < 2048; idx += 256) {
        int c = idx >> 6, j = idx & 63;
        w3t[idx] = W3[j * 32 + c];
    }
    for (int idx = tid; idx < NTH * 64; idx += 256)
        lrho[idx] = rho8[(idx >> 6) * NTOK + n0 + (idx & 63)];
    __syncthreads();

    // phase 1b: iht gather, 1 token x 8 channels per thread (16B loads)
    {
        const int c0 = (tid & 3) * 8, tok = tid >> 2;
        const ushort* hb = htcT + (size_t)b * NTH * NRHO * CHH + c0;
        float s[8] = {};
        #pragma unroll 6
        for (int t = 0; t < NTH; ++t) {
            int r = lrho[t * 64 + tok];
            uint4 v = *(const uint4*)&hb[(size_t)(t * NRHO + r) * CHH];
            s[0] += bf2f((ushort)(v.x & 0xffff)); s[1] += bf2f((ushort)(v.x >> 16));
            s[2] += bf2f((ushort)(v.y & 0xffff)); s[3] += bf2f((ushort)(v.y >> 16));
            s[4] += bf2f((ushort)(v.z & 0xffff)); s[5] += bf2f((ushort)(v.z >> 16));
            s[6] += bf2f((ushort)(v.w & 0xffff)); s[7] += bf2f((ushort)(v.w >> 16));
        }
        __syncthreads();   // all lrho reads done before ihts writes (overlap region)
        float4 r0, r1;
        r0.x = s[0] * (1.0f / 60.0f); r0.y = s[1] * (1.0f / 60.0f);
        r0.z = s[2] * (1.0f / 60.0f); r0.w = s[3] * (1.0f / 60.0f);
        r1.x = s[4] * (1.0f / 60.0f); r1.y = s[5] * (1.0f / 60.0f);
        r1.z = s[6] * (1.0f / 60.0f); r1.w = s[7] * (1.0f / 60.0f);
        *(float4*)&ihts[tok * 32 + c0] = r0;
        *(float4*)&ihts[tok * 32 + c0 + 4] = r1;
    }
    __syncthreads();

    // phase 1c: z = iht @ W3^T; A = bf16(feat + z) packed [kg8][m64][k8]
    {
        const int j = tid & 63, nb = tid >> 6;
        ushort* Au = (ushort*)Alds;
        for (int nn = nb; nn < 64; nn += 4) {
            float z = 0.0f;
            #pragma unroll 8
            for (int cc = 0; cc < 32; ++cc) z += ihts[nn * 32 + cc] * w3t[cc * 64 + j];
            float v = bf2f(featb[(size_t)(bid * 64 + nn) * CF + j]) + z;
            Au[((j >> 3) * 64 + nn) * 8 + (j & 7)] = f2bf(v);
        }
    }
    __syncthreads();   // w3t/ihts dead; A visible

    // phase 2: out GEMM, db loop over 6 column tiles, double-buffered B
    for (int ch = tid; ch < 1024; ch += 256)
        GLDS16((const char*)wout + ch * 16, (char*)Blds + ch * 16);
    __syncthreads();   // drains vmcnt -> buf0 valid

    const bf16x8* Ap = (const bf16x8*)Alds;
    for (int db = 0; db < 6; ++db) {
        if (db < 5) {
            const char* src = (const char*)wout + (size_t)(db + 1) * 16384;
            char* dst = (char*)Blds + ((db + 1) & 1) * 16384;
            for (int ch = tid; ch < 1024; ch += 256)
                GLDS16(src + ch * 16, dst + ch * 16);
        }
        const bf16x8* Bp = (const bf16x8*)((const char*)Blds + (db & 1) * 16384);
        f32x4 acc[2][4] = {};
        #pragma unroll
        for (int ks = 0; ks < 2; ++ks) {
            int kg = (lane >> 4) + ks * 4;
            bf16x8 avv[2], bvv[4];
            #pragma unroll
            for (int i = 0; i < 2; ++i)
                avv[i] = Ap[kg * 64 + wm * 32 + i * 16 + (lane & 15)];
            #pragma unroll
            for (int jf = 0; jf < 4; ++jf)
                bvv[jf] = Bp[kg * 128 + wn * 64 + jf * 16 + (lane & 15)];
            #pragma unroll
            for (int i = 0; i < 2; ++i)
                #pragma unroll
                for (int jf = 0; jf < 4; ++jf)
                    acc[i][jf] = __builtin_amdgcn_mfma_f32_16x16x32_bf16(
                        avv[i], bvv[jf], acc[i][jf], 0, 0, 0);
        }
        const int d0 = db * 128 + wn * 64 + (lane & 15);
        float bb[4];
        #pragma unroll
        for (int jf = 0; jf < 4; ++jf) bb[jf] = bt_out[d0 + jf * 16];
        const int mrow = bid * 64 + wm * 32 + ((lane >> 4) << 2);
        #pragma unroll
        for (int i = 0; i < 2; ++i)
            #pragma unroll
            for (int r = 0; r < 4; ++r)
                #pragma unroll
                for (int jf = 0; jf < 4; ++jf)
                    out[(size_t)(mrow + i * 16 + r) * DMODEL + d0 + jf * 16] =
                        acc[i][jf][r] + bb[jf];
        __syncthreads();
    }
}

// ---------------------------------------------------------------------------
extern "C" void kernel_launch(void* const* d_in, const int* in_sizes, int n_in,
                              void* d_out, int out_size, void* d_ws, size_t ws_size,
                              hipStream_t stream) {
    const float* tokens = (const float*)d_in[0];
    const float* Wt_in  = (const float*)d_in[2];
    const float* bt_in  = (const float*)d_in[3];
    const float* W1     = (const float*)d_in[4];
    const float* W2     = (const float*)d_in[5];
    const float* W3     = (const float*)d_in[6];
    const float* Wt_out = (const float*)d_in[7];
    const float* bt_out = (const float*)d_in[8];
    float* out = (float*)d_out;

    // workspace layout (bytes, 16-aligned)
    char* w = (char*)d_ws;
    int*    perm   = (int*)(w);                  // 245760   -> 245760
    int*    rowptr = (int*)(w + 245760);         // 21600    -> 267360
    uchar*  rho8   = (uchar*)(w + 267360);       // 61440    -> 328800
    short*  wcat   = (short*)(w + 328800);       // 147456   -> 476256
    float*  bcat   = (float*)(w + 476256);       // 384      -> 476640
    short*  wout   = (short*)(w + 476640);       // 98304    -> 574944
    short*  w2t    = (short*)(w + 574944);       // 18432    -> 593376
    ushort* featb  = (ushort*)(w + 593376);      // 4194304  -> 4787680
    ushort* ybb    = (ushort*)(w + 4787680);     // 2097152  -> 6884832
    ushort* htcT   = (ushort*)(w + 6884832);     // 10936320 -> 17821152

    k0_prep<<<216, 256, 0, stream>>>(perm, rowptr, rho8, Wt_in, bt_in, W1,
                                     wcat, bcat, Wt_out, W2, wout, w2t);
    k1_mfma<<<NB * NTOK / 64, 256, 0, stream>>>(tokens, wcat, bcat, featb, ybb);
    k23_ht_conv<<<NB * NTH, 256, 0, stream>>>(ybb, perm, rowptr, w2t, htcT);
    k45_iht_out<<<NB * (NTOK / 64), 256, 0, stream>>>(htcT, rho8, W3, featb,
                                                      wout, bt_out, out);
}